// Round 15
// baseline (4182.075 us; speedup 1.0000x reference)
//

#include <hip/hip_runtime.h>
#include <hip/hip_bf16.h>

// ROUND 15: round 14's 774.375 = |bf16(777) - 1.625| -> the 777 sentinel fired:
// pipeline runs, outputs (float32) are visible, but vi==vtx==0 exactly =>
// labels are all NaN. Leading hypothesis: embedding inputs are float32, not
// bf16 (misreading f32 words as bf16 pairs -> ~1/256 Inf/NaN per element ->
// S saturates -> NaN cascade -> every KL term fails t>0 -> exact-zero sums).
// This round: (1) device-side dtype autodetect (row-norm test) with dual
// load paths; (2) validate_kernel: reports first non-finite stage as a float
// code 100..115 in out[0] (aux in out[1]) if anything is still broken;
// (3) clamped LSE in sinkhorn combines.

#define NN 4096
#define LDA 4104          /* fp16 row stride for S (4097 padded to x8) */
#define DD 512
#define NCNUM 409         /* int(0.1*4096) */
#define REGc 0.03f
#define INVREG (1.0f/0.03f)
#define GAM 0.8f
#define THRESHc 1e-4f
#define LOGN 8.3177661667193433f   /* ln(4096) */
#define LOGM 8.3180102775477533f   /* ln(4097) */
#define NEGINF (-__builtin_inff())

typedef unsigned short u16;
typedef unsigned int u32;

struct alignas(16) Q  { u32 x, y, z, w; };
struct alignas(8)  Q2 { u32 x, y; };
struct alignas(16) F4 { float a, b, c, d; };

__device__ __forceinline__ float bf2f(u32 u) { return __uint_as_float(u << 16); }
__device__ __forceinline__ float bflo(u32 w) { return __uint_as_float(w << 16); }
__device__ __forceinline__ float bfhi(u32 w) { return __uint_as_float(w & 0xFFFF0000u); }
__device__ __forceinline__ float h2f(u32 h) {
  u32 s = (h & 0x8000u) << 16;
  u32 e = (h >> 10) & 0x1Fu;
  u32 m = h & 0x3FFu;
  u32 r;
  if (e == 0u) r = s;
  else if (e == 31u) r = s | 0x7F800000u | (m << 13);
  else r = s | ((e + 112u) << 23) | (m << 13);
  return __uint_as_float(r);
}
__device__ __forceinline__ u32 f2h(float f) {
  u32 b = __float_as_uint(f);
  u32 s = (b >> 16) & 0x8000u;
  int e = (int)((b >> 23) & 0xFFu) - 112;
  u32 m = b & 0x7FFFFFu;
  if (e <= 0) return s;
  if (e >= 31) return s | 0x7C00u;
  u32 h = ((u32)e << 10) | (m >> 13);
  u32 rem = m & 0x1FFFu;
  h += ((rem > 0x1000u) || (rem == 0x1000u && (h & 1u))) ? 1u : 0u;
  return s | h;
}
__device__ __forceinline__ void unpack8h(Q q, float* x) {
  x[0] = h2f(q.x & 0xFFFFu); x[1] = h2f(q.x >> 16);
  x[2] = h2f(q.y & 0xFFFFu); x[3] = h2f(q.y >> 16);
  x[4] = h2f(q.z & 0xFFFFu); x[5] = h2f(q.z >> 16);
  x[6] = h2f(q.w & 0xFFFFu); x[7] = h2f(q.w >> 16);
}
__device__ __forceinline__ void lse_merge(float& m, float& s, float om, float os) {
  float nm = fmaxf(m, om);
  if (nm == NEGINF) return;
  float acc = 0.f;
  if (s  > 0.f) acc += s  * __expf(m  - nm);
  if (os > 0.f) acc += os * __expf(om - nm);
  m = nm; s = acc;
}
__device__ __forceinline__ float blockReduce256(float v) {
  __shared__ float sh[4];
  #pragma unroll
  for (int off = 32; off >= 1; off >>= 1) v += __shfl_xor(v, off);
  int w = threadIdx.x >> 6;
  if ((threadIdx.x & 63) == 0) sh[w] = v;
  __syncthreads();
  float r = 0.f;
  if (threadIdx.x == 0) r = sh[0] + sh[1] + sh[2] + sh[3];
  __syncthreads();
  return r;
}
__device__ __forceinline__ int fbad(float x) { return !(fabsf(x) < 1e30f); }

/* Template-named kernel: execution-witness probe. */
__global__ void ContrastiveLoss_83391085019222_kernel(float* out) {
  if (threadIdx.x == 0) { out[0] = 0.5f; out[1] = 0.5f; }
}
__global__ void diag_kernel(float* out, float a, float b) {
  if (threadIdx.x == 0) { out[0] = a; out[1] = b; }
}

/* ---- dtype autodetect: inputs are unit-normalized rows. Compute row-0 norm
   under bf16 and float32 interpretations; the true dtype gives norm ~= 1. ---- */
__global__ void detect_kernel(const u16* img, float* misc) {
  const int lane = threadIdx.x;  /* 64 */
  float nb = 0.f, nf = 0.f;
  const float* fimg = (const float*)img;
  for (int c = lane * 8; c < lane * 8 + 8; ++c) {
    float xb = bf2f((u32)img[c]);
    nb += xb * xb;
    float xf = fimg[c];
    if (fabsf(xf) < 1e10f) nf += xf * xf; else nf += 1e10f;
  }
  #pragma unroll
  for (int off = 32; off >= 1; off >>= 1) { nb += __shfl_xor(nb, off); nf += __shfl_xor(nf, off); }
  if (lane == 0) {
    float db = fabsf(nb - 1.f);
    float df = fabsf(nf - 1.f);
    if (!(db == db)) db = 1e30f;
    if (!(df == df)) df = 1e30f;
    ((int*)misc)[10] = (df < db) ? 1 : 0;   /* 1 = float32 inputs */
  }
}

__global__ void init_kernel(const u16* ls, float* vecs, float* misc) {
  int t = blockIdx.x * 256 + threadIdx.x;
  if (t < 16400) vecs[t] = 0.f;
  if (t == 0) {
    const int isF = ((const int*)misc)[10];
    float lsv = isF ? ((const float*)ls)[0] : bf2f((u32)ls[0]);
    misc[0] = __expf(lsv);               /* scale = exp(logit_scale) */
    int* f = (int*)misc + 6;
    f[0] = 0; f[1] = 0; f[2] = 0; f[3] = 0;
    misc[12] = 0.f; misc[13] = 0.f;      /* validate diag slots */
  }
}

/* ------- GEMM: S[i,j] = dot(img_i, txt_j) -> fp16 bits + per-block min ------- */
__global__ void gemm_kernel(const u16* A, const u16* B, u16* S, float* gmin,
                            const float* misc) {
  __shared__ float As[64 * 20];
  __shared__ float Bs[64 * 20];
  __shared__ float red[256];
  const int isF = ((const int*)misc)[10];
  const int tid = threadIdx.x;
  const int tx = tid & 15, ty = tid >> 4;
  const int rb = (int)blockIdx.y << 6, cb = (int)blockIdx.x << 6;
  const int lrow = tid >> 2;
  const int lchunk = (tid & 3) << 2;
  float acc[4][4];
  #pragma unroll
  for (int r = 0; r < 4; ++r)
    #pragma unroll
    for (int c = 0; c < 4; ++c) acc[r][c] = 0.f;
  for (int kt = 0; kt < DD; kt += 16) {
    float v0, v1, v2, v3, w0, w1, w2, w3;
    if (isF) {
      const float* Af = (const float*)A;
      const float* Bf = (const float*)B;
      F4 a4 = *(const F4*)(Af + (size_t)(rb + lrow) * DD + kt + lchunk);
      F4 b4 = *(const F4*)(Bf + (size_t)(cb + lrow) * DD + kt + lchunk);
      v0 = a4.a; v1 = a4.b; v2 = a4.c; v3 = a4.d;
      w0 = b4.a; w1 = b4.b; w2 = b4.c; w3 = b4.d;
    } else {
      Q2 a2 = *(const Q2*)(A + (size_t)(rb + lrow) * DD + kt + lchunk);
      Q2 b2 = *(const Q2*)(B + (size_t)(cb + lrow) * DD + kt + lchunk);
      v0 = bflo(a2.x); v1 = bfhi(a2.x); v2 = bflo(a2.y); v3 = bfhi(a2.y);
      w0 = bflo(b2.x); w1 = bfhi(b2.x); w2 = bflo(b2.y); w3 = bfhi(b2.y);
    }
    __syncthreads();
    As[lrow*20 + lchunk + 0] = v0; As[lrow*20 + lchunk + 1] = v1;
    As[lrow*20 + lchunk + 2] = v2; As[lrow*20 + lchunk + 3] = v3;
    Bs[lrow*20 + lchunk + 0] = w0; Bs[lrow*20 + lchunk + 1] = w1;
    Bs[lrow*20 + lchunk + 2] = w2; Bs[lrow*20 + lchunk + 3] = w3;
    __syncthreads();
    #pragma unroll
    for (int k = 0; k < 16; k += 4) {
      F4 aF[4], bF[4];
      #pragma unroll
      for (int r = 0; r < 4; ++r) aF[r] = *(const F4*)&As[(ty*4 + r)*20 + k];
      #pragma unroll
      for (int c = 0; c < 4; ++c) bF[c] = *(const F4*)&Bs[(tx*4 + c)*20 + k];
      #pragma unroll
      for (int r = 0; r < 4; ++r)
        #pragma unroll
        for (int c = 0; c < 4; ++c) {
          acc[r][c] = fmaf(aF[r].a, bF[c].a, acc[r][c]);
          acc[r][c] = fmaf(aF[r].b, bF[c].b, acc[r][c]);
          acc[r][c] = fmaf(aF[r].c, bF[c].c, acc[r][c]);
          acc[r][c] = fmaf(aF[r].d, bF[c].d, acc[r][c]);
        }
    }
  }
  float lmin = 1e30f;
  #pragma unroll
  for (int r = 0; r < 4; ++r) {
    u32 h0 = f2h(acc[r][0]), h1 = f2h(acc[r][1]);
    u32 h2 = f2h(acc[r][2]), h3 = f2h(acc[r][3]);
    lmin = fminf(lmin, h2f(h0)); lmin = fminf(lmin, h2f(h1));
    lmin = fminf(lmin, h2f(h2)); lmin = fminf(lmin, h2f(h3));
    Q2 o; o.x = h0 | (h1 << 16); o.y = h2 | (h3 << 16);
    *(Q2*)(S + (size_t)(rb + ty*4 + r) * LDA + cb + tx*4) = o;
  }
  red[tid] = lmin;
  __syncthreads();
  for (int sN = 128; sN >= 1; sN >>= 1) {
    if (tid < sN) red[tid] = fminf(red[tid], red[tid + sN]);
    __syncthreads();
  }
  if (tid == 0) gmin[blockIdx.y * 64 + blockIdx.x] = red[0];
}

/* ------- sims_no values (fp32) + per-block loss_op partial ------- */
__global__ void colvec_kernel(const u16* img, const u16* txt, const u16* tno,
                              float* colvals, float* opP, const float* misc) {
  __shared__ float shOp[4];
  const int isF = ((const int*)misc)[10];
  const int wv = threadIdx.x >> 6;
  const int row = (int)(blockIdx.x << 2) + wv;
  const int lane = threadIdx.x & 63;
  const size_t base = (size_t)row * DD + lane * 8;
  float xi[8], xt[8], xn[8];
  if (isF) {
    const float* fi = (const float*)img;
    const float* ft = (const float*)txt;
    const float* fn = (const float*)tno;
    #pragma unroll
    for (int c = 0; c < 8; ++c) { xi[c] = fi[base+c]; xt[c] = ft[base+c]; xn[c] = fn[base+c]; }
  } else {
    Q qi = *(const Q*)(img + base);
    Q qt = *(const Q*)(txt + base);
    Q qn = *(const Q*)(tno + base);
    xi[0]=bflo(qi.x); xi[1]=bfhi(qi.x); xi[2]=bflo(qi.y); xi[3]=bfhi(qi.y);
    xi[4]=bflo(qi.z); xi[5]=bfhi(qi.z); xi[6]=bflo(qi.w); xi[7]=bfhi(qi.w);
    xt[0]=bflo(qt.x); xt[1]=bfhi(qt.x); xt[2]=bflo(qt.y); xt[3]=bfhi(qt.y);
    xt[4]=bflo(qt.z); xt[5]=bfhi(qt.z); xt[6]=bflo(qt.w); xt[7]=bfhi(qt.w);
    xn[0]=bflo(qn.x); xn[1]=bfhi(qn.x); xn[2]=bflo(qn.y); xn[3]=bfhi(qn.y);
    xn[4]=bflo(qn.z); xn[5]=bfhi(qn.z); xn[6]=bflo(qn.w); xn[7]=bfhi(qn.w);
  }
  float sn = 0.f, cs = 0.f;
  #pragma unroll
  for (int c = 0; c < 8; ++c) { sn += xi[c]*xn[c]; cs += xt[c]*xn[c]; }
  #pragma unroll
  for (int off = 32; off >= 1; off >>= 1) { sn += __shfl_xor(sn, off); cs += __shfl_xor(cs, off); }
  if (lane == 0) {
    colvals[row] = sn;
    shOp[wv] = fmaxf(cs + 0.2f, 0.f) + fmaxf(-0.7f - cs, 0.f);
  }
  __syncthreads();
  if (threadIdx.x == 0) opP[blockIdx.x] = shOp[0] + shOp[1] + shOp[2] + shOp[3];
}

__global__ void scatter_col(u16* S, const float* colvals) {
  int r = blockIdx.x * 256 + threadIdx.x;
  if (r < NN) S[(size_t)r * LDA + NN] = (u16)f2h(colvals[r]);
}

__global__ void reduce_kernel(const float* gmin, const float* colvals,
                              const float* opP, float* misc) {
  __shared__ float smin[256];
  __shared__ float ssum[256];
  float mn = 1e30f, sm = 0.f;
  for (int i = threadIdx.x; i < 4096; i += 256) {
    mn = fminf(mn, gmin[i]);
    mn = fminf(mn, h2f(f2h(colvals[i])));
  }
  for (int i = threadIdx.x; i < 1024; i += 256) sm += opP[i];
  smin[threadIdx.x] = mn; ssum[threadIdx.x] = sm;
  __syncthreads();
  for (int sN = 128; sN >= 1; sN >>= 1) {
    if (threadIdx.x < sN) {
      smin[threadIdx.x] = fminf(smin[threadIdx.x], smin[threadIdx.x + sN]);
      ssum[threadIdx.x] += ssum[threadIdx.x + sN];
    }
    __syncthreads();
  }
  if (threadIdx.x == 0) {
    float maxC = 1.0f - smin[0];         /* max(1-S) = 1 - min(S) */
    misc[1] = 1.0f / (maxC * REGc);      /* a */
    misc[4] = ssum[0];
  }
}

__global__ void preds_kernel(const u16* S, const float* misc, float* preds) {
  const int row = (int)(blockIdx.x << 2) + (int)(threadIdx.x >> 6);
  const int lane = threadIdx.x & 63;
  const float scale = misc[0];
  const u16* Sr = S + (size_t)row * LDA;
  float m = NEGINF, s = 0.f;
  for (int it = 0; it < 8; ++it) {
    const int j0 = (it << 9) + (lane << 3);
    Q q = *(const Q*)(Sr + j0);
    float x[8];
    unpack8h(q, x);
    float lm = NEGINF;
    #pragma unroll
    for (int c = 0; c < 8; ++c) { x[c] *= scale; lm = fmaxf(lm, x[c]); }
    float lsum = 0.f;
    #pragma unroll
    for (int c = 0; c < 8; ++c) lsum += __expf(x[c] - lm);
    lse_merge(m, s, lm, lsum);
  }
  #pragma unroll
  for (int off = 32; off >= 1; off >>= 1) {
    float om = __shfl_xor(m, off), os = __shfl_xor(s, off);
    lse_merge(m, s, om, os);
  }
  if (lane == 0) {
    float sii = h2f((u32)Sr[row]);
    preds[row] = __expf(scale * sii - m) / s;
  }
}

__global__ void rank_kernel(const float* preds, int* is_nc) {
  __shared__ float sp[NN];
  for (int idx = threadIdx.x; idx < NN; idx += 128) sp[idx] = preds[idx];
  __syncthreads();
  const int i = blockIdx.x * 128 + threadIdx.x;
  const float pv = sp[i];
  int cnt = 0;
  for (int k2 = 0; k2 < NN; ++k2) {
    float pk = sp[k2];
    cnt += (pk < pv || (pk == pv && k2 < i)) ? 1 : 0;
  }
  is_nc[i] = (cnt < NCNUM) ? 1 : 0;
}

__device__ __forceinline__ bool unmasked(int j, int r, bool ncr) {
  return (j == NN) ? ncr : !((j == r) && ncr);
}

/* ------- fused sinkhorn pass: masked row-LSE + col-LSE partials ------- */
__global__ void sink_pass(const u16* S, const float* colVec, const float* rowVec,
                          const float* misc, const int* conv,
                          int rowGate, int colGate, const int* is_nc,
                          float* rowPM, float* rowPS, float* colPM, float* colPS) {
  const bool doRow = (conv[rowGate] == 0);
  const bool doCol = (conv[colGate] == 0);
  if (!doRow && !doCol) return;
  const float a = misc[1];
  const int ct = blockIdx.x, rt = blockIdx.y;
  const int tid = threadIdx.x;
  const int tc = tid & 31, tr = tid >> 5;
  const int cbase = ct << 8, r0 = rt << 8;
  const int j0 = cbase + (tc << 3);
  const bool anyv = (j0 <= NN);
  float wc[8]; unsigned jval = 0;
  #pragma unroll
  for (int c = 0; c < 8; ++c) {
    int j = j0 + c;
    wc[c] = 0.f;
    if (j <= NN) { jval |= 1u << c; wc[c] = colVec[j] * INVREG - a; }
  }
  float cm[8], cs[8];
  #pragma unroll
  for (int c = 0; c < 8; ++c) { cm[c] = NEGINF; cs[c] = 0.f; }

  for (int st = 0; st < 32; ++st) {
    const int r = r0 + (st << 3) + tr;
    float xv[8]; unsigned um = 0;
    if (anyv) {
      Q q = *(const Q*)(S + (size_t)r * LDA + j0);
      unpack8h(q, xv);
      const bool ncr = (is_nc[r] != 0);
      #pragma unroll
      for (int c = 0; c < 8; ++c) {
        xv[c] *= a;
        if ((jval >> c & 1u) && unmasked(j0 + c, r, ncr)) um |= 1u << c;
      }
    }
    if (doCol && anyv) {
      const float wr = rowVec[r] * INVREG - a;
      #pragma unroll
      for (int c = 0; c < 8; ++c) {
        if (um >> c & 1u) {
          float e2 = xv[c] + wr;
          float nm = fmaxf(cm[c], e2);
          cs[c] = cs[c] * __expf(cm[c] - nm) + __expf(e2 - nm);
          cm[c] = nm;
        }
      }
    }
    if (doRow) {
      float rm = NEGINF;
      if (anyv) {
        #pragma unroll
        for (int c = 0; c < 8; ++c) if (um >> c & 1u) rm = fmaxf(rm, xv[c] + wc[c]);
      }
      #pragma unroll
      for (int off = 16; off >= 1; off >>= 1) rm = fmaxf(rm, __shfl_xor(rm, off));
      float rs = 0.f;
      if (anyv && rm > NEGINF) {
        #pragma unroll
        for (int c = 0; c < 8; ++c) if (um >> c & 1u) rs += __expf(xv[c] + wc[c] - rm);
      }
      #pragma unroll
      for (int off = 16; off >= 1; off >>= 1) rs += __shfl_xor(rs, off);
      if (tc == 0) { rowPM[ct * NN + r] = rm; rowPS[ct * NN + r] = rs; }
    }
  }
  if (doCol) {
    __shared__ float shm[8][256];
    __shared__ float shs[8][256];
    #pragma unroll
    for (int c = 0; c < 8; ++c) { shm[tr][(tc << 3) + c] = cm[c]; shs[tr][(tc << 3) + c] = cs[c]; }
    __syncthreads();
    float m = NEGINF, s = 0.f;
    #pragma unroll
    for (int g = 0; g < 8; ++g) lse_merge(m, s, shm[g][tid], shs[g][tid]);
    const int j = cbase + tid;
    if (j <= NN) { colPM[rt * LDA + j] = m; colPS[rt * LDA + j] = s; }
  }
}

__device__ __forceinline__ float clamped_lse(float s, float m) {
  float lse = __logf(s + 1e-10f) + m;
  if (!(lse >= -1e6f)) lse = -1e6f;      /* catches -inf and NaN */
  else if (lse > 1e6f) lse = 1e6f;
  return lse;
}

__global__ void sink_combineA(const float* rowPM, const float* rowPS,
                              const float* colPM, const float* colPS,
                              float* uvec, float* utvec,
                              float* errP, const int* conv) {
  const int b = blockIdx.x;
  if (b < 16) {
    if (conv[0]) return;
    const int i = (b << 8) + threadIdx.x;
    float m = NEGINF, s = 0.f;
    for (int t = 0; t < 17; ++t) lse_merge(m, s, rowPM[t * NN + i], rowPS[t * NN + i]);
    float un = REGc * (-LOGN - clamped_lse(s, m));
    float d = fabsf(un - uvec[i]);
    uvec[i] = un;
    d = blockReduce256(d);
    if (threadIdx.x == 0) errP[b] = d;
  } else {
    if (conv[1]) return;
    const int j = ((b - 16) << 8) + threadIdx.x;
    float d = 0.f;
    if (j <= NN) {
      float m = NEGINF, s = 0.f;
      for (int t = 0; t < 16; ++t) lse_merge(m, s, colPM[t * LDA + j], colPS[t * LDA + j]);
      float un = REGc * (-LOGM - clamped_lse(s, m));
      d = fabsf(un - utvec[j]);
      utvec[j] = un;
    }
    d = blockReduce256(d);
    if (threadIdx.x == 0) errP[b] = d;
  }
}

__global__ void sink_combineB(const float* rowPM, const float* rowPS,
                              const float* colPM, const float* colPS,
                              float* vvec, float* vtvec,
                              const float* errP, const int* convCur, int* convNext) {
  if (blockIdx.x == 0 && threadIdx.x == 0) {
    float er = 0.f, ec = 0.f;
    for (int t = 0; t < 16; ++t) er += errP[t];
    for (int t = 16; t < 33; ++t) ec += errP[t];
    convNext[0] = convCur[0] | ((er < THRESHc) ? 1 : 0);
    convNext[1] = convCur[1] | ((ec < THRESHc) ? 1 : 0);
  }
  const int b = blockIdx.x;
  if (b < 16) {
    if (convCur[1]) return;
    const int i = (b << 8) + threadIdx.x;
    float m = NEGINF, s = 0.f;
    for (int t = 0; t < 17; ++t) lse_merge(m, s, rowPM[t * NN + i], rowPS[t * NN + i]);
    vtvec[i] = REGc * (-LOGN - clamped_lse(s, m));
  } else {
    if (convCur[0]) return;
    const int j = ((b - 16) << 8) + threadIdx.x;
    if (j <= NN) {
      float m = NEGINF, s = 0.f;
      for (int t = 0; t < 16; ++t) lse_merge(m, s, colPM[t * LDA + j], colPS[t * LDA + j]);
      vvec[j] = REGc * (-LOGM - clamped_lse(s, m));
    }
  }
}

/* ------- final pass 1: logit sums + masked label LSEs (row & col) ------- */
__global__ void final_pass(const u16* S, const float* vvec, const float* vtvec,
                           const float* misc, const int* is_nc,
                           float* rowLm, float* rowLs, float* rowGs,
                           float* colLm, float* colLs, float* colGs) {
  const float a = misc[1], scale = misc[0];
  const int ct = blockIdx.x, rt = blockIdx.y;
  const int tid = threadIdx.x;
  const int tc = tid & 31, tr = tid >> 5;
  const int cbase = ct << 8, r0 = rt << 8;
  const int j0 = cbase + (tc << 3);
  const bool anyv = (j0 <= NN);
  float wc[8]; unsigned jval = 0;
  #pragma unroll
  for (int c = 0; c < 8; ++c) {
    int j = j0 + c;
    wc[c] = 0.f;
    if (j <= NN) { jval |= 1u << c; wc[c] = vvec[j] * INVREG; }
  }
  float cLm[8], cLs[8], cGs[8];
  #pragma unroll
  for (int c = 0; c < 8; ++c) { cLm[c] = NEGINF; cLs[c] = 0.f; cGs[c] = 0.f; }
  for (int st = 0; st < 32; ++st) {
    const int r = r0 + (st << 3) + tr;
    float xv[8], lg[8]; unsigned um = 0;
    #pragma unroll
    for (int c = 0; c < 8; ++c) { xv[c] = 0.f; lg[c] = 0.f; }
    if (anyv) {
      float raw[8];
      Q q = *(const Q*)(S + (size_t)r * LDA + j0);
      unpack8h(q, raw);
      const bool ncr = (is_nc[r] != 0);
      const float vtr = vtvec[r] * INVREG;
      #pragma unroll
      for (int c = 0; c < 8; ++c) {
        if (!(jval >> c & 1u)) continue;
        xv[c] = raw[c] * a;
        lg[c] = scale * raw[c];
        cGs[c] += __expf(lg[c]);
        if (unmasked(j0 + c, r, ncr)) {
          um |= 1u << c;
          float e2 = xv[c] + vtr;
          float nm = fmaxf(cLm[c], e2);
          cLs[c] = cLs[c] * __expf(cLm[c] - nm) + __expf(e2 - nm);
          cLm[c] = nm;
        }
      }
    }
    float rsG = 0.f;
    if (anyv) {
      #pragma unroll
      for (int c = 0; c < 8; ++c) if (jval >> c & 1u) rsG += __expf(lg[c]);
    }
    #pragma unroll
    for (int off = 16; off >= 1; off >>= 1) rsG += __shfl_xor(rsG, off);
    float rmL = NEGINF;
    if (anyv) {
      #pragma unroll
      for (int c = 0; c < 8; ++c) if (um >> c & 1u) rmL = fmaxf(rmL, xv[c] + wc[c]);
    }
    #pragma unroll
    for (int off = 16; off >= 1; off >>= 1) rmL = fmaxf(rmL, __shfl_xor(rmL, off));
    float rsL = 0.f;
    if (anyv && rmL > NEGINF) {
      #pragma unroll
      for (int c = 0; c < 8; ++c) if (um >> c & 1u) rsL += __expf(xv[c] + wc[c] - rmL);
    }
    #pragma unroll
    for (int off = 16; off >= 1; off >>= 1) rsL += __shfl_xor(rsL, off);
    if (tc == 0) {
      rowGs[ct * NN + r] = rsG;
      rowLm[ct * NN + r] = rmL;
      rowLs[ct * NN + r] = rsL;
    }
  }
  __shared__ float shm[8][256];
  __shared__ float shs[8][256];
  #pragma unroll
  for (int c = 0; c < 8; ++c) { shm[tr][(tc << 3) + c] = cLm[c]; shs[tr][(tc << 3) + c] = cLs[c]; }
  __syncthreads();
  {
    float m = NEGINF, s = 0.f;
    #pragma unroll
    for (int g = 0; g < 8; ++g) lse_merge(m, s, shm[g][tid], shs[g][tid]);
    const int j = cbase + tid;
    if (j <= NN) { colLm[rt * LDA + j] = m; colLs[rt * LDA + j] = s; }
  }
  __syncthreads();
  #pragma unroll
  for (int c = 0; c < 8; ++c) shs[tr][(tc << 3) + c] = cGs[c];
  __syncthreads();
  {
    float s = 0.f;
    #pragma unroll
    for (int g = 0; g < 8; ++g) s += shs[g][tid];
    const int j = cbase + tid;
    if (j <= NN) colGs[rt * LDA + j] = s;
  }
}

__global__ void final_combine(const float* rowLm, const float* rowLs, const float* rowGs,
                              const float* colLm, const float* colLs, const float* colGs,
                              float* LSMrow, float* LBLm, float* LBLs,
                              float* LSMcol, float* LBTm, float* LBTs) {
  const int b = blockIdx.x;
  if (b < 16) {
    const int i = (b << 8) + threadIdx.x;
    float m = NEGINF, s = 0.f, sg = 0.f;
    for (int t = 0; t < 17; ++t) {
      lse_merge(m, s, rowLm[t * NN + i], rowLs[t * NN + i]);
      sg += rowGs[t * NN + i];
    }
    LBLm[i] = m; LBLs[i] = s;
    LSMrow[i] = __logf(sg);
  } else {
    const int j = ((b - 16) << 8) + threadIdx.x;
    if (j <= NN) {
      float m = NEGINF, s = 0.f, sg = 0.f;
      for (int t = 0; t < 16; ++t) {
        lse_merge(m, s, colLm[t * LDA + j], colLs[t * LDA + j]);
        sg += colGs[t * LDA + j];
      }
      LBTm[j] = m; LBTs[j] = s;
      LSMcol[j] = __logf(sg);
    }
  }
}

/* ------- final pass 2: KL sums for both orientations ------- */
__global__ void loss_pass(const u16* S, const float* vvec, const float* vtvec,
                          const float* misc, const int* is_nc,
                          const float* LSMrow, const float* LBLm, const float* LBLs,
                          const float* LSMcol, const float* LBTm, const float* LBTs,
                          float* imgP, float* txtP) {
  const float a = misc[1], scale = misc[0];
  const int ct = blockIdx.x, rt = blockIdx.y;
  const int tid = threadIdx.x;
  const int tc = tid & 31, tr = tid >> 5;
  const int cbase = ct << 8, r0 = rt << 8;
  const int j0 = cbase + (tc << 3);
  const bool anyv = (j0 <= NN);
  float vcw[8], bm[8], bsi[8], cg[8]; unsigned jval = 0;
  #pragma unroll
  for (int c = 0; c < 8; ++c) {
    int j = j0 + c;
    vcw[c] = 0.f; bm[c] = 0.f; bsi[c] = 0.f; cg[c] = 0.f;
    if (j <= NN) {
      jval |= 1u << c;
      vcw[c] = vvec[j] * INVREG; bm[c] = LBTm[j]; bsi[c] = 1.f / LBTs[j]; cg[c] = LSMcol[j];
    }
  }
  float sImg = 0.f, sTxt = 0.f;
  for (int st = 0; st < 32; ++st) {
    const int r = r0 + (st << 3) + tr;
    if (anyv) {
      float raw[8];
      Q q = *(const Q*)(S + (size_t)r * LDA + j0);
      unpack8h(q, raw);
      const bool ncr = (is_nc[r] != 0);
      const float vtr = vtvec[r] * INVREG;
      const float rm = LBLm[r], rsi = 1.f / LBLs[r], rg = LSMrow[r];
      #pragma unroll
      for (int c = 0; c < 8; ++c) {
        if (!(jval >> c & 1u)) continue;
        const int j = j0 + c;
        float xv = raw[c] * a;
        float lgt = scale * raw[c];
        bool unm = unmasked(j, r, ncr);
        bool lv = (j == NN) ? ncr : ((j == r) && !ncr);
        float rr = unm ? __expf(xv + vcw[c] - rm) * rsi : 0.f;
        float t = GAM * rr + (lv ? 0.2f : 0.f);
        if (t > 0.f) sImg += t * (__logf(t) - (lgt - rg));
        float r2 = unm ? __expf(xv + vtr - bm[c]) * bsi[c] : 0.f;
        float t2 = GAM * r2 + (lv ? 0.2f : 0.f);
        if (t2 > 0.f) sTxt += t2 * (__logf(t2) - (lgt - cg[c]));
      }
    }
  }
  sImg = blockReduce256(sImg);
  sTxt = blockReduce256(sTxt);
  if (tid == 0) { imgP[rt * 17 + ct] = sImg; txtP[rt * 17 + ct] = sTxt; }
}

/* ------- validate: report first non-finite stage as code in misc[12] ------- */
__global__ void validate_kernel(const u16* S, float* misc,
                                const float* preds, const int* is_nc,
                                const float* uvec, const float* vvec,
                                const float* utvec, const float* vtvec,
                                const float* LBLm, const float* LBLs,
                                const float* LBTm, const float* LBTs,
                                const float* LSMrow, const float* LSMcol,
                                const float* imgP, const float* txtP) {
  __shared__ float sc[2];
  const int tid = threadIdx.x;
  if (tid == 0) { sc[0] = 0.f; sc[1] = 0.f; }
  __syncthreads();
  float cnt;
  /* 100: inf/NaN in fp16 S (sampled stride 7) */
  cnt = 0.f;
  for (int r = tid; r < NN; r += 256) {
    const u16* Sr = S + (size_t)r * LDA;
    for (int j = 0; j <= NN; j += 7)
      if ((Sr[j] & 0x7C00u) == 0x7C00u) cnt += 1.f;
  }
  cnt = blockReduce256(cnt);
  if (tid == 0 && sc[0] == 0.f && cnt > 0.f) { sc[0] = 100.f; sc[1] = cnt; }
  __syncthreads();
  if (tid == 0) {
    if (sc[0] == 0.f && (fbad(misc[1]) || misc[1] <= 0.f)) { sc[0] = 101.f; sc[1] = misc[1]; }
    if (sc[0] == 0.f && (fbad(misc[0]) || misc[0] <= 0.f)) { sc[0] = 102.f; sc[1] = misc[0]; }
  }
  __syncthreads();
  cnt = 0.f;
  for (int i = tid; i < NN; i += 256) if (fbad(preds[i])) cnt += 1.f;
  cnt = blockReduce256(cnt);
  if (tid == 0 && sc[0] == 0.f && cnt > 0.f) { sc[0] = 103.f; sc[1] = cnt; }
  __syncthreads();
  cnt = 0.f;
  for (int i = tid; i < NN; i += 256) cnt += (float)is_nc[i];
  cnt = blockReduce256(cnt);
  if (tid == 0 && sc[0] == 0.f && cnt != 409.f) { sc[0] = 104.f; sc[1] = cnt; }
  __syncthreads();
  cnt = 0.f;
  for (int i = tid; i < NN; i += 256) if (fbad(uvec[i])) cnt += 1.f;
  cnt = blockReduce256(cnt);
  if (tid == 0 && sc[0] == 0.f && cnt > 0.f) { sc[0] = 105.f; sc[1] = cnt; }
  __syncthreads();
  cnt = 0.f;
  for (int i = tid; i <= NN; i += 256) if (fbad(vvec[i])) cnt += 1.f;
  cnt = blockReduce256(cnt);
  if (tid == 0 && sc[0] == 0.f && cnt > 0.f) { sc[0] = 106.f; sc[1] = cnt; }
  __syncthreads();
  cnt = 0.f;
  for (int i = tid; i <= NN; i += 256) if (fbad(utvec[i])) cnt += 1.f;
  cnt = blockReduce256(cnt);
  if (tid == 0 && sc[0] == 0.f && cnt > 0.f) { sc[0] = 107.f; sc[1] = cnt; }
  __syncthreads();
  cnt = 0.f;
  for (int i = tid; i < NN; i += 256) if (fbad(vtvec[i])) cnt += 1.f;
  cnt = blockReduce256(cnt);
  if (tid == 0 && sc[0] == 0.f && cnt > 0.f) { sc[0] = 108.f; sc[1] = cnt; }
  __syncthreads();
  cnt = 0.f;
  for (int i = tid; i < NN; i += 256) if (fbad(LBLm[i])) cnt += 1.f;
  cnt = blockReduce256(cnt);
  if (tid == 0 && sc[0] == 0.f && cnt > 0.f) { sc[0] = 109.f; sc[1] = cnt; }
  __syncthreads();
  cnt = 0.f;
  for (int i = tid; i < NN; i += 256) if (fbad(LBLs[i]) || LBLs[i] <= 0.f) cnt += 1.f;
  cnt = blockReduce256(cnt);
  if (tid == 0 && sc[0] == 0.f && cnt > 0.f) { sc[0] = 110.f; sc[1] = cnt; }
  __syncthreads();
  cnt = 0.f;
  for (int i = tid; i <= NN; i += 256) if (fbad(LBTm[i])) cnt += 1.f;
  cnt = blockReduce256(cnt);
  if (tid == 0 && sc[0] == 0.f && cnt > 0.f) { sc[0] = 111.f; sc[1] = cnt; }
  __syncthreads();
  cnt = 0.f;
  for (int i = tid; i <= NN; i += 256) if (fbad(LBTs[i]) || LBTs[i] <= 0.f) cnt += 1.f;
  cnt = blockReduce256(cnt);
  if (tid == 0 && sc[0] == 0.f && cnt > 0.f) { sc[0] = 112.f; sc[1] = cnt; }
  __syncthreads();
  cnt = 0.f;
  for (int i = tid; i < NN; i += 256) if (fbad(LSMrow[i])) cnt += 1.f;
  cnt = blockReduce256(cnt);
  if (tid == 0 && sc[0] == 0.f && cnt > 0.f) { sc[0] = 113.f; sc[1] = cnt; }
  __syncthreads();
  cnt = 0.f;
  for (int i = tid; i <= NN; i += 256) if (fbad(LSMcol[i])) cnt += 1.f;
  cnt = blockReduce256(cnt);
  if (tid == 0 && sc[0] == 0.f && cnt > 0.f) { sc[0] = 114.f; sc[1] = cnt; }
  __syncthreads();
  cnt = 0.f;
  for (int i = tid; i < 272; i += 256) if (fbad(imgP[i]) || fbad(txtP[i])) cnt += 1.f;
  cnt = blockReduce256(cnt);
  if (tid == 0 && sc[0] == 0.f && cnt > 0.f) { sc[0] = 115.f; sc[1] = cnt; }
  __syncthreads();
  if (tid == 0) { misc[12] = sc[0]; misc[13] = sc[1]; }
}

__global__ void finish_kernel(const float* imgP, const float* txtP,
                              const float* misc, float* out) {
  float vi = 0.f, vtx = 0.f;
  for (int idx = threadIdx.x; idx < 272; idx += 256) { vi += imgP[idx]; vtx += txtP[idx]; }
  vi = blockReduce256(vi);
  vtx = blockReduce256(vtx);
  if (threadIdx.x == 0) {
    if (misc[12] != 0.f) { out[0] = misc[12]; out[1] = misc[13]; return; }
    float loss_img = vi / 4096.0f;
    float loss_txt = vtx / 4097.0f;
    float loss_ul = 0.5f * (loss_img + loss_txt);
    float loss_op = misc[4] / 4096.0f;
    if (vi == 0.f && vtx == 0.f) loss_ul = 777.0f;
    if (!(loss_ul == loss_ul))   loss_ul = 888.0f;
    out[0] = loss_ul;
    out[1] = loss_op;
  }
}

extern "C" void kernel_launch(void* const* d_in, const int* in_sizes, int n_in,
                              void* d_out, int out_size, void* d_ws, size_t ws_size,
                              hipStream_t stream) {
  (void)in_sizes; (void)n_in; (void)out_size;
  const u16* img = (const u16*)d_in[0];
  const u16* txt = (const u16*)d_in[1];
  const u16* tno = (const u16*)d_in[2];
  const u16* ls  = (const u16*)d_in[3];
  float* out = (float*)d_out;

  ContrastiveLoss_83391085019222_kernel<<<1, 64, 0, stream>>>(out);

  size_t off = 0;
  char* w = (char*)d_ws;
  u16* S; float *rowPM, *rowPS, *rowGs, *colPM, *colPS, *colGs;
  float *vecs, *preds, *colvals, *gmin, *opP, *errP;
  float *LSMrow, *LBLm, *LBLs, *LSMcol, *LBTm, *LBTs, *imgP, *txtP, *misc;
  int* is_nc;
  #define ALLOC(ptr, type, nbytes) ptr = (type)(w + off); off = (off + (size_t)(nbytes) + 255) & ~(size_t)255
  ALLOC(S,      u16*,   (size_t)NN * LDA * 2);
  ALLOC(rowPM,  float*, (size_t)17 * NN * 4);
  ALLOC(rowPS,  float*, (size_t)17 * NN * 4);
  ALLOC(rowGs,  float*, (size_t)17 * NN * 4);
  ALLOC(colPM,  float*, (size_t)16 * LDA * 4);
  ALLOC(colPS,  float*, (size_t)16 * LDA * 4);
  ALLOC(colGs,  float*, (size_t)16 * LDA * 4);
  ALLOC(vecs,   float*, 16400 * 4);
  ALLOC(preds,  float*, NN * 4);
  ALLOC(is_nc,  int*,   NN * 4);
  ALLOC(colvals,float*, NN * 4);
  ALLOC(gmin,   float*, 4096 * 4);
  ALLOC(opP,    float*, 1024 * 4);
  ALLOC(errP,   float*, 33 * 4);
  ALLOC(LSMrow, float*, NN * 4);
  ALLOC(LBLm,   float*, NN * 4);
  ALLOC(LBLs,   float*, NN * 4);
  ALLOC(LSMcol, float*, LDA * 4);
  ALLOC(LBTm,   float*, LDA * 4);
  ALLOC(LBTs,   float*, LDA * 4);
  ALLOC(imgP,   float*, 272 * 4);
  ALLOC(txtP,   float*, 272 * 4);
  ALLOC(misc,   float*, 64);
  #undef ALLOC

  if (ws_size < off) {
    diag_kernel<<<1, 64, 0, stream>>>(out, -(float)(ws_size / 1000000.0),
                                      -(float)(off / 1000000.0));
    return;
  }

  float* uvec  = vecs;
  float* vvec  = vecs + 4096;
  float* utvec = vecs + 8200;
  float* vtvec = vecs + 12304;
  int* flags = (int*)misc + 6;

  detect_kernel<<<1, 64, 0, stream>>>(img, misc);
  init_kernel<<<65, 256, 0, stream>>>(ls, vecs, misc);
  gemm_kernel<<<dim3(64, 64), 256, 0, stream>>>(img, txt, S, gmin, misc);
  colvec_kernel<<<1024, 256, 0, stream>>>(img, txt, tno, colvals, opP, misc);
  scatter_col<<<16, 256, 0, stream>>>(S, colvals);
  reduce_kernel<<<1, 256, 0, stream>>>(gmin, colvals, opP, misc);

  preds_kernel<<<1024, 256, 0, stream>>>(S, misc, preds);
  rank_kernel<<<32, 128, 0, stream>>>(preds, is_nc);

  for (int k = 0; k < 100; ++k) {
    const int* cc = flags + 2 * (k & 1);
    int* cn = flags + 2 * ((k + 1) & 1);
    sink_pass<<<dim3(17, 16), 256, 0, stream>>>(S, vvec, vtvec, misc, cc, 0, 1, is_nc,
                                                rowPM, rowPS, colPM, colPS);
    sink_combineA<<<33, 256, 0, stream>>>(rowPM, rowPS, colPM, colPS, uvec, utvec, errP, cc);
    sink_pass<<<dim3(17, 16), 256, 0, stream>>>(S, utvec, uvec, misc, cc, 1, 0, is_nc,
                                                rowPM, rowPS, colPM, colPS);
    sink_combineB<<<33, 256, 0, stream>>>(rowPM, rowPS, colPM, colPS, vvec, vtvec, errP, cc, cn);
  }

  final_pass<<<dim3(17, 16), 256, 0, stream>>>(S, vvec, vtvec, misc, is_nc,
                                               rowPM, rowPS, rowGs, colPM, colPS, colGs);
  final_combine<<<33, 256, 0, stream>>>(rowPM, rowPS, rowGs, colPM, colPS, colGs,
                                        LSMrow, LBLm, LBLs, LSMcol, LBTm, LBTs);
  loss_pass<<<dim3(17, 16), 256, 0, stream>>>(S, vvec, vtvec, misc, is_nc,
                                              LSMrow, LBLm, LBLs, LSMcol, LBTm, LBTs, imgP, txtP);
  validate_kernel<<<1, 256, 0, stream>>>(S, misc, preds, is_nc, uvec, vvec, utvec, vtvec,
                                         LBLm, LBLs, LBTm, LBTs, LSMrow, LSMcol, imgP, txtP);
  finish_kernel<<<1, 256, 0, stream>>>(imgP, txtP, misc, out);
}


// Round 16
// 1607.814 us; speedup vs baseline: 2.6011x; 2.6011x over previous
//

#include <hip/hip_runtime.h>
#include <hip/hip_bf16.h>

// ROUND 16 (first optimization round; round 15 passed, 4182 us, absmax 0.0):
//  - sink_pass: exp-once restructure (E=exp(a*S) shared by row & col paths,
//    plain-sum partials, no online max -- exponents provably bounded << 88),
//    retiled 128x128 -> grid(33,32)=1056 blocks (~4 blocks/CU vs 1.06).
//  - hardware _Float16 conversions replace the ~10-op software h2f/f2h.
//  - validate_kernel removed (debug-only).

#define NN 4096
#define LDA 4104          /* fp16 row stride for S (4097 padded to x8) */
#define DD 512
#define NCNUM 409         /* int(0.1*4096) */
#define REGc 0.03f
#define INVREG (1.0f/0.03f)
#define GAM 0.8f
#define THRESHc 1e-4f
#define LOGN 8.3177661667193433f   /* ln(4096) */
#define LOGM 8.3180102775477533f   /* ln(4097) */
#define NEGINF (-__builtin_inff())
#define CTILES 33                  /* ceil(4097/128) col tiles for sinkhorn */
#define RTILES 32                  /* 4096/128 row tiles */

typedef unsigned short u16;
typedef unsigned int u32;
typedef _Float16 f16;

struct alignas(16) Q  { u32 x, y, z, w; };
struct alignas(8)  Q2 { u32 x, y; };
struct alignas(16) F4 { float a, b, c, d; };
union H8 { Q q; f16 h[8]; };

__device__ __forceinline__ float bf2f(u32 u) { return __uint_as_float(u << 16); }
__device__ __forceinline__ float bflo(u32 w) { return __uint_as_float(w << 16); }
__device__ __forceinline__ float bfhi(u32 w) { return __uint_as_float(w & 0xFFFF0000u); }
__device__ __forceinline__ u16 f2h_hw(float f) {
  union { f16 h; u16 u; } X; X.h = (f16)f; return X.u;
}
__device__ __forceinline__ float h2f_hw(u16 v) {
  union { u16 u; f16 h; } X; X.u = v; return (float)X.h;
}
__device__ __forceinline__ void unpack8(Q q, float* x) {
  H8 u; u.q = q;
  #pragma unroll
  for (int c = 0; c < 8; ++c) x[c] = (float)u.h[c];
}
__device__ __forceinline__ void lse_merge(float& m, float& s, float om, float os) {
  float nm = fmaxf(m, om);
  if (nm == NEGINF) return;
  float acc = 0.f;
  if (s  > 0.f) acc += s  * __expf(m  - nm);
  if (os > 0.f) acc += os * __expf(om - nm);
  m = nm; s = acc;
}
__device__ __forceinline__ float blockReduce256(float v) {
  __shared__ float sh[4];
  #pragma unroll
  for (int off = 32; off >= 1; off >>= 1) v += __shfl_xor(v, off);
  int w = threadIdx.x >> 6;
  if ((threadIdx.x & 63) == 0) sh[w] = v;
  __syncthreads();
  float r = 0.f;
  if (threadIdx.x == 0) r = sh[0] + sh[1] + sh[2] + sh[3];
  __syncthreads();
  return r;
}

__global__ void ContrastiveLoss_83391085019222_kernel(float* out) {
  if (threadIdx.x == 0) { out[0] = 0.5f; out[1] = 0.5f; }
}
__global__ void diag_kernel(float* out, float a, float b) {
  if (threadIdx.x == 0) { out[0] = a; out[1] = b; }
}

/* ---- dtype autodetect: inputs are unit-normalized rows ---- */
__global__ void detect_kernel(const u16* img, float* misc) {
  const int lane = threadIdx.x;  /* 64 */
  float nb = 0.f, nf = 0.f;
  const float* fimg = (const float*)img;
  for (int c = lane * 8; c < lane * 8 + 8; ++c) {
    float xb = bf2f((u32)img[c]);
    nb += xb * xb;
    float xf = fimg[c];
    if (fabsf(xf) < 1e10f) nf += xf * xf; else nf += 1e10f;
  }
  #pragma unroll
  for (int off = 32; off >= 1; off >>= 1) { nb += __shfl_xor(nb, off); nf += __shfl_xor(nf, off); }
  if (lane == 0) {
    float db = fabsf(nb - 1.f);
    float df = fabsf(nf - 1.f);
    if (!(db == db)) db = 1e30f;
    if (!(df == df)) df = 1e30f;
    ((int*)misc)[10] = (df < db) ? 1 : 0;   /* 1 = float32 inputs */
  }
}

__global__ void init_kernel(const u16* ls, float* vecs, float* misc) {
  int t = blockIdx.x * 256 + threadIdx.x;
  if (t < 16400) vecs[t] = 0.f;
  if (t == 0) {
    const int isF = ((const int*)misc)[10];
    float lsv = isF ? ((const float*)ls)[0] : bf2f((u32)ls[0]);
    misc[0] = __expf(lsv);               /* scale = exp(logit_scale) */
    int* f = (int*)misc + 6;
    f[0] = 0; f[1] = 0; f[2] = 0; f[3] = 0;
  }
}

/* ------- GEMM: S[i,j] = dot(img_i, txt_j) -> fp16 bits + per-block min ------- */
__global__ void gemm_kernel(const u16* A, const u16* B, u16* S, float* gmin,
                            const float* misc) {
  __shared__ float As[64 * 20];
  __shared__ float Bs[64 * 20];
  __shared__ float red[256];
  const int isF = ((const int*)misc)[10];
  const int tid = threadIdx.x;
  const int tx = tid & 15, ty = tid >> 4;
  const int rb = (int)blockIdx.y << 6, cb = (int)blockIdx.x << 6;
  const int lrow = tid >> 2;
  const int lchunk = (tid & 3) << 2;
  float acc[4][4];
  #pragma unroll
  for (int r = 0; r < 4; ++r)
    #pragma unroll
    for (int c = 0; c < 4; ++c) acc[r][c] = 0.f;
  for (int kt = 0; kt < DD; kt += 16) {
    float v0, v1, v2, v3, w0, w1, w2, w3;
    if (isF) {
      const float* Af = (const float*)A;
      const float* Bf = (const float*)B;
      F4 a4 = *(const F4*)(Af + (size_t)(rb + lrow) * DD + kt + lchunk);
      F4 b4 = *(const F4*)(Bf + (size_t)(cb + lrow) * DD + kt + lchunk);
      v0 = a4.a; v1 = a4.b; v2 = a4.c; v3 = a4.d;
      w0 = b4.a; w1 = b4.b; w2 = b4.c; w3 = b4.d;
    } else {
      Q2 a2 = *(const Q2*)(A + (size_t)(rb + lrow) * DD + kt + lchunk);
      Q2 b2 = *(const Q2*)(B + (size_t)(cb + lrow) * DD + kt + lchunk);
      v0 = bflo(a2.x); v1 = bfhi(a2.x); v2 = bflo(a2.y); v3 = bfhi(a2.y);
      w0 = bflo(b2.x); w1 = bfhi(b2.x); w2 = bflo(b2.y); w3 = bfhi(b2.y);
    }
    __syncthreads();
    As[lrow*20 + lchunk + 0] = v0; As[lrow*20 + lchunk + 1] = v1;
    As[lrow*20 + lchunk + 2] = v2; As[lrow*20 + lchunk + 3] = v3;
    Bs[lrow*20 + lchunk + 0] = w0; Bs[lrow*20 + lchunk + 1] = w1;
    Bs[lrow*20 + lchunk + 2] = w2; Bs[lrow*20 + lchunk + 3] = w3;
    __syncthreads();
    #pragma unroll
    for (int k = 0; k < 16; k += 4) {
      F4 aF[4], bF[4];
      #pragma unroll
      for (int r = 0; r < 4; ++r) aF[r] = *(const F4*)&As[(ty*4 + r)*20 + k];
      #pragma unroll
      for (int c = 0; c < 4; ++c) bF[c] = *(const F4*)&Bs[(tx*4 + c)*20 + k];
      #pragma unroll
      for (int r = 0; r < 4; ++r)
        #pragma unroll
        for (int c = 0; c < 4; ++c) {
          acc[r][c] = fmaf(aF[r].a, bF[c].a, acc[r][c]);
          acc[r][c] = fmaf(aF[r].b, bF[c].b, acc[r][c]);
          acc[r][c] = fmaf(aF[r].c, bF[c].c, acc[r][c]);
          acc[r][c] = fmaf(aF[r].d, bF[c].d, acc[r][c]);
        }
    }
  }
  float lmin = 1e30f;
  #pragma unroll
  for (int r = 0; r < 4; ++r) {
    u16 h0 = f2h_hw(acc[r][0]), h1 = f2h_hw(acc[r][1]);
    u16 h2 = f2h_hw(acc[r][2]), h3 = f2h_hw(acc[r][3]);
    lmin = fminf(lmin, h2f_hw(h0)); lmin = fminf(lmin, h2f_hw(h1));
    lmin = fminf(lmin, h2f_hw(h2)); lmin = fminf(lmin, h2f_hw(h3));
    Q2 o; o.x = (u32)h0 | ((u32)h1 << 16); o.y = (u32)h2 | ((u32)h3 << 16);
    *(Q2*)(S + (size_t)(rb + ty*4 + r) * LDA + cb + tx*4) = o;
  }
  red[tid] = lmin;
  __syncthreads();
  for (int sN = 128; sN >= 1; sN >>= 1) {
    if (tid < sN) red[tid] = fminf(red[tid], red[tid + sN]);
    __syncthreads();
  }
  if (tid == 0) gmin[blockIdx.y * 64 + blockIdx.x] = red[0];
}

/* ------- sims_no values (fp32) + per-block loss_op partial ------- */
__global__ void colvec_kernel(const u16* img, const u16* txt, const u16* tno,
                              float* colvals, float* opP, const float* misc) {
  __shared__ float shOp[4];
  const int isF = ((const int*)misc)[10];
  const int wv = threadIdx.x >> 6;
  const int row = (int)(blockIdx.x << 2) + wv;
  const int lane = threadIdx.x & 63;
  const size_t base = (size_t)row * DD + lane * 8;
  float xi[8], xt[8], xn[8];
  if (isF) {
    const float* fi = (const float*)img;
    const float* ft = (const float*)txt;
    const float* fn = (const float*)tno;
    #pragma unroll
    for (int c = 0; c < 8; ++c) { xi[c] = fi[base+c]; xt[c] = ft[base+c]; xn[c] = fn[base+c]; }
  } else {
    Q qi = *(const Q*)(img + base);
    Q qt = *(const Q*)(txt + base);
    Q qn = *(const Q*)(tno + base);
    xi[0]=bflo(qi.x); xi[1]=bfhi(qi.x); xi[2]=bflo(qi.y); xi[3]=bfhi(qi.y);
    xi[4]=bflo(qi.z); xi[5]=bfhi(qi.z); xi[6]=bflo(qi.w); xi[7]=bfhi(qi.w);
    xt[0]=bflo(qt.x); xt[1]=bfhi(qt.x); xt[2]=bflo(qt.y); xt[3]=bfhi(qt.y);
    xt[4]=bflo(qt.z); xt[5]=bfhi(qt.z); xt[6]=bflo(qt.w); xt[7]=bfhi(qt.w);
    xn[0]=bflo(qn.x); xn[1]=bfhi(qn.x); xn[2]=bflo(qn.y); xn[3]=bfhi(qn.y);
    xn[4]=bflo(qn.z); xn[5]=bfhi(qn.z); xn[6]=bflo(qn.w); xn[7]=bfhi(qn.w);
  }
  float sn = 0.f, cs = 0.f;
  #pragma unroll
  for (int c = 0; c < 8; ++c) { sn += xi[c]*xn[c]; cs += xt[c]*xn[c]; }
  #pragma unroll
  for (int off = 32; off >= 1; off >>= 1) { sn += __shfl_xor(sn, off); cs += __shfl_xor(cs, off); }
  if (lane == 0) {
    colvals[row] = sn;
    shOp[wv] = fmaxf(cs + 0.2f, 0.f) + fmaxf(-0.7f - cs, 0.f);
  }
  __syncthreads();
  if (threadIdx.x == 0) opP[blockIdx.x] = shOp[0] + shOp[1] + shOp[2] + shOp[3];
}

__global__ void scatter_col(u16* S, const float* colvals) {
  int r = blockIdx.x * 256 + threadIdx.x;
  if (r < NN) S[(size_t)r * LDA + NN] = f2h_hw(colvals[r]);
}

__global__ void reduce_kernel(const float* gmin, const float* colvals,
                              const float* opP, float* misc) {
  __shared__ float smin[256];
  __shared__ float ssum[256];
  float mn = 1e30f, sm = 0.f;
  for (int i = threadIdx.x; i < 4096; i += 256) {
    mn = fminf(mn, gmin[i]);
    mn = fminf(mn, h2f_hw(f2h_hw(colvals[i])));
  }
  for (int i = threadIdx.x; i < 1024; i += 256) sm += opP[i];
  smin[threadIdx.x] = mn; ssum[threadIdx.x] = sm;
  __syncthreads();
  for (int sN = 128; sN >= 1; sN >>= 1) {
    if (threadIdx.x < sN) {
      smin[threadIdx.x] = fminf(smin[threadIdx.x], smin[threadIdx.x + sN]);
      ssum[threadIdx.x] += ssum[threadIdx.x + sN];
    }
    __syncthreads();
  }
  if (threadIdx.x == 0) {
    float maxC = 1.0f - smin[0];         /* max(1-S) = 1 - min(S) */
    misc[1] = 1.0f / (maxC * REGc);      /* a */
    misc[4] = ssum[0];
  }
}

__global__ void preds_kernel(const u16* S, const float* misc, float* preds) {
  const int row = (int)(blockIdx.x << 2) + (int)(threadIdx.x >> 6);
  const int lane = threadIdx.x & 63;
  const float scale = misc[0];
  const u16* Sr = S + (size_t)row * LDA;
  float m = NEGINF, s = 0.f;
  for (int it = 0; it < 8; ++it) {
    const int j0 = (it << 9) + (lane << 3);
    float x[8];
    unpack8(*(const Q*)(Sr + j0), x);
    float lm = NEGINF;
    #pragma unroll
    for (int c = 0; c < 8; ++c) { x[c] *= scale; lm = fmaxf(lm, x[c]); }
    float lsum = 0.f;
    #pragma unroll
    for (int c = 0; c < 8; ++c) lsum += __expf(x[c] - lm);
    lse_merge(m, s, lm, lsum);
  }
  #pragma unroll
  for (int off = 32; off >= 1; off >>= 1) {
    float om = __shfl_xor(m, off), os = __shfl_xor(s, off);
    lse_merge(m, s, om, os);
  }
  if (lane == 0) {
    float sii = h2f_hw(Sr[row]);
    preds[row] = __expf(scale * sii - m) / s;
  }
}

__global__ void rank_kernel(const float* preds, int* is_nc) {
  __shared__ float sp[NN];
  for (int idx = threadIdx.x; idx < NN; idx += 128) sp[idx] = preds[idx];
  __syncthreads();
  const int i = blockIdx.x * 128 + threadIdx.x;
  const float pv = sp[i];
  int cnt = 0;
  for (int k2 = 0; k2 < NN; ++k2) {
    float pk = sp[k2];
    cnt += (pk < pv || (pk == pv && k2 < i)) ? 1 : 0;
  }
  is_nc[i] = (cnt < NCNUM) ? 1 : 0;
}

__device__ __forceinline__ bool unmasked(int j, int r, bool ncr) {
  return (j == NN) ? ncr : !((j == r) && ncr);
}

/* ------- sinkhorn pass, exp-once / plain-sum form, 128x128 tiles -------
   rowP[ct][r] = sum_j E(r,j)*exp(colVec[j]/REG - a)   (masked)
   colP[rt][j] = sum_r E(r,j)*exp(rowVec[r]/REG - a)   (masked)
   where E = exp(a*S). Exponents bounded (|.| < ~45 << 88): no max needed. */
__global__ void sink_pass(const u16* S, const float* colVec, const float* rowVec,
                          const float* misc, const int* conv,
                          int rowGate, int colGate, const int* is_nc,
                          float* rowP, float* colP) {
  const bool doRow = (conv[rowGate] == 0);
  const bool doCol = (conv[colGate] == 0);
  if (!doRow && !doCol) return;
  const float a = misc[1];
  const int ct = blockIdx.x, rt = blockIdx.y;
  const int tid = threadIdx.x;
  const int tc = tid & 15, tr = tid >> 4;     /* 16 col-groups x 16 rows/step */
  const int cbase = ct << 7, r0 = rt << 7;
  const int j0 = cbase + (tc << 3);
  const bool anyv = (j0 <= NN);
  float Wc[8]; unsigned jval = 0;
  #pragma unroll
  for (int c = 0; c < 8; ++c) {
    int j = j0 + c;
    Wc[c] = 0.f;
    if (j <= NN) { jval |= 1u << c; Wc[c] = __expf(colVec[j] * INVREG - a); }
  }
  float cs[8];
  #pragma unroll
  for (int c = 0; c < 8; ++c) cs[c] = 0.f;

  for (int st = 0; st < 8; ++st) {
    const int r = r0 + (st << 4) + tr;
    float E[8];
    if (anyv) {
      float xv[8];
      unpack8(*(const Q*)(S + (size_t)r * LDA + j0), xv);
      const bool ncr = (is_nc[r] != 0);
      #pragma unroll
      for (int c = 0; c < 8; ++c) {
        E[c] = __expf(xv[c] * a);
        if (!((jval >> c & 1u) && unmasked(j0 + c, r, ncr))) E[c] = 0.f;
      }
    } else {
      #pragma unroll
      for (int c = 0; c < 8; ++c) E[c] = 0.f;
    }
    if (doCol) {
      float Wr = __expf(rowVec[r] * INVREG - a);
      #pragma unroll
      for (int c = 0; c < 8; ++c) cs[c] = fmaf(E[c], Wr, cs[c]);
    }
    if (doRow) {
      float rs = 0.f;
      #pragma unroll
      for (int c = 0; c < 8; ++c) rs = fmaf(E[c], Wc[c], rs);
      #pragma unroll
      for (int off = 8; off >= 1; off >>= 1) rs += __shfl_xor(rs, off);
      if (tc == 0) rowP[ct * NN + r] = rs;
    }
  }
  if (doCol) {
    __shared__ float sh[16][128];
    #pragma unroll
    for (int c = 0; c < 8; ++c) sh[tr][(tc << 3) + c] = cs[c];
    __syncthreads();
    if (tid < 128) {
      float s = 0.f;
      #pragma unroll
      for (int g = 0; g < 16; ++g) s += sh[g][tid];
      const int j = cbase + tid;
      if (j <= NN) colP[rt * LDA + j] = s;
    }
  }
}

__global__ void sink_combineA(const float* rowP, const float* colP,
                              float* uvec, float* utvec,
                              float* errP, const int* conv) {
  const int b = blockIdx.x;
  if (b < 16) {
    if (conv[0]) return;
    const int i = (b << 8) + threadIdx.x;
    float s = 0.f;
    for (int t = 0; t < CTILES; ++t) s += rowP[t * NN + i];
    float un = REGc * (-LOGN - __logf(fmaxf(s, 1e-30f)));
    float d = fabsf(un - uvec[i]);
    uvec[i] = un;
    d = blockReduce256(d);
    if (threadIdx.x == 0) errP[b] = d;
  } else {
    if (conv[1]) return;
    const int j = ((b - 16) << 8) + threadIdx.x;
    float d = 0.f;
    if (j <= NN) {
      float s = 0.f;
      for (int t = 0; t < RTILES; ++t) s += colP[t * LDA + j];
      float un = REGc * (-LOGM - __logf(fmaxf(s, 1e-30f)));
      d = fabsf(un - utvec[j]);
      utvec[j] = un;
    }
    d = blockReduce256(d);
    if (threadIdx.x == 0) errP[b] = d;
  }
}

__global__ void sink_combineB(const float* rowP, const float* colP,
                              float* vvec, float* vtvec,
                              const float* errP, const int* convCur, int* convNext) {
  if (blockIdx.x == 0 && threadIdx.x == 0) {
    float er = 0.f, ec = 0.f;
    for (int t = 0; t < 16; ++t) er += errP[t];
    for (int t = 16; t < 33; ++t) ec += errP[t];
    convNext[0] = convCur[0] | ((er < THRESHc) ? 1 : 0);
    convNext[1] = convCur[1] | ((ec < THRESHc) ? 1 : 0);
  }
  const int b = blockIdx.x;
  if (b < 16) {
    if (convCur[1]) return;
    const int i = (b << 8) + threadIdx.x;
    float s = 0.f;
    for (int t = 0; t < CTILES; ++t) s += rowP[t * NN + i];
    vtvec[i] = REGc * (-LOGN - __logf(fmaxf(s, 1e-30f)));
  } else {
    if (convCur[0]) return;
    const int j = ((b - 16) << 8) + threadIdx.x;
    if (j <= NN) {
      float s = 0.f;
      for (int t = 0; t < RTILES; ++t) s += colP[t * LDA + j];
      vvec[j] = REGc * (-LOGM - __logf(fmaxf(s, 1e-30f)));
    }
  }
}

/* ------- final pass 1: logit sums + masked label LSEs (row & col) ------- */
__global__ void final_pass(const u16* S, const float* vvec, const float* vtvec,
                           const float* misc, const int* is_nc,
                           float* rowLm, float* rowLs, float* rowGs,
                           float* colLm, float* colLs, float* colGs) {
  const float a = misc[1], scale = misc[0];
  const int ct = blockIdx.x, rt = blockIdx.y;
  const int tid = threadIdx.x;
  const int tc = tid & 31, tr = tid >> 5;
  const int cbase = ct << 8, r0 = rt << 8;
  const int j0 = cbase + (tc << 3);
  const bool anyv = (j0 <= NN);
  float wc[8]; unsigned jval = 0;
  #pragma unroll
  for (int c = 0; c < 8; ++c) {
    int j = j0 + c;
    wc[c] = 0.f;
    if (j <= NN) { jval |= 1u << c; wc[c] = vvec[j] * INVREG; }
  }
  float cLm[8], cLs[8], cGs[8];
  #pragma unroll
  for (int c = 0; c < 8; ++c) { cLm[c] = NEGINF; cLs[c] = 0.f; cGs[c] = 0.f; }
  for (int st = 0; st < 32; ++st) {
    const int r = r0 + (st << 3) + tr;
    float xv[8], lg[8]; unsigned um = 0;
    #pragma unroll
    for (int c = 0; c < 8; ++c) { xv[c] = 0.f; lg[c] = 0.f; }
    if (anyv) {
      float raw[8];
      unpack8(*(const Q*)(S + (size_t)r * LDA + j0), raw);
      const bool ncr = (is_nc[r] != 0);
      const float vtr = vtvec[r] * INVREG;
      #pragma unroll
      for (int c = 0; c < 8; ++c) {
        if (!(jval >> c & 1u)) continue;
        xv[c] = raw[c] * a;
        lg[c] = scale * raw[c];
        cGs[c] += __expf(lg[c]);
        if (unmasked(j0 + c, r, ncr)) {
          um |= 1u << c;
          float e2 = xv[c] + vtr;
          float nm = fmaxf(cLm[c], e2);
          cLs[c] = cLs[c] * __expf(cLm[c] - nm) + __expf(e2 - nm);
          cLm[c] = nm;
        }
      }
    }
    float rsG = 0.f;
    if (anyv) {
      #pragma unroll
      for (int c = 0; c < 8; ++c) if (jval >> c & 1u) rsG += __expf(lg[c]);
    }
    #pragma unroll
    for (int off = 16; off >= 1; off >>= 1) rsG += __shfl_xor(rsG, off);
    float rmL = NEGINF;
    if (anyv) {
      #pragma unroll
      for (int c = 0; c < 8; ++c) if (um >> c & 1u) rmL = fmaxf(rmL, xv[c] + wc[c]);
    }
    #pragma unroll
    for (int off = 16; off >= 1; off >>= 1) rmL = fmaxf(rmL, __shfl_xor(rmL, off));
    float rsL = 0.f;
    if (anyv && rmL > NEGINF) {
      #pragma unroll
      for (int c = 0; c < 8; ++c) if (um >> c & 1u) rsL += __expf(xv[c] + wc[c] - rmL);
    }
    #pragma unroll
    for (int off = 16; off >= 1; off >>= 1) rsL += __shfl_xor(rsL, off);
    if (tc == 0) {
      rowGs[ct * NN + r] = rsG;
      rowLm[ct * NN + r] = rmL;
      rowLs[ct * NN + r] = rsL;
    }
  }
  __shared__ float shm[8][256];
  __shared__ float shs[8][256];
  #pragma unroll
  for (int c = 0; c < 8; ++c) { shm[tr][(tc << 3) + c] = cLm[c]; shs[tr][(tc << 3) + c] = cLs[c]; }
  __syncthreads();
  {
    float m = NEGINF, s = 0.f;
    #pragma unroll
    for (int g = 0; g < 8; ++g) lse_merge(m, s, shm[g][tid], shs[g][tid]);
    const int j = cbase + tid;
    if (j <= NN) { colLm[rt * LDA + j] = m; colLs[rt * LDA + j] = s; }
  }
  __syncthreads();
  #pragma unroll
  for (int c = 0; c < 8; ++c) shs[tr][(tc << 3) + c] = cGs[c];
  __syncthreads();
  {
    float s = 0.f;
    #pragma unroll
    for (int g = 0; g < 8; ++g) s += shs[g][tid];
    const int j = cbase + tid;
    if (j <= NN) colGs[rt * LDA + j] = s;
  }
}

__global__ void final_combine(const float* rowLm, const float* rowLs, const float* rowGs,
                              const float* colLm, const float* colLs, const float* colGs,
                              float* LSMrow, float* LBLm, float* LBLs,
                              float* LSMcol, float* LBTm, float* LBTs) {
  const int b = blockIdx.x;
  if (b < 16) {
    const int i = (b << 8) + threadIdx.x;
    float m = NEGINF, s = 0.f, sg = 0.f;
    for (int t = 0; t < 17; ++t) {
      lse_merge(m, s, rowLm[t * NN + i], rowLs[t * NN + i]);
      sg += rowGs[t * NN + i];
    }
    LBLm[i] = m; LBLs[i] = s;
    LSMrow[i] = __logf(sg);
  } else {
    const int j = ((b - 16) << 8) + threadIdx.x;
    if (j <= NN) {
      float m = NEGINF, s = 0.f, sg = 0.f;
      for (int t = 0; t < 16; ++t) {
        lse_merge(m, s, colLm[t * LDA + j], colLs[t * LDA + j]);
        sg += colGs[t * LDA + j];
      }
      LBTm[j] = m; LBTs[j] = s;
      LSMcol[j] = __logf(sg);
    }
  }
}

/* ------- final pass 2: KL sums for both orientations ------- */
__global__ void loss_pass(const u16* S, const float* vvec, const float* vtvec,
                          const float* misc, const int* is_nc,
                          const float* LSMrow, const float* LBLm, const float* LBLs,
                          const float* LSMcol, const float* LBTm, const float* LBTs,
                          float* imgP, float* txtP) {
  const float a = misc[1], scale = misc[0];
  const int ct = blockIdx.x, rt = blockIdx.y;
  const int tid = threadIdx.x;
  const int tc = tid & 31, tr = tid >> 5;
  const int cbase = ct << 8, r0 = rt << 8;
  const int j0 = cbase + (tc << 3);
  const bool anyv = (j0 <= NN);
  float vcw[8], bm[8], bsi[8], cg[8]; unsigned jval = 0;
  #pragma unroll
  for (int c = 0; c < 8; ++c) {
    int j = j0 + c;
    vcw[c] = 0.f; bm[c] = 0.f; bsi[c] = 0.f; cg[c] = 0.f;
    if (j <= NN) {
      jval |= 1u << c;
      vcw[c] = vvec[j] * INVREG; bm[c] = LBTm[j]; bsi[c] = 1.f / LBTs[j]; cg[c] = LSMcol[j];
    }
  }
  float sImg = 0.f, sTxt = 0.f;
  for (int st = 0; st < 32; ++st) {
    const int r = r0 + (st << 3) + tr;
    if (anyv) {
      float raw[8];
      unpack8(*(const Q*)(S + (size_t)r * LDA + j0), raw);
      const bool ncr = (is_nc[r] != 0);
      const float vtr = vtvec[r] * INVREG;
      const float rm = LBLm[r], rsi = 1.f / LBLs[r], rg = LSMrow[r];
      #pragma unroll
      for (int c = 0; c < 8; ++c) {
        if (!(jval >> c & 1u)) continue;
        const int j = j0 + c;
        float xv = raw[c] * a;
        float lgt = scale * raw[c];
        bool unm = unmasked(j, r, ncr);
        bool lv = (j == NN) ? ncr : ((j == r) && !ncr);
        float rr = unm ? __expf(xv + vcw[c] - rm) * rsi : 0.f;
        float t = GAM * rr + (lv ? 0.2f : 0.f);
        if (t > 0.f) sImg += t * (__logf(t) - (lgt - rg));
        float r2 = unm ? __expf(xv + vtr - bm[c]) * bsi[c] : 0.f;
        float t2 = GAM * r2 + (lv ? 0.2f : 0.f);
        if (t2 > 0.f) sTxt += t2 * (__logf(t2) - (lgt - cg[c]));
      }
    }
  }
  sImg = blockReduce256(sImg);
  sTxt = blockReduce256(sTxt);
  if (tid == 0) { imgP[rt * 17 + ct] = sImg; txtP[rt * 17 + ct] = sTxt; }
}

__global__ void finish_kernel(const float* imgP, const float* txtP,
                              const float* misc, float* out) {
  float vi = 0.f, vtx = 0.f;
  for (int idx = threadIdx.x; idx < 272; idx += 256) { vi += imgP[idx]; vtx += txtP[idx]; }
  vi = blockReduce256(vi);
  vtx = blockReduce256(vtx);
  if (threadIdx.x == 0) {
    float loss_img = vi / 4096.0f;
    float loss_txt = vtx / 4097.0f;
    float loss_ul = 0.5f * (loss_img + loss_txt);
    float loss_op = misc[4] / 4096.0f;
    if (vi == 0.f && vtx == 0.f) loss_ul = 777.0f;
    if (!(loss_ul == loss_ul))   loss_ul = 888.0f;
    out[0] = loss_ul;
    out[1] = loss_op;
  }
}

extern "C" void kernel_launch(void* const* d_in, const int* in_sizes, int n_in,
                              void* d_out, int out_size, void* d_ws, size_t ws_size,
                              hipStream_t stream) {
  (void)in_sizes; (void)n_in; (void)out_size;
  const u16* img = (const u16*)d_in[0];
  const u16* txt = (const u16*)d_in[1];
  const u16* tno = (const u16*)d_in[2];
  const u16* ls  = (const u16*)d_in[3];
  float* out = (float*)d_out;

  ContrastiveLoss_83391085019222_kernel<<<1, 64, 0, stream>>>(out);

  size_t off = 0;
  char* w = (char*)d_ws;
  u16* S; float *rowP, *colP;
  float *rowLm, *rowLs, *rowGs, *colLm, *colLs, *colGs;
  float *vecs, *preds, *colvals, *gmin, *opP, *errP;
  float *LSMrow, *LBLm, *LBLs, *LSMcol, *LBTm, *LBTs, *imgP, *txtP, *misc;
  int* is_nc;
  #define ALLOC(ptr, type, nbytes) ptr = (type)(w + off); off = (off + (size_t)(nbytes) + 255) & ~(size_t)255
  ALLOC(S,      u16*,   (size_t)NN * LDA * 2);
  ALLOC(rowP,   float*, (size_t)CTILES * NN * 4);
  ALLOC(colP,   float*, (size_t)RTILES * LDA * 4);
  ALLOC(rowLm,  float*, (size_t)17 * NN * 4);
  ALLOC(rowLs,  float*, (size_t)17 * NN * 4);
  ALLOC(rowGs,  float*, (size_t)17 * NN * 4);
  ALLOC(colLm,  float*, (size_t)16 * LDA * 4);
  ALLOC(colLs,  float*, (size_t)16 * LDA * 4);
  ALLOC(colGs,  float*, (size_t)16 * LDA * 4);
  ALLOC(vecs,   float*, 16400 * 4);
  ALLOC(preds,  float*, NN * 4);
  ALLOC(is_nc,  int*,   NN * 4);
  ALLOC(colvals,float*, NN * 4);
  ALLOC(gmin,   float*, 4096 * 4);
  ALLOC(opP,    float*, 1024 * 4);
  ALLOC(errP,   float*, 33 * 4);
  ALLOC(LSMrow, float*, NN * 4);
  ALLOC(LBLm,   float*, NN * 4);
  ALLOC(LBLs,   float*, NN * 4);
  ALLOC(LSMcol, float*, LDA * 4);
  ALLOC(LBTm,   float*, LDA * 4);
  ALLOC(LBTs,   float*, LDA * 4);
  ALLOC(imgP,   float*, 272 * 4);
  ALLOC(txtP,   float*, 272 * 4);
  ALLOC(misc,   float*, 64);
  #undef ALLOC

  if (ws_size < off) {
    diag_kernel<<<1, 64, 0, stream>>>(out, -(float)(ws_size / 1000000.0),
                                      -(float)(off / 1000000.0));
    return;
  }

  float* uvec  = vecs;
  float* vvec  = vecs + 4096;
  float* utvec = vecs + 8200;
  float* vtvec = vecs + 12304;
  int* flags = (int*)misc + 6;

  detect_kernel<<<1, 64, 0, stream>>>(img, misc);
  init_kernel<<<65, 256, 0, stream>>>(ls, vecs, misc);
  gemm_kernel<<<dim3(64, 64), 256, 0, stream>>>(img, txt, S, gmin, misc);
  colvec_kernel<<<1024, 256, 0, stream>>>(img, txt, tno, colvals, opP, misc);
  scatter_col<<<16, 256, 0, stream>>>(S, colvals);
  reduce_kernel<<<1, 256, 0, stream>>>(gmin, colvals, opP, misc);

  preds_kernel<<<1024, 256, 0, stream>>>(S, misc, preds);
  rank_kernel<<<32, 128, 0, stream>>>(preds, is_nc);

  for (int k = 0; k < 100; ++k) {
    const int* cc = flags + 2 * (k & 1);
    int* cn = flags + 2 * ((k + 1) & 1);
    sink_pass<<<dim3(CTILES, RTILES), 256, 0, stream>>>(S, vvec, vtvec, misc, cc, 0, 1, is_nc,
                                                        rowP, colP);
    sink_combineA<<<33, 256, 0, stream>>>(rowP, colP, uvec, utvec, errP, cc);
    sink_pass<<<dim3(CTILES, RTILES), 256, 0, stream>>>(S, utvec, uvec, misc, cc, 1, 0, is_nc,
                                                        rowP, colP);
    sink_combineB<<<33, 256, 0, stream>>>(rowP, colP, vvec, vtvec, errP, cc, cn);
  }

  final_pass<<<dim3(17, 16), 256, 0, stream>>>(S, vvec, vtvec, misc, is_nc,
                                               rowLm, rowLs, rowGs, colLm, colLs, colGs);
  final_combine<<<33, 256, 0, stream>>>(rowLm, rowLs, rowGs, colLm, colLs, colGs,
                                        LSMrow, LBLm, LBLs, LSMcol, LBTm, LBTs);
  loss_pass<<<dim3(17, 16), 256, 0, stream>>>(S, vvec, vtvec, misc, is_nc,
                                              LSMrow, LBLm, LBLs, LSMcol, LBTm, LBTs, imgP, txtP);
  finish_kernel<<<1, 256, 0, stream>>>(imgP, txtP, misc, out);
}


// Round 17
// 1405.814 us; speedup vs baseline: 2.9748x; 1.1437x over previous
//

#include <hip/hip_runtime.h>
#include <hip/hip_bf16.h>

// ROUND 17 (round 16: 1607.8 us, absmax 0.0):
//  - Multiplicative-domain Sinkhorn: weights derived on the fly as
//    e^{-a}/(dim*sum) from the previous pass's atomically-accumulated sums.
//    Combine kernels eliminated -> 2 launches/iter (was 4), ~215 total.
//  - Convergence: sticky flag == (errs[k-1] < THRESH) single-lag test.
//  - scatter_col merged into colvec_kernel.

#define NN 4096
#define LDA 4104          /* fp16 row stride for S (4097 padded to x8) */
#define DD 512
#define NCNUM 409         /* int(0.1*4096) */
#define REGc 0.03f
#define INVREG (1.0f/0.03f)
#define GAM 0.8f
#define THRESHc 1e-4f
#define LOGN 8.3177661667193433f   /* ln(4096) */
#define LOGM 8.3180102775477533f   /* ln(4097) */
#define NEGINF (-__builtin_inff())

typedef unsigned short u16;
typedef unsigned int u32;
typedef _Float16 f16;

struct alignas(16) Q  { u32 x, y, z, w; };
struct alignas(8)  Q2 { u32 x, y; };
struct alignas(16) F4 { float a, b, c, d; };
union H8 { Q q; f16 h[8]; };

__device__ __forceinline__ float bf2f(u32 u) { return __uint_as_float(u << 16); }
__device__ __forceinline__ float bflo(u32 w) { return __uint_as_float(w << 16); }
__device__ __forceinline__ float bfhi(u32 w) { return __uint_as_float(w & 0xFFFF0000u); }
__device__ __forceinline__ u16 f2h_hw(float f) {
  union { f16 h; u16 u; } X; X.h = (f16)f; return X.u;
}
__device__ __forceinline__ float h2f_hw(u16 v) {
  union { u16 u; f16 h; } X; X.u = v; return (float)X.h;
}
__device__ __forceinline__ void unpack8(Q q, float* x) {
  H8 u; u.q = q;
  #pragma unroll
  for (int c = 0; c < 8; ++c) x[c] = (float)u.h[c];
}
__device__ __forceinline__ void lse_merge(float& m, float& s, float om, float os) {
  float nm = fmaxf(m, om);
  if (nm == NEGINF) return;
  float acc = 0.f;
  if (s  > 0.f) acc += s  * __expf(m  - nm);
  if (os > 0.f) acc += os * __expf(om - nm);
  m = nm; s = acc;
}
__device__ __forceinline__ float blockReduce256(float v) {
  __shared__ float sh[4];
  #pragma unroll
  for (int off = 32; off >= 1; off >>= 1) v += __shfl_xor(v, off);
  int w = threadIdx.x >> 6;
  if ((threadIdx.x & 63) == 0) sh[w] = v;
  __syncthreads();
  float r = 0.f;
  if (threadIdx.x == 0) r = sh[0] + sh[1] + sh[2] + sh[3];
  __syncthreads();
  return r;
}

__global__ void ContrastiveLoss_83391085019222_kernel(float* out) {
  if (threadIdx.x == 0) { out[0] = 0.5f; out[1] = 0.5f; }
}
__global__ void diag_kernel(float* out, float a, float b) {
  if (threadIdx.x == 0) { out[0] = a; out[1] = b; }
}

/* ---- dtype autodetect: inputs are unit-normalized rows ---- */
__global__ void detect_kernel(const u16* img, float* misc) {
  const int lane = threadIdx.x;  /* 64 */
  float nb = 0.f, nf = 0.f;
  const float* fimg = (const float*)img;
  for (int c = lane * 8; c < lane * 8 + 8; ++c) {
    float xb = bf2f((u32)img[c]);
    nb += xb * xb;
    float xf = fimg[c];
    if (fabsf(xf) < 1e10f) nf += xf * xf; else nf += 1e10f;
  }
  #pragma unroll
  for (int off = 32; off >= 1; off >>= 1) { nb += __shfl_xor(nb, off); nf += __shfl_xor(nf, off); }
  if (lane == 0) {
    float db = fabsf(nb - 1.f);
    float df = fabsf(nf - 1.f);
    if (!(db == db)) db = 1e30f;
    if (!(df == df)) df = 1e30f;
    ((int*)misc)[10] = (df < db) ? 1 : 0;   /* 1 = float32 inputs */
  }
}

/* init: zero vecs(16400: u,vvec,ut,vt) + errs(256) + rsA0(4096) + csA0(4104), scale */
__global__ void init_kernel(const u16* ls, float* vecs, float* errs,
                            float* rsA0, float* csA0, float* misc) {
  int t = blockIdx.x * 256 + threadIdx.x;
  if (t < 16400) vecs[t] = 0.f;
  if (t < 256)  errs[t] = 0.f;
  if (t < 4096) rsA0[t] = 0.f;
  if (t < 4104) csA0[t] = 0.f;
  if (t == 0) {
    const int isF = ((const int*)misc)[10];
    float lsv = isF ? ((const float*)ls)[0] : bf2f((u32)ls[0]);
    misc[0] = __expf(lsv);               /* scale = exp(logit_scale) */
  }
}

/* ------- GEMM: S[i,j] = dot(img_i, txt_j) -> fp16 bits + per-block min ------- */
__global__ void gemm_kernel(const u16* A, const u16* B, u16* S, float* gmin,
                            const float* misc) {
  __shared__ float As[64 * 20];
  __shared__ float Bs[64 * 20];
  __shared__ float red[256];
  const int isF = ((const int*)misc)[10];
  const int tid = threadIdx.x;
  const int tx = tid & 15, ty = tid >> 4;
  const int rb = (int)blockIdx.y << 6, cb = (int)blockIdx.x << 6;
  const int lrow = tid >> 2;
  const int lchunk = (tid & 3) << 2;
  float acc[4][4];
  #pragma unroll
  for (int r = 0; r < 4; ++r)
    #pragma unroll
    for (int c = 0; c < 4; ++c) acc[r][c] = 0.f;
  for (int kt = 0; kt < DD; kt += 16) {
    float v0, v1, v2, v3, w0, w1, w2, w3;
    if (isF) {
      const float* Af = (const float*)A;
      const float* Bf = (const float*)B;
      F4 a4 = *(const F4*)(Af + (size_t)(rb + lrow) * DD + kt + lchunk);
      F4 b4 = *(const F4*)(Bf + (size_t)(cb + lrow) * DD + kt + lchunk);
      v0 = a4.a; v1 = a4.b; v2 = a4.c; v3 = a4.d;
      w0 = b4.a; w1 = b4.b; w2 = b4.c; w3 = b4.d;
    } else {
      Q2 a2 = *(const Q2*)(A + (size_t)(rb + lrow) * DD + kt + lchunk);
      Q2 b2 = *(const Q2*)(B + (size_t)(cb + lrow) * DD + kt + lchunk);
      v0 = bflo(a2.x); v1 = bfhi(a2.x); v2 = bflo(a2.y); v3 = bfhi(a2.y);
      w0 = bflo(b2.x); w1 = bfhi(b2.x); w2 = bflo(b2.y); w3 = bfhi(b2.y);
    }
    __syncthreads();
    As[lrow*20 + lchunk + 0] = v0; As[lrow*20 + lchunk + 1] = v1;
    As[lrow*20 + lchunk + 2] = v2; As[lrow*20 + lchunk + 3] = v3;
    Bs[lrow*20 + lchunk + 0] = w0; Bs[lrow*20 + lchunk + 1] = w1;
    Bs[lrow*20 + lchunk + 2] = w2; Bs[lrow*20 + lchunk + 3] = w3;
    __syncthreads();
    #pragma unroll
    for (int k = 0; k < 16; k += 4) {
      F4 aF[4], bF[4];
      #pragma unroll
      for (int r = 0; r < 4; ++r) aF[r] = *(const F4*)&As[(ty*4 + r)*20 + k];
      #pragma unroll
      for (int c = 0; c < 4; ++c) bF[c] = *(const F4*)&Bs[(tx*4 + c)*20 + k];
      #pragma unroll
      for (int r = 0; r < 4; ++r)
        #pragma unroll
        for (int c = 0; c < 4; ++c) {
          acc[r][c] = fmaf(aF[r].a, bF[c].a, acc[r][c]);
          acc[r][c] = fmaf(aF[r].b, bF[c].b, acc[r][c]);
          acc[r][c] = fmaf(aF[r].c, bF[c].c, acc[r][c]);
          acc[r][c] = fmaf(aF[r].d, bF[c].d, acc[r][c]);
        }
    }
  }
  float lmin = 1e30f;
  #pragma unroll
  for (int r = 0; r < 4; ++r) {
    u16 h0 = f2h_hw(acc[r][0]), h1 = f2h_hw(acc[r][1]);
    u16 h2 = f2h_hw(acc[r][2]), h3 = f2h_hw(acc[r][3]);
    lmin = fminf(lmin, h2f_hw(h0)); lmin = fminf(lmin, h2f_hw(h1));
    lmin = fminf(lmin, h2f_hw(h2)); lmin = fminf(lmin, h2f_hw(h3));
    Q2 o; o.x = (u32)h0 | ((u32)h1 << 16); o.y = (u32)h2 | ((u32)h3 << 16);
    *(Q2*)(S + (size_t)(rb + ty*4 + r) * LDA + cb + tx*4) = o;
  }
  red[tid] = lmin;
  __syncthreads();
  for (int sN = 128; sN >= 1; sN >>= 1) {
    if (tid < sN) red[tid] = fminf(red[tid], red[tid + sN]);
    __syncthreads();
  }
  if (tid == 0) gmin[blockIdx.y * 64 + blockIdx.x] = red[0];
}

/* ------- sims_no -> S col NN (merged scatter) + loss_op partial ------- */
__global__ void colvec_kernel(const u16* img, const u16* txt, const u16* tno,
                              u16* S, float* colvals, float* opP, const float* misc) {
  __shared__ float shOp[4];
  const int isF = ((const int*)misc)[10];
  const int wv = threadIdx.x >> 6;
  const int row = (int)(blockIdx.x << 2) + wv;
  const int lane = threadIdx.x & 63;
  const size_t base = (size_t)row * DD + lane * 8;
  float xi[8], xt[8], xn[8];
  if (isF) {
    const float* fi = (const float*)img;
    const float* ft = (const float*)txt;
    const float* fn = (const float*)tno;
    #pragma unroll
    for (int c = 0; c < 8; ++c) { xi[c] = fi[base+c]; xt[c] = ft[base+c]; xn[c] = fn[base+c]; }
  } else {
    Q qi = *(const Q*)(img + base);
    Q qt = *(const Q*)(txt + base);
    Q qn = *(const Q*)(tno + base);
    xi[0]=bflo(qi.x); xi[1]=bfhi(qi.x); xi[2]=bflo(qi.y); xi[3]=bfhi(qi.y);
    xi[4]=bflo(qi.z); xi[5]=bfhi(qi.z); xi[6]=bflo(qi.w); xi[7]=bfhi(qi.w);
    xt[0]=bflo(qt.x); xt[1]=bfhi(qt.x); xt[2]=bflo(qt.y); xt[3]=bfhi(qt.y);
    xt[4]=bflo(qt.z); xt[5]=bfhi(qt.z); xt[6]=bflo(qt.w); xt[7]=bfhi(qt.w);
    xn[0]=bflo(qn.x); xn[1]=bfhi(qn.x); xn[2]=bflo(qn.y); xn[3]=bfhi(qn.y);
    xn[4]=bflo(qn.z); xn[5]=bfhi(qn.z); xn[6]=bflo(qn.w); xn[7]=bfhi(qn.w);
  }
  float sn = 0.f, cs = 0.f;
  #pragma unroll
  for (int c = 0; c < 8; ++c) { sn += xi[c]*xn[c]; cs += xt[c]*xn[c]; }
  #pragma unroll
  for (int off = 32; off >= 1; off >>= 1) { sn += __shfl_xor(sn, off); cs += __shfl_xor(cs, off); }
  if (lane == 0) {
    colvals[row] = sn;
    S[(size_t)row * LDA + NN] = f2h_hw(sn);
    shOp[wv] = fmaxf(cs + 0.2f, 0.f) + fmaxf(-0.7f - cs, 0.f);
  }
  __syncthreads();
  if (threadIdx.x == 0) opP[blockIdx.x] = shOp[0] + shOp[1] + shOp[2] + shOp[3];
}

__global__ void reduce_kernel(const float* gmin, const float* colvals,
                              const float* opP, float* misc) {
  __shared__ float smin[256];
  __shared__ float ssum[256];
  float mn = 1e30f, sm = 0.f;
  for (int i = threadIdx.x; i < 4096; i += 256) {
    mn = fminf(mn, gmin[i]);
    mn = fminf(mn, h2f_hw(f2h_hw(colvals[i])));
  }
  for (int i = threadIdx.x; i < 1024; i += 256) sm += opP[i];
  smin[threadIdx.x] = mn; ssum[threadIdx.x] = sm;
  __syncthreads();
  for (int sN = 128; sN >= 1; sN >>= 1) {
    if (threadIdx.x < sN) {
      smin[threadIdx.x] = fminf(smin[threadIdx.x], smin[threadIdx.x + sN]);
      ssum[threadIdx.x] += ssum[threadIdx.x + sN];
    }
    __syncthreads();
  }
  if (threadIdx.x == 0) {
    float maxC = 1.0f - smin[0];         /* max(1-S) = 1 - min(S) */
    float a = 1.0f / (maxC * REGc);
    misc[1] = a;
    misc[4] = ssum[0];
    misc[5] = __expf(-a);                /* ea */
  }
}

__global__ void preds_kernel(const u16* S, const float* misc, float* preds) {
  const int row = (int)(blockIdx.x << 2) + (int)(threadIdx.x >> 6);
  const int lane = threadIdx.x & 63;
  const float scale = misc[0];
  const u16* Sr = S + (size_t)row * LDA;
  float m = NEGINF, s = 0.f;
  for (int it = 0; it < 8; ++it) {
    const int j0 = (it << 9) + (lane << 3);
    float x[8];
    unpack8(*(const Q*)(Sr + j0), x);
    float lm = NEGINF;
    #pragma unroll
    for (int c = 0; c < 8; ++c) { x[c] *= scale; lm = fmaxf(lm, x[c]); }
    float lsum = 0.f;
    #pragma unroll
    for (int c = 0; c < 8; ++c) lsum += __expf(x[c] - lm);
    lse_merge(m, s, lm, lsum);
  }
  #pragma unroll
  for (int off = 32; off >= 1; off >>= 1) {
    float om = __shfl_xor(m, off), os = __shfl_xor(s, off);
    lse_merge(m, s, om, os);
  }
  if (lane == 0) {
    float sii = h2f_hw(Sr[row]);
    preds[row] = __expf(scale * sii - m) / s;
  }
}

__global__ void rank_kernel(const float* preds, int* is_nc) {
  __shared__ float sp[NN];
  for (int idx = threadIdx.x; idx < NN; idx += 128) sp[idx] = preds[idx];
  __syncthreads();
  const int i = blockIdx.x * 128 + threadIdx.x;
  const float pv = sp[i];
  int cnt = 0;
  for (int k2 = 0; k2 < NN; ++k2) {
    float pk = sp[k2];
    cnt += (pk < pv || (pk == pv && k2 < i)) ? 1 : 0;
  }
  is_nc[i] = (cnt < NCNUM) ? 1 : 0;
}

__device__ __forceinline__ bool unmasked(int j, int r, bool ncr) {
  return (j == NN) ? ncr : !((j == r) && ncr);
}

/* ------- fused sinkhorn step (multiplicative domain) -------
   role A(k): rowAccum->rowsumA[k&1] (s1,u; W1=beta from prevCol=colsumB),
              colAccum->colsumA[k&1] (s2,ut; W2=betat from prevRow=rowsumB)
   role B(k): rowAccum->rowsumB[k&1] (s2,vt; W1=alphat from prevCol=colsumA),
              colAccum->colsumB[k&1] (s1,v; W2=alpha from prevRow=rowsumA)
   W from COL sums: ea/(M*sum); from ROW sums: ea/(N*sum).
   Gates: sticky conv == (errs[k-1] < THRESH).                            */
__global__ void sink_step(const u16* S, const float* misc,
                          float* errs1, float* errs2,
                          float* u, float* ut, float* vvec, float* vtvec,
                          const float* prevRow, const float* prevCol,
                          float* outRow, float* outCol,
                          float* zero1, float* zero2, int nz1, int nz2,
                          int k, int roleB, int finalOnly,
                          const int* is_nc) {
  __shared__ float shW1[128];
  __shared__ float shW2[128];
  __shared__ float shAcc[16][128];
  __shared__ int   shG[4];
  __shared__ float se[4];
  const int tid = threadIdx.x;
  const int ct = blockIdx.x, rt = blockIdx.y;
  const int cbase = ct << 7, r0 = rt << 7;
  const float a = misc[1], ea = misc[5];

  if (!finalOnly) {
    int bid = (int)blockIdx.y * 33 + (int)blockIdx.x;
    int tot = nz1 + nz2;
    for (int z = bid * 256 + tid; z < tot; z += 1056 * 256) {
      if (z < nz1) zero1[z] = 0.f; else zero2[z - nz1] = 0.f;
    }
  }
  if (tid == 0) {
    shG[0] = (k >= 1) && (errs1[k-1] < THRESHc);   /* conv1(k) */
    shG[1] = (k >= 1) && (errs2[k-1] < THRESHc);   /* conv2(k) */
    shG[2] = (k >= 2) && (errs1[k-2] < THRESHc);   /* conv1(k-1) */
    shG[3] = (k >= 2) && (errs2[k-2] < THRESHc);   /* conv2(k-1) */
  }
  __syncthreads();
  const int c1 = shG[0], c2 = shG[1], c1p = shG[2], c2p = shG[3];
  const int gRow = roleB ? c2 : c1;   /* gate for row accumulation (+W1) */
  const int gCol = roleB ? c1 : c2;   /* gate for col accumulation (+W2) */

  float errd = 0.f;
  if (tid < 128) {
    const int i = r0 + tid;
    float w = 0.f;
    if (!roleB) {
      if (!finalOnly && !gCol) w = (k == 0) ? ea : ea / (4096.0f * prevRow[i]);
      if (ct == 0 && k >= 1 && !c2p) vtvec[i] = REGc * (-LOGN - __logf(prevRow[i]));
    } else {
      if (!gCol) {
        w = ea / (4096.0f * prevRow[i]);
        if (ct == 0) {
          float un = REGc * (-LOGN - __logf(prevRow[i]));
          errd = fabsf(un - u[i]);
          u[i] = un;
        }
      }
    }
    shW2[tid] = w;
  } else {
    const int j = cbase + (tid - 128);
    float w = 0.f;
    if (j <= NN) {
      if (!roleB) {
        if (!finalOnly && !gRow) w = (k == 0) ? ea : ea / (4097.0f * prevCol[j]);
        if (rt == 0 && k >= 1 && !c1p) vvec[j] = REGc * (-LOGM - __logf(prevCol[j]));
      } else {
        if (!gRow) {
          w = ea / (4097.0f * prevCol[j]);
          if (rt == 0) {
            float un = REGc * (-LOGM - __logf(prevCol[j]));
            errd = fabsf(un - ut[j]);
            ut[j] = un;
          }
        }
      }
    }
    shW1[tid - 128] = w;
  }
  __syncthreads();

  if (!finalOnly && !(gRow && gCol)) {
    const int tc = tid & 15, tr = tid >> 4;
    const int j0c = tc << 3;
    const int j0 = cbase + j0c;
    const bool anyv = (j0 <= NN);
    unsigned jval = 0;
    #pragma unroll
    for (int c = 0; c < 8; ++c) if (j0 + c <= NN) jval |= 1u << c;
    float W1l[8];
    #pragma unroll
    for (int c = 0; c < 8; ++c) W1l[c] = shW1[j0c + c];
    float cs[8];
    #pragma unroll
    for (int c = 0; c < 8; ++c) cs[c] = 0.f;
    for (int st = 0; st < 8; ++st) {
      const int rr = (st << 4) + tr;
      const int r = r0 + rr;
      float E[8];
      if (anyv) {
        float xv[8];
        unpack8(*(const Q*)(S + (size_t)r * LDA + j0), xv);
        const bool ncr = (is_nc[r] != 0);
        #pragma unroll
        for (int c = 0; c < 8; ++c) {
          E[c] = __expf(xv[c] * a);
          if (!((jval >> c & 1u) && unmasked(j0 + c, r, ncr))) E[c] = 0.f;
        }
      } else {
        #pragma unroll
        for (int c = 0; c < 8; ++c) E[c] = 0.f;
      }
      if (!gCol) {
        float Wr = shW2[rr];
        #pragma unroll
        for (int c = 0; c < 8; ++c) cs[c] = fmaf(E[c], Wr, cs[c]);
      }
      if (!gRow) {
        float rs = 0.f;
        #pragma unroll
        for (int c = 0; c < 8; ++c) rs = fmaf(E[c], W1l[c], rs);
        #pragma unroll
        for (int off = 8; off >= 1; off >>= 1) rs += __shfl_xor(rs, off);
        if (tc == 0) atomicAdd(&outRow[r], rs);
      }
    }
    if (!gCol) {
      #pragma unroll
      for (int c = 0; c < 8; ++c) shAcc[tr][j0c + c] = cs[c];
      __syncthreads();
      if (tid < 128) {
        float s = 0.f;
        #pragma unroll
        for (int g = 0; g < 16; ++g) s += shAcc[g][tid];
        const int j = cbase + tid;
        if (j <= NN) atomicAdd(&outCol[j], s);
      }
    }
  }

  if (roleB) {
    #pragma unroll
    for (int off = 32; off >= 1; off >>= 1) errd += __shfl_xor(errd, off);
    if ((tid & 63) == 0) se[tid >> 6] = errd;
    __syncthreads();
    if (tid == 0) {
      if (ct == 0) atomicAdd(&errs1[k], se[0] + se[1]);
      if (rt == 0) atomicAdd(&errs2[k], se[2] + se[3]);
    }
  }
}

/* ------- final pass 1: logit sums + masked label LSEs (row & col) ------- */
__global__ void final_pass(const u16* S, const float* vvec, const float* vtvec,
                           const float* misc, const int* is_nc,
                           float* rowLm, float* rowLs, float* rowGs,
                           float* colLm, float* colLs, float* colGs) {
  const float a = misc[1], scale = misc[0];
  const int ct = blockIdx.x, rt = blockIdx.y;
  const int tid = threadIdx.x;
  const int tc = tid & 31, tr = tid >> 5;
  const int cbase = ct << 8, r0 = rt << 8;
  const int j0 = cbase + (tc << 3);
  const bool anyv = (j0 <= NN);
  float wc[8]; unsigned jval = 0;
  #pragma unroll
  for (int c = 0; c < 8; ++c) {
    int j = j0 + c;
    wc[c] = 0.f;
    if (j <= NN) { jval |= 1u << c; wc[c] = vvec[j] * INVREG; }
  }
  float cLm[8], cLs[8], cGs[8];
  #pragma unroll
  for (int c = 0; c < 8; ++c) { cLm[c] = NEGINF; cLs[c] = 0.f; cGs[c] = 0.f; }
  for (int st = 0; st < 32; ++st) {
    const int r = r0 + (st << 3) + tr;
    float xv[8], lg[8]; unsigned um = 0;
    #pragma unroll
    for (int c = 0; c < 8; ++c) { xv[c] = 0.f; lg[c] = 0.f; }
    if (anyv) {
      float raw[8];
      unpack8(*(const Q*)(S + (size_t)r * LDA + j0), raw);
      const bool ncr = (is_nc[r] != 0);
      const float vtr = vtvec[r] * INVREG;
      #pragma unroll
      for (int c = 0; c < 8; ++c) {
        if (!(jval >> c & 1u)) continue;
        xv[c] = raw[c] * a;
        lg[c] = scale * raw[c];
        cGs[c] += __expf(lg[c]);
        if (unmasked(j0 + c, r, ncr)) {
          um |= 1u << c;
          float e2 = xv[c] + vtr;
          float nm = fmaxf(cLm[c], e2);
          cLs[c] = cLs[c] * __expf(cLm[c] - nm) + __expf(e2 - nm);
          cLm[c] = nm;
        }
      }
    }
    float rsG = 0.f;
    if (anyv) {
      #pragma unroll
      for (int c = 0; c < 8; ++c) if (jval >> c & 1u) rsG += __expf(lg[c]);
    }
    #pragma unroll
    for (int off = 16; off >= 1; off >>= 1) rsG += __shfl_xor(rsG, off);
    float rmL = NEGINF;
    if (anyv) {
      #pragma unroll
      for (int c = 0; c < 8; ++c) if (um >> c & 1u) rmL = fmaxf(rmL, xv[c] + wc[c]);
    }
    #pragma unroll
    for (int off = 16; off >= 1; off >>= 1) rmL = fmaxf(rmL, __shfl_xor(rmL, off));
    float rsL = 0.f;
    if (anyv && rmL > NEGINF) {
      #pragma unroll
      for (int c = 0; c < 8; ++c) if (um >> c & 1u) rsL += __expf(xv[c] + wc[c] - rmL);
    }
    #pragma unroll
    for (int off = 16; off >= 1; off >>= 1) rsL += __shfl_xor(rsL, off);
    if (tc == 0) {
      rowGs[ct * NN + r] = rsG;
      rowLm[ct * NN + r] = rmL;
      rowLs[ct * NN + r] = rsL;
    }
  }
  __shared__ float shm[8][256];
  __shared__ float shs[8][256];
  #pragma unroll
  for (int c = 0; c < 8; ++c) { shm[tr][(tc << 3) + c] = cLm[c]; shs[tr][(tc << 3) + c] = cLs[c]; }
  __syncthreads();
  {
    float m = NEGINF, s = 0.f;
    #pragma unroll
    for (int g = 0; g < 8; ++g) lse_merge(m, s, shm[g][tid], shs[g][tid]);
    const int j = cbase + tid;
    if (j <= NN) { colLm[rt * LDA + j] = m; colLs[rt * LDA + j] = s; }
  }
  __syncthreads();
  #pragma unroll
  for (int c = 0; c < 8; ++c) shs[tr][(tc << 3) + c] = cGs[c];
  __syncthreads();
  {
    float s = 0.f;
    #pragma unroll
    for (int g = 0; g < 8; ++g) s += shs[g][tid];
    const int j = cbase + tid;
    if (j <= NN) colGs[rt * LDA + j] = s;
  }
}

__global__ void final_combine(const float* rowLm, const float* rowLs, const float* rowGs,
                              const float* colLm, const float* colLs, const float* colGs,
                              float* LSMrow, float* LBLm, float* LBLs,
                              float* LSMcol, float* LBTm, float* LBTs) {
  const int b = blockIdx.x;
  if (b < 16) {
    const int i = (b << 8) + threadIdx.x;
    float m = NEGINF, s = 0.f, sg = 0.f;
    for (int t = 0; t < 17; ++t) {
      lse_merge(m, s, rowLm[t * NN + i], rowLs[t * NN + i]);
      sg += rowGs[t * NN + i];
    }
    LBLm[i] = m; LBLs[i] = s;
    LSMrow[i] = __logf(sg);
  } else {
    const int j = ((b - 16) << 8) + threadIdx.x;
    if (j <= NN) {
      float m = NEGINF, s = 0.f, sg = 0.f;
      for (int t = 0; t < 16; ++t) {
        lse_merge(m, s, colLm[t * LDA + j], colLs[t * LDA + j]);
        sg += colGs[t * LDA + j];
      }
      LBTm[j] = m; LBTs[j] = s;
      LSMcol[j] = __logf(sg);
    }
  }
}

/* ------- final pass 2: KL sums for both orientations ------- */
__global__ void loss_pass(const u16* S, const float* vvec, const float* vtvec,
                          const float* misc, const int* is_nc,
                          const float* LSMrow, const float* LBLm, const float* LBLs,
                          const float* LSMcol, const float* LBTm, const float* LBTs,
                          float* imgP, float* txtP) {
  const float a = misc[1], scale = misc[0];
  const int ct = blockIdx.x, rt = blockIdx.y;
  const int tid = threadIdx.x;
  const int tc = tid & 31, tr = tid >> 5;
  const int cbase = ct << 8, r0 = rt << 8;
  const int j0 = cbase + (tc << 3);
  const bool anyv = (j0 <= NN);
  float vcw[8], bm[8], bsi[8], cg[8]; unsigned jval = 0;
  #pragma unroll
  for (int c = 0; c < 8; ++c) {
    int j = j0 + c;
    vcw[c] = 0.f; bm[c] = 0.f; bsi[c] = 0.f; cg[c] = 0.f;
    if (j <= NN) {
      jval |= 1u << c;
      vcw[c] = vvec[j] * INVREG; bm[c] = LBTm[j]; bsi[c] = 1.f / LBTs[j]; cg[c] = LSMcol[j];
    }
  }
  float sImg = 0.f, sTxt = 0.f;
  for (int st = 0; st < 32; ++st) {
    const int r = r0 + (st << 3) + tr;
    if (anyv) {
      float raw[8];
      unpack8(*(const Q*)(S + (size_t)r * LDA + j0), raw);
      const bool ncr = (is_nc[r] != 0);
      const float vtr = vtvec[r] * INVREG;
      const float rm = LBLm[r], rsi = 1.f / LBLs[r], rg = LSMrow[r];
      #pragma unroll
      for (int c = 0; c < 8; ++c) {
        if (!(jval >> c & 1u)) continue;
        const int j = j0 + c;
        float xv = raw[c] * a;
        float lgt = scale * raw[c];
        bool unm = unmasked(j, r, ncr);
        bool lv = (j == NN) ? ncr : ((j == r) && !ncr);
        float rr = unm ? __expf(xv + vcw[c] - rm) * rsi : 0.f;
        float t = GAM * rr + (lv ? 0.2f : 0.f);
        if (t > 0.f) sImg += t * (__logf(t) - (lgt - rg));
        float r2 = unm ? __expf(xv + vtr - bm[c]) * bsi[c] : 0.f;
        float t2 = GAM * r2 + (lv ? 0.2f : 0.f);
        if (t2 > 0.f) sTxt += t2 * (__logf(t2) - (lgt - cg[c]));
      }
    }
  }
  sImg = blockReduce256(sImg);
  sTxt = blockReduce256(sTxt);
  if (tid == 0) { imgP[rt * 17 + ct] = sImg; txtP[rt * 17 + ct] = sTxt; }
}

__global__ void finish_kernel(const float* imgP, const float* txtP,
                              const float* misc, float* out) {
  float vi = 0.f, vtx = 0.f;
  for (int idx = threadIdx.x; idx < 272; idx += 256) { vi += imgP[idx]; vtx += txtP[idx]; }
  vi = blockReduce256(vi);
  vtx = blockReduce256(vtx);
  if (threadIdx.x == 0) {
    float loss_img = vi / 4096.0f;
    float loss_txt = vtx / 4097.0f;
    float loss_ul = 0.5f * (loss_img + loss_txt);
    float loss_op = misc[4] / 4096.0f;
    if (vi == 0.f && vtx == 0.f) loss_ul = 777.0f;
    if (!(loss_ul == loss_ul))   loss_ul = 888.0f;
    out[0] = loss_ul;
    out[1] = loss_op;
  }
}

extern "C" void kernel_launch(void* const* d_in, const int* in_sizes, int n_in,
                              void* d_out, int out_size, void* d_ws, size_t ws_size,
                              hipStream_t stream) {
  (void)in_sizes; (void)n_in; (void)out_size;
  const u16* img = (const u16*)d_in[0];
  const u16* txt = (const u16*)d_in[1];
  const u16* tno = (const u16*)d_in[2];
  const u16* ls  = (const u16*)d_in[3];
  float* out = (float*)d_out;

  ContrastiveLoss_83391085019222_kernel<<<1, 64, 0, stream>>>(out);

  size_t off = 0;
  char* w = (char*)d_ws;
  u16* S;
  float *rsA0, *rsA1, *csA0, *csA1, *rsB0, *rsB1, *csB0, *csB1, *errs;
  float *rowLm, *rowLs, *rowGs, *colLm, *colLs, *colGs;
  float *vecs, *preds, *colvals, *gmin, *opP;
  float *LSMrow, *LBLm, *LBLs, *LSMcol, *LBTm, *LBTs, *imgP, *txtP, *misc;
  int* is_nc;
  #define ALLOC(ptr, type, nbytes) ptr = (type)(w + off); off = (off + (size_t)(nbytes) + 255) & ~(size_t)255
  ALLOC(S,      u16*,   (size_t)NN * LDA * 2);
  ALLOC(rsA0,   float*, 4096 * 4);
  ALLOC(rsA1,   float*, 4096 * 4);
  ALLOC(csA0,   float*, 4104 * 4);
  ALLOC(csA1,   float*, 4104 * 4);
  ALLOC(rsB0,   float*, 4096 * 4);
  ALLOC(rsB1,   float*, 4096 * 4);
  ALLOC(csB0,   float*, 4104 * 4);
  ALLOC(csB1,   float*, 4104 * 4);
  ALLOC(errs,   float*, 256 * 4);
  ALLOC(rowLm,  float*, (size_t)17 * NN * 4);
  ALLOC(rowLs,  float*, (size_t)17 * NN * 4);
  ALLOC(rowGs,  float*, (size_t)17 * NN * 4);
  ALLOC(colLm,  float*, (size_t)16 * LDA * 4);
  ALLOC(colLs,  float*, (size_t)16 * LDA * 4);
  ALLOC(colGs,  float*, (size_t)16 * LDA * 4);
  ALLOC(vecs,   float*, 16400 * 4);
  ALLOC(preds,  float*, NN * 4);
  ALLOC(is_nc,  int*,   NN * 4);
  ALLOC(colvals,float*, NN * 4);
  ALLOC(gmin,   float*, 4096 * 4);
  ALLOC(opP,    float*, 1024 * 4);
  ALLOC(LSMrow, float*, NN * 4);
  ALLOC(LBLm,   float*, NN * 4);
  ALLOC(LBLs,   float*, NN * 4);
  ALLOC(LSMcol, float*, LDA * 4);
  ALLOC(LBTm,   float*, LDA * 4);
  ALLOC(LBTs,   float*, LDA * 4);
  ALLOC(imgP,   float*, 272 * 4);
  ALLOC(txtP,   float*, 272 * 4);
  ALLOC(misc,   float*, 64);
  #undef ALLOC

  if (ws_size < off) {
    diag_kernel<<<1, 64, 0, stream>>>(out, -(float)(ws_size / 1000000.0),
                                      -(float)(off / 1000000.0));
    return;
  }

  float* uvec  = vecs;
  float* vvec  = vecs + 4096;
  float* utvec = vecs + 8200;
  float* vtvec = vecs + 12304;
  float* errs1 = errs;
  float* errs2 = errs + 128;
  float* rsA[2] = { rsA0, rsA1 };
  float* csA[2] = { csA0, csA1 };
  float* rsB[2] = { rsB0, rsB1 };
  float* csB[2] = { csB0, csB1 };

  detect_kernel<<<1, 64, 0, stream>>>(img, misc);
  init_kernel<<<65, 256, 0, stream>>>(ls, vecs, errs, rsA0, csA0, misc);
  gemm_kernel<<<dim3(64, 64), 256, 0, stream>>>(img, txt, S, gmin, misc);
  colvec_kernel<<<1024, 256, 0, stream>>>(img, txt, tno, S, colvals, opP, misc);
  reduce_kernel<<<1, 256, 0, stream>>>(gmin, colvals, opP, misc);

  preds_kernel<<<1024, 256, 0, stream>>>(S, misc, preds);
  rank_kernel<<<32, 128, 0, stream>>>(preds, is_nc);

  const dim3 sg(33, 32);
  for (int k = 0; k < 100; ++k) {
    const int p = k & 1, q = (k + 1) & 1;
    const int pm = (k > 0) ? ((k - 1) & 1) : 0;
    /* role A: out rowsumA[p], colsumA[p]; zero csB[p], rsB[p] */
    sink_step<<<sg, 256, 0, stream>>>(S, misc, errs1, errs2,
        uvec, utvec, vvec, vtvec,
        rsB[pm], csB[pm], rsA[p], csA[p],
        csB[p], rsB[p], 4104, 4096,
        k, 0, 0, is_nc);
    /* role B: out rowsumB[p], colsumB[p]; zero rsA[q], csA[q] */
    sink_step<<<sg, 256, 0, stream>>>(S, misc, errs1, errs2,
        uvec, utvec, vvec, vtvec,
        rsA[p], csA[p], rsB[p], csB[p],
        rsA[q], csA[q], 4096, 4104,
        k, 1, 0, is_nc);
  }
  /* finalize: role A, k=100 -> write final vvec/vtvec if still active */
  sink_step<<<sg, 256, 0, stream>>>(S, misc, errs1, errs2,
      uvec, utvec, vvec, vtvec,
      rsB[1], csB[1], rsA[0], csA[0],
      csB[0], rsB[0], 4104, 4096,
      100, 0, 1, is_nc);

  final_pass<<<dim3(17, 16), 256, 0, stream>>>(S, vvec, vtvec, misc, is_nc,
                                               rowLm, rowLs, rowGs, colLm, colLs, colGs);
  final_combine<<<33, 256, 0, stream>>>(rowLm, rowLs, rowGs, colLm, colLs, colGs,
                                        LSMrow, LBLm, LBLs, LSMcol, LBTm, LBTs);
  loss_pass<<<dim3(17, 16), 256, 0, stream>>>(S, vvec, vtvec, misc, is_nc,
                                              LSMrow, LBLm, LBLs, LSMcol, LBTm, LBTs, imgP, txtP);
  finish_kernel<<<1, 256, 0, stream>>>(imgP, txtP, misc, out);
}


// Round 18
// 1017.386 us; speedup vs baseline: 4.1106x; 1.3818x over previous
//

#include <hip/hip_runtime.h>
#include <hip/hip_bf16.h>

// ROUND 18 (round 17: 1405.8 us, absmax 0.0; rocprof: gemm_kernel 511 us,
// MfmaUtil=0, 1.8e8 LDS bank conflicts):
//  - Replace VALU fp32 GEMM with bf16 MFMA GEMM (mfma_f32_16x16x32_bf16),
//    128x128 block tile, 2x2 waves, 4x4 mfma tiles/wave, direct global
//    fragment loads (16B/lane), no LDS in the hot loop.
//  - cvt_kernel: one-time f32/bf16 -> bf16 planes for img/txt (8 MB ws).
//  - reduce_kernel min-scan bound updated to the 1024-block gmin.

#define NN 4096
#define LDA 4104          /* fp16 row stride for S (4097 padded to x8) */
#define DD 512
#define NCNUM 409         /* int(0.1*4096) */
#define REGc 0.03f
#define INVREG (1.0f/0.03f)
#define GAM 0.8f
#define THRESHc 1e-4f
#define LOGN 8.3177661667193433f   /* ln(4096) */
#define LOGM 8.3180102775477533f   /* ln(4097) */
#define NEGINF (-__builtin_inff())

typedef unsigned short u16;
typedef unsigned int u32;
typedef _Float16 f16;

struct alignas(16) Q  { u32 x, y, z, w; };
struct alignas(8)  Q2 { u32 x, y; };
struct alignas(16) F4 { float a, b, c, d; };
union H8 { Q q; f16 h[8]; };

typedef __attribute__((ext_vector_type(8))) short frag_ab;   /* 8 bf16 */
typedef __attribute__((ext_vector_type(4))) float frag_cd;   /* 4 f32  */

__device__ __forceinline__ float bf2f(u32 u) { return __uint_as_float(u << 16); }
__device__ __forceinline__ float bflo(u32 w) { return __uint_as_float(w << 16); }
__device__ __forceinline__ float bfhi(u32 w) { return __uint_as_float(w & 0xFFFF0000u); }
__device__ __forceinline__ u16 f2bf_rne(float f) {
  u32 b = __float_as_uint(f);
  b += 0x7FFFu + ((b >> 16) & 1u);
  return (u16)(b >> 16);
}
__device__ __forceinline__ u16 f2h_hw(float f) {
  union { f16 h; u16 u; } X; X.h = (f16)f; return X.u;
}
__device__ __forceinline__ float h2f_hw(u16 v) {
  union { u16 u; f16 h; } X; X.u = v; return (float)X.h;
}
__device__ __forceinline__ void unpack8(Q q, float* x) {
  H8 u; u.q = q;
  #pragma unroll
  for (int c = 0; c < 8; ++c) x[c] = (float)u.h[c];
}
__device__ __forceinline__ void lse_merge(float& m, float& s, float om, float os) {
  float nm = fmaxf(m, om);
  if (nm == NEGINF) return;
  float acc = 0.f;
  if (s  > 0.f) acc += s  * __expf(m  - nm);
  if (os > 0.f) acc += os * __expf(om - nm);
  m = nm; s = acc;
}
__device__ __forceinline__ float blockReduce256(float v) {
  __shared__ float sh[4];
  #pragma unroll
  for (int off = 32; off >= 1; off >>= 1) v += __shfl_xor(v, off);
  int w = threadIdx.x >> 6;
  if ((threadIdx.x & 63) == 0) sh[w] = v;
  __syncthreads();
  float r = 0.f;
  if (threadIdx.x == 0) r = sh[0] + sh[1] + sh[2] + sh[3];
  __syncthreads();
  return r;
}

__global__ void ContrastiveLoss_83391085019222_kernel(float* out) {
  if (threadIdx.x == 0) { out[0] = 0.5f; out[1] = 0.5f; }
}
__global__ void diag_kernel(float* out, float a, float b) {
  if (threadIdx.x == 0) { out[0] = a; out[1] = b; }
}

/* ---- dtype autodetect: inputs are unit-normalized rows ---- */
__global__ void detect_kernel(const u16* img, float* misc) {
  const int lane = threadIdx.x;  /* 64 */
  float nb = 0.f, nf = 0.f;
  const float* fimg = (const float*)img;
  for (int c = lane * 8; c < lane * 8 + 8; ++c) {
    float xb = bf2f((u32)img[c]);
    nb += xb * xb;
    float xf = fimg[c];
    if (fabsf(xf) < 1e10f) nf += xf * xf; else nf += 1e10f;
  }
  #pragma unroll
  for (int off = 32; off >= 1; off >>= 1) { nb += __shfl_xor(nb, off); nf += __shfl_xor(nf, off); }
  if (lane == 0) {
    float db = fabsf(nb - 1.f);
    float df = fabsf(nf - 1.f);
    if (!(db == db)) db = 1e30f;
    if (!(df == df)) df = 1e30f;
    ((int*)misc)[10] = (df < db) ? 1 : 0;   /* 1 = float32 inputs */
  }
}

/* ---- convert img/txt to bf16 planes (handles f32 or bf16 input) ---- */
__global__ void cvt_kernel(const u16* img, const u16* txt,
                           u16* Abf, u16* Bbf, const float* misc) {
  const int isF = ((const int*)misc)[10];
  const int t = blockIdx.x * 256 + threadIdx.x;   /* grid 2048 -> 524288 x4 */
  const int base = t * 4;
  if (isF) {
    const float* fi = (const float*)img;
    const float* ft = (const float*)txt;
    ushort4 oa, ob;
    oa.x = f2bf_rne(fi[base+0]); oa.y = f2bf_rne(fi[base+1]);
    oa.z = f2bf_rne(fi[base+2]); oa.w = f2bf_rne(fi[base+3]);
    ob.x = f2bf_rne(ft[base+0]); ob.y = f2bf_rne(ft[base+1]);
    ob.z = f2bf_rne(ft[base+2]); ob.w = f2bf_rne(ft[base+3]);
    *(ushort4*)(Abf + base) = oa;
    *(ushort4*)(Bbf + base) = ob;
  } else {
    *(ushort4*)(Abf + base) = *(const ushort4*)(img + base);
    *(ushort4*)(Bbf + base) = *(const ushort4*)(txt + base);
  }
}

/* init: zero vecs(16400) + errs(256) + rsA0(4096) + csA0(4104), scale */
__global__ void init_kernel(const u16* ls, float* vecs, float* errs,
                            float* rsA0, float* csA0, float* misc) {
  int t = blockIdx.x * 256 + threadIdx.x;
  if (t < 16400) vecs[t] = 0.f;
  if (t < 256)  errs[t] = 0.f;
  if (t < 4096) rsA0[t] = 0.f;
  if (t < 4104) csA0[t] = 0.f;
  if (t == 0) {
    const int isF = ((const int*)misc)[10];
    float lsv = isF ? ((const float*)ls)[0] : bf2f((u32)ls[0]);
    misc[0] = __expf(lsv);               /* scale = exp(logit_scale) */
  }
}

/* ------- MFMA GEMM: S = Abf x Bbf^T -> fp16 + per-block min -------
   128x128 block tile; 4 waves (2x2); each wave 4x4 tiles of 16x16.
   A frag: lane holds A[m=lane&15][k=quad*8+j]; B^T input symmetric.
   C/D:   col=lane&15, row=quad*4+reg. */
__global__ __launch_bounds__(256) void gemm_mfma(const u16* Abf, const u16* Bbf,
                                                 u16* S, float* gmin) {
  __shared__ float red[256];
  const int tid = threadIdx.x;
  const int wave = tid >> 6, lane = tid & 63;
  const int wr = wave >> 1, wc = wave & 1;
  const int rb = (int)blockIdx.y * 128 + wr * 64;
  const int cb = (int)blockIdx.x * 128 + wc * 64;
  const int l15 = lane & 15, q = lane >> 4;

  frag_cd acc[4][4];
  #pragma unroll
  for (int i = 0; i < 4; ++i)
    #pragma unroll
    for (int j = 0; j < 4; ++j) acc[i][j] = (frag_cd){0.f, 0.f, 0.f, 0.f};

  for (int kt = 0; kt < DD; kt += 32) {
    frag_ab af[4], bfr[4];
    #pragma unroll
    for (int t = 0; t < 4; ++t) {
      af[t]  = *(const frag_ab*)(Abf + (size_t)(rb + t*16 + l15) * DD + kt + q*8);
      bfr[t] = *(const frag_ab*)(Bbf + (size_t)(cb + t*16 + l15) * DD + kt + q*8);
    }
    #pragma unroll
    for (int i = 0; i < 4; ++i)
      #pragma unroll
      for (int j = 0; j < 4; ++j)
        acc[i][j] = __builtin_amdgcn_mfma_f32_16x16x32_bf16(af[i], bfr[j], acc[i][j], 0, 0, 0);
  }

  float lmin = 1e30f;
  #pragma unroll
  for (int i = 0; i < 4; ++i) {
    #pragma unroll
    for (int j = 0; j < 4; ++j) {
      #pragma unroll
      for (int r = 0; r < 4; ++r) {
        const int row = rb + i*16 + q*4 + r;
        const int col = cb + j*16 + l15;
        u16 h = f2h_hw(acc[i][j][r]);
        lmin = fminf(lmin, h2f_hw(h));
        S[(size_t)row * LDA + col] = h;
      }
    }
  }
  red[tid] = lmin;
  __syncthreads();
  for (int sN = 128; sN >= 1; sN >>= 1) {
    if (tid < sN) red[tid] = fminf(red[tid], red[tid + sN]);
    __syncthreads();
  }
  if (tid == 0) gmin[blockIdx.y * 32 + blockIdx.x] = red[0];
}

/* ------- sims_no -> S col NN + loss_op partial ------- */
__global__ void colvec_kernel(const u16* img, const u16* txt, const u16* tno,
                              u16* S, float* colvals, float* opP, const float* misc) {
  __shared__ float shOp[4];
  const int isF = ((const int*)misc)[10];
  const int wv = threadIdx.x >> 6;
  const int row = (int)(blockIdx.x << 2) + wv;
  const int lane = threadIdx.x & 63;
  const size_t base = (size_t)row * DD + lane * 8;
  float xi[8], xt[8], xn[8];
  if (isF) {
    const float* fi = (const float*)img;
    const float* ft = (const float*)txt;
    const float* fn = (const float*)tno;
    #pragma unroll
    for (int c = 0; c < 8; ++c) { xi[c] = fi[base+c]; xt[c] = ft[base+c]; xn[c] = fn[base+c]; }
  } else {
    Q qi = *(const Q*)(img + base);
    Q qt = *(const Q*)(txt + base);
    Q qn = *(const Q*)(tno + base);
    xi[0]=bflo(qi.x); xi[1]=bfhi(qi.x); xi[2]=bflo(qi.y); xi[3]=bfhi(qi.y);
    xi[4]=bflo(qi.z); xi[5]=bfhi(qi.z); xi[6]=bflo(qi.w); xi[7]=bfhi(qi.w);
    xt[0]=bflo(qt.x); xt[1]=bfhi(qt.x); xt[2]=bflo(qt.y); xt[3]=bfhi(qt.y);
    xt[4]=bflo(qt.z); xt[5]=bfhi(qt.z); xt[6]=bflo(qt.w); xt[7]=bfhi(qt.w);
    xn[0]=bflo(qn.x); xn[1]=bfhi(qn.x); xn[2]=bflo(qn.y); xn[3]=bfhi(qn.y);
    xn[4]=bflo(qn.z); xn[5]=bfhi(qn.z); xn[6]=bflo(qn.w); xn[7]=bfhi(qn.w);
  }
  float sn = 0.f, cs = 0.f;
  #pragma unroll
  for (int c = 0; c < 8; ++c) { sn += xi[c]*xn[c]; cs += xt[c]*xn[c]; }
  #pragma unroll
  for (int off = 32; off >= 1; off >>= 1) { sn += __shfl_xor(sn, off); cs += __shfl_xor(cs, off); }
  if (lane == 0) {
    colvals[row] = sn;
    S[(size_t)row * LDA + NN] = f2h_hw(sn);
    shOp[wv] = fmaxf(cs + 0.2f, 0.f) + fmaxf(-0.7f - cs, 0.f);
  }
  __syncthreads();
  if (threadIdx.x == 0) opP[blockIdx.x] = shOp[0] + shOp[1] + shOp[2] + shOp[3];
}

__global__ void reduce_kernel(const float* gmin, const float* colvals,
                              const float* opP, float* misc) {
  __shared__ float smin[256];
  __shared__ float ssum[256];
  float mn = 1e30f, sm = 0.f;
  for (int i = threadIdx.x; i < 1024; i += 256) mn = fminf(mn, gmin[i]);
  for (int i = threadIdx.x; i < 4096; i += 256) mn = fminf(mn, h2f_hw(f2h_hw(colvals[i])));
  for (int i = threadIdx.x; i < 1024; i += 256) sm += opP[i];
  smin[threadIdx.x] = mn; ssum[threadIdx.x] = sm;
  __syncthreads();
  for (int sN = 128; sN >= 1; sN >>= 1) {
    if (threadIdx.x < sN) {
      smin[threadIdx.x] = fminf(smin[threadIdx.x], smin[threadIdx.x + sN]);
      ssum[threadIdx.x] += ssum[threadIdx.x + sN];
    }
    __syncthreads();
  }
  if (threadIdx.x == 0) {
    float maxC = 1.0f - smin[0];         /* max(1-S) = 1 - min(S) */
    float a = 1.0f / (maxC * REGc);
    misc[1] = a;
    misc[4] = ssum[0];
    misc[5] = __expf(-a);                /* ea */
  }
}

__global__ void preds_kernel(const u16* S, const float* misc, float* preds) {
  const int row = (int)(blockIdx.x << 2) + (int)(threadIdx.x >> 6);
  const int lane = threadIdx.x & 63;
  const float scale = misc[0];
  const u16* Sr = S + (size_t)row * LDA;
  float m = NEGINF, s = 0.f;
  for (int it = 0; it < 8; ++it) {
    const int j0 = (it << 9) + (lane << 3);
    float x[8];
    unpack8(*(const Q*)(Sr + j0), x);
    float lm = NEGINF;
    #pragma unroll
    for (int c = 0; c < 8; ++c) { x[c] *= scale; lm = fmaxf(lm, x[c]); }
    float lsum = 0.f;
    #pragma unroll
    for (int c = 0; c < 8; ++c) lsum += __expf(x[c] - lm);
    lse_merge(m, s, lm, lsum);
  }
  #pragma unroll
  for (int off = 32; off >= 1; off >>= 1) {
    float om = __shfl_xor(m, off), os = __shfl_xor(s, off);
    lse_merge(m, s, om, os);
  }
  if (lane == 0) {
    float sii = h2f_hw(Sr[row]);
    preds[row] = __expf(scale * sii - m) / s;
  }
}

__global__ void rank_kernel(const float* preds, int* is_nc) {
  __shared__ float sp[NN];
  for (int idx = threadIdx.x; idx < NN; idx += 128) sp[idx] = preds[idx];
  __syncthreads();
  const int i = blockIdx.x * 128 + threadIdx.x;
  const float pv = sp[i];
  int cnt = 0;
  for (int k2 = 0; k2 < NN; ++k2) {
    float pk = sp[k2];
    cnt += (pk < pv || (pk == pv && k2 < i)) ? 1 : 0;
  }
  is_nc[i] = (cnt < NCNUM) ? 1 : 0;
}

__device__ __forceinline__ bool unmasked(int j, int r, bool ncr) {
  return (j == NN) ? ncr : !((j == r) && ncr);
}

/* ------- fused sinkhorn step (multiplicative domain) ------- */
__global__ void sink_step(const u16* S, const float* misc,
                          float* errs1, float* errs2,
                          float* u, float* ut, float* vvec, float* vtvec,
                          const float* prevRow, const float* prevCol,
                          float* outRow, float* outCol,
                          float* zero1, float* zero2, int nz1, int nz2,
                          int k, int roleB, int finalOnly,
                          const int* is_nc) {
  __shared__ float shW1[128];
  __shared__ float shW2[128];
  __shared__ float shAcc[16][128];
  __shared__ int   shG[4];
  __shared__ float se[4];
  const int tid = threadIdx.x;
  const int ct = blockIdx.x, rt = blockIdx.y;
  const int cbase = ct << 7, r0 = rt << 7;
  const float a = misc[1], ea = misc[5];

  if (!finalOnly) {
    int bid = (int)blockIdx.y * 33 + (int)blockIdx.x;
    int tot = nz1 + nz2;
    for (int z = bid * 256 + tid; z < tot; z += 1056 * 256) {
      if (z < nz1) zero1[z] = 0.f; else zero2[z - nz1] = 0.f;
    }
  }
  if (tid == 0) {
    shG[0] = (k >= 1) && (errs1[k-1] < THRESHc);
    shG[1] = (k >= 1) && (errs2[k-1] < THRESHc);
    shG[2] = (k >= 2) && (errs1[k-2] < THRESHc);
    shG[3] = (k >= 2) && (errs2[k-2] < THRESHc);
  }
  __syncthreads();
  const int c1 = shG[0], c2 = shG[1], c1p = shG[2], c2p = shG[3];
  const int gRow = roleB ? c2 : c1;
  const int gCol = roleB ? c1 : c2;

  float errd = 0.f;
  if (tid < 128) {
    const int i = r0 + tid;
    float w = 0.f;
    if (!roleB) {
      if (!finalOnly && !gCol) w = (k == 0) ? ea : ea / (4096.0f * prevRow[i]);
      if (ct == 0 && k >= 1 && !c2p) vtvec[i] = REGc * (-LOGN - __logf(prevRow[i]));
    } else {
      if (!gCol) {
        w = ea / (4096.0f * prevRow[i]);
        if (ct == 0) {
          float un = REGc * (-LOGN - __logf(prevRow[i]));
          errd = fabsf(un - u[i]);
          u[i] = un;
        }
      }
    }
    shW2[tid] = w;
  } else {
    const int j = cbase + (tid - 128);
    float w = 0.f;
    if (j <= NN) {
      if (!roleB) {
        if (!finalOnly && !gRow) w = (k == 0) ? ea : ea / (4097.0f * prevCol[j]);
        if (rt == 0 && k >= 1 && !c1p) vvec[j] = REGc * (-LOGM - __logf(prevCol[j]));
      } else {
        if (!gRow) {
          w = ea / (4097.0f * prevCol[j]);
          if (rt == 0) {
            float un = REGc * (-LOGM - __logf(prevCol[j]));
            errd = fabsf(un - ut[j]);
            ut[j] = un;
          }
        }
      }
    }
    shW1[tid - 128] = w;
  }
  __syncthreads();

  if (!finalOnly && !(gRow && gCol)) {
    const int tc = tid & 15, tr = tid >> 4;
    const int j0c = tc << 3;
    const int j0 = cbase + j0c;
    const bool anyv = (j0 <= NN);
    unsigned jval = 0;
    #pragma unroll
    for (int c = 0; c < 8; ++c) if (j0 + c <= NN) jval |= 1u << c;
    float W1l[8];
    #pragma unroll
    for (int c = 0; c < 8; ++c) W1l[c] = shW1[j0c + c];
    float cs[8];
    #pragma unroll
    for (int c = 0; c < 8; ++c) cs[c] = 0.f;
    for (int st = 0; st < 8; ++st) {
      const int rr = (st << 4) + tr;
      const int r = r0 + rr;
      float E[8];
      if (anyv) {
        float xv[8];
        unpack8(*(const Q*)(S + (size_t)r * LDA + j0), xv);
        const bool ncr = (is_nc[r] != 0);
        #pragma unroll
        for (int c = 0; c < 8; ++c) {
          E[c] = __expf(xv[c] * a);
          if (!((jval >> c & 1u) && unmasked(j0 + c, r, ncr))) E[c] = 0.f;
        }
      } else {
        #pragma unroll
        for (int c = 0; c < 8; ++c) E[c] = 0.f;
      }
      if (!gCol) {
        float Wr = shW2[rr];
        #pragma unroll
        for (int c = 0; c < 8; ++c) cs[c] = fmaf(E[c], Wr, cs[c]);
      }
      if (!gRow) {
        float rs = 0.f;
        #pragma unroll
        for (int c = 0; c < 8; ++c) rs = fmaf(E[c], W1l[c], rs);
        #pragma unroll
        for (int off = 8; off >= 1; off >>= 1) rs += __shfl_xor(rs, off);
        if (tc == 0) atomicAdd(&outRow[r], rs);
      }
    }
    if (!gCol) {
      #pragma unroll
      for (int c = 0; c < 8; ++c) shAcc[tr][j0c + c] = cs[c];
      __syncthreads();
      if (tid < 128) {
        float s = 0.f;
        #pragma unroll
        for (int g = 0; g < 16; ++g) s += shAcc[g][tid];
        const int j = cbase + tid;
        if (j <= NN) atomicAdd(&outCol[j], s);
      }
    }
  }

  if (roleB) {
    #pragma unroll
    for (int off = 32; off >= 1; off >>= 1) errd += __shfl_xor(errd, off);
    if ((tid & 63) == 0) se[tid >> 6] = errd;
    __syncthreads();
    if (tid == 0) {
      if (ct == 0) atomicAdd(&errs1[k], se[0] + se[1]);
      if (rt == 0) atomicAdd(&errs2[k], se[2] + se[3]);
    }
  }
}

/* ------- final pass 1: logit sums + masked label LSEs (row & col) ------- */
__global__ void final_pass(const u16* S, const float* vvec, const float* vtvec,
                           const float* misc, const int* is_nc,
                           float* rowLm, float* rowLs, float* rowGs,
                           float* colLm, float* colLs, float* colGs) {
  const float a = misc[1], scale = misc[0];
  const int ct = blockIdx.x, rt = blockIdx.y;
  const int tid = threadIdx.x;
  const int tc = tid & 31, tr = tid >> 5;
  const int cbase = ct << 8, r0 = rt << 8;
  const int j0 = cbase + (tc << 3);
  const bool anyv = (j0 <= NN);
  float wc[8]; unsigned jval = 0;
  #pragma unroll
  for (int c = 0; c < 8; ++c) {
    int j = j0 + c;
    wc[c] = 0.f;
    if (j <= NN) { jval |= 1u << c; wc[c] = vvec[j] * INVREG; }
  }
  float cLm[8], cLs[8], cGs[8];
  #pragma unroll
  for (int c = 0; c < 8; ++c) { cLm[c] = NEGINF; cLs[c] = 0.f; cGs[c] = 0.f; }
  for (int st = 0; st < 32; ++st) {
    const int r = r0 + (st << 3) + tr;
    float xv[8], lg[8]; unsigned um = 0;
    #pragma unroll
    for (int c = 0; c < 8; ++c) { xv[c] = 0.f; lg[c] = 0.f; }
    if (anyv) {
      float raw[8];
      unpack8(*(const Q*)(S + (size_t)r * LDA + j0), raw);
      const bool ncr = (is_nc[r] != 0);
      const float vtr = vtvec[r] * INVREG;
      #pragma unroll
      for (int c = 0; c < 8; ++c) {
        if (!(jval >> c & 1u)) continue;
        xv[c] = raw[c] * a;
        lg[c] = scale * raw[c];
        cGs[c] += __expf(lg[c]);
        if (unmasked(j0 + c, r, ncr)) {
          um |= 1u << c;
          float e2 = xv[c] + vtr;
          float nm = fmaxf(cLm[c], e2);
          cLs[c] = cLs[c] * __expf(cLm[c] - nm) + __expf(e2 - nm);
          cLm[c] = nm;
        }
      }
    }
    float rsG = 0.f;
    if (anyv) {
      #pragma unroll
      for (int c = 0; c < 8; ++c) if (jval >> c & 1u) rsG += __expf(lg[c]);
    }
    #pragma unroll
    for (int off = 16; off >= 1; off >>= 1) rsG += __shfl_xor(rsG, off);
    float rmL = NEGINF;
    if (anyv) {
      #pragma unroll
      for (int c = 0; c < 8; ++c) if (um >> c & 1u) rmL = fmaxf(rmL, xv[c] + wc[c]);
    }
    #pragma unroll
    for (int off = 16; off >= 1; off >>= 1) rmL = fmaxf(rmL, __shfl_xor(rmL, off));
    float rsL = 0.f;
    if (anyv && rmL > NEGINF) {
      #pragma unroll
      for (int c = 0; c < 8; ++c) if (um >> c & 1u) rsL += __expf(xv[c] + wc[c] - rmL);
    }
    #pragma unroll
    for (int off = 16; off >= 1; off >>= 1) rsL += __shfl_xor(rsL, off);
    if (tc == 0) {
      rowGs[ct * NN + r] = rsG;
      rowLm[ct * NN + r] = rmL;
      rowLs[ct * NN + r] = rsL;
    }
  }
  __shared__ float shm[8][256];
  __shared__ float shs[8][256];
  #pragma unroll
  for (int c = 0; c < 8; ++c) { shm[tr][(tc << 3) + c] = cLm[c]; shs[tr][(tc << 3) + c] = cLs[c]; }
  __syncthreads();
  {
    float m = NEGINF, s = 0.f;
    #pragma unroll
    for (int g = 0; g < 8; ++g) lse_merge(m, s, shm[g][tid], shs[g][tid]);
    const int j = cbase + tid;
    if (j <= NN) { colLm[rt * LDA + j] = m; colLs[rt * LDA + j] = s; }
  }
  __syncthreads();
  #pragma unroll
  for (int c = 0; c < 8; ++c) shs[tr][(tc << 3) + c] = cGs[c];
  __syncthreads();
  {
    float s = 0.f;
    #pragma unroll
    for (int g = 0; g < 8; ++g) s += shs[g][tid];
    const int j = cbase + tid;
    if (j <= NN) colGs[rt * LDA + j] = s;
  }
}

__global__ void final_combine(const float* rowLm, const float* rowLs, const float* rowGs,
                              const float* colLm, const float* colLs, const float* colGs,
                              float* LSMrow, float* LBLm, float* LBLs,
                              float* LSMcol, float* LBTm, float* LBTs) {
  const int b = blockIdx.x;
  if (b < 16) {
    const int i = (b << 8) + threadIdx.x;
    float m = NEGINF, s = 0.f, sg = 0.f;
    for (int t = 0; t < 17; ++t) {
      lse_merge(m, s, rowLm[t * NN + i], rowLs[t * NN + i]);
      sg += rowGs[t * NN + i];
    }
    LBLm[i] = m; LBLs[i] = s;
    LSMrow[i] = __logf(sg);
  } else {
    const int j = ((b - 16) << 8) + threadIdx.x;
    if (j <= NN) {
      float m = NEGINF, s = 0.f, sg = 0.f;
      for (int t = 0; t < 16; ++t) {
        lse_merge(m, s, colLm[t * LDA + j], colLs[t * LDA + j]);
        sg += colGs[t * LDA + j];
      }
      LBTm[j] = m; LBTs[j] = s;
      LSMcol[j] = __logf(sg);
    }
  }
}

/* ------- final pass 2: KL sums for both orientations ------- */
__global__ void loss_pass(const u16* S, const float* vvec, const float* vtvec,
                          const float* misc, const int* is_nc,
                          const float* LSMrow, const float* LBLm, const float* LBLs,
                          const float* LSMcol, const float* LBTm, const float* LBTs,
                          float* imgP, float* txtP) {
  const float a = misc[1], scale = misc[0];
  const int ct = blockIdx.x, rt = blockIdx.y;
  const int tid = threadIdx.x;
  const int tc = tid & 31, tr = tid >> 5;
  const int cbase = ct << 8, r0 = rt << 8;
  const int j0 = cbase + (tc << 3);
  const bool anyv = (j0 <= NN);
  float vcw[8], bm[8], bsi[8], cg[8]; unsigned jval = 0;
  #pragma unroll
  for (int c = 0; c < 8; ++c) {
    int j = j0 + c;
    vcw[c] = 0.f; bm[c] = 0.f; bsi[c] = 0.f; cg[c] = 0.f;
    if (j <= NN) {
      jval |= 1u << c;
      vcw[c] = vvec[j] * INVREG; bm[c] = LBTm[j]; bsi[c] = 1.f / LBTs[j]; cg[c] = LSMcol[j];
    }
  }
  float sImg = 0.f, sTxt = 0.f;
  for (int st = 0; st < 32; ++st) {
    const int r = r0 + (st << 3) + tr;
    if (anyv) {
      float raw[8];
      unpack8(*(const Q*)(S + (size_t)r * LDA + j0), raw);
      const bool ncr = (is_nc[r] != 0);
      const float vtr = vtvec[r] * INVREG;
      const float rm = LBLm[r], rsi = 1.f / LBLs[r], rg = LSMrow[r];
      #pragma unroll
      for (int c = 0; c < 8; ++c) {
        if (!(jval >> c & 1u)) continue;
        const int j = j0 + c;
        float xv = raw[c] * a;
        float lgt = scale * raw[c];
        bool unm = unmasked(j, r, ncr);
        bool lv = (j == NN) ? ncr : ((j == r) && !ncr);
        float rr = unm ? __expf(xv + vcw[c] - rm) * rsi : 0.f;
        float t = GAM * rr + (lv ? 0.2f : 0.f);
        if (t > 0.f) sImg += t * (__logf(t) - (lgt - rg));
        float r2 = unm ? __expf(xv + vtr - bm[c]) * bsi[c] : 0.f;
        float t2 = GAM * r2 + (lv ? 0.2f : 0.f);
        if (t2 > 0.f) sTxt += t2 * (__logf(t2) - (lgt - cg[c]));
      }
    }
  }
  sImg = blockReduce256(sImg);
  sTxt = blockReduce256(sTxt);
  if (tid == 0) { imgP[rt * 17 + ct] = sImg; txtP[rt * 17 + ct] = sTxt; }
}

__global__ void finish_kernel(const float* imgP, const float* txtP,
                              const float* misc, float* out) {
  float vi = 0.f, vtx = 0.f;
  for (int idx = threadIdx.x; idx < 272; idx += 256) { vi += imgP[idx]; vtx += txtP[idx]; }
  vi = blockReduce256(vi);
  vtx = blockReduce256(vtx);
  if (threadIdx.x == 0) {
    float loss_img = vi / 4096.0f;
    float loss_txt = vtx / 4097.0f;
    float loss_ul = 0.5f * (loss_img + loss_txt);
    float loss_op = misc[4] / 4096.0f;
    if (vi == 0.f && vtx == 0.f) loss_ul = 777.0f;
    if (!(loss_ul == loss_ul))   loss_ul = 888.0f;
    out[0] = loss_ul;
    out[1] = loss_op;
  }
}

extern "C" void kernel_launch(void* const* d_in, const int* in_sizes, int n_in,
                              void* d_out, int out_size, void* d_ws, size_t ws_size,
                              hipStream_t stream) {
  (void)in_sizes; (void)n_in; (void)out_size;
  const u16* img = (const u16*)d_in[0];
  const u16* txt = (const u16*)d_in[1];
  const u16* tno = (const u16*)d_in[2];
  const u16* ls  = (const u16*)d_in[3];
  float* out = (float*)d_out;

  ContrastiveLoss_83391085019222_kernel<<<1, 64, 0, stream>>>(out);

  size_t off = 0;
  char* w = (char*)d_ws;
  u16* S; u16* Abf; u16* Bbf;
  float *rsA0, *rsA1, *csA0, *csA1, *rsB0, *rsB1, *csB0, *csB1, *errs;
  float *rowLm, *rowLs, *rowGs, *colLm, *colLs, *colGs;
  float *vecs, *preds, *colvals, *gmin, *opP;
  float *LSMrow, *LBLm, *LBLs, *LSMcol, *LBTm, *LBTs, *imgP, *txtP, *misc;
  int* is_nc;
  #define ALLOC(ptr, type, nbytes) ptr = (type)(w + off); off = (off + (size_t)(nbytes) + 255) & ~(size_t)255
  ALLOC(S,      u16*,   (size_t)NN * LDA * 2);
  ALLOC(Abf,    u16*,   (size_t)NN * DD * 2);
  ALLOC(Bbf,    u16*,   (size_t)NN * DD * 2);
  ALLOC(rsA0,   float*, 4096 * 4);
  ALLOC(rsA1,   float*, 4096 * 4);
  ALLOC(csA0,   float*, 4104 * 4);
  ALLOC(csA1,   float*, 4104 * 4);
  ALLOC(rsB0,   float*, 4096 * 4);
  ALLOC(rsB1,   float*, 4096 * 4);
  ALLOC(csB0,   float*, 4104 * 4);
  ALLOC(csB1,   float*, 4104 * 4);
  ALLOC(errs,   float*, 256 * 4);
  ALLOC(rowLm,  float*, (size_t)17 * NN * 4);
  ALLOC(rowLs,  float*, (size_t)17 * NN * 4);
  ALLOC(rowGs,  float*, (size_t)17 * NN * 4);
  ALLOC(colLm,  float*, (size_t)16 * LDA * 4);
  ALLOC(colLs,  float*, (size_t)16 * LDA * 4);
  ALLOC(colGs,  float*, (size_t)16 * LDA * 4);
  ALLOC(vecs,   float*, 16400 * 4);
  ALLOC(preds,  float*, NN * 4);
  ALLOC(is_nc,  int*,   NN * 4);
  ALLOC(colvals,float*, NN * 4);
  ALLOC(gmin,   float*, 1024 * 4);
  ALLOC(opP,    float*, 1024 * 4);
  ALLOC(LSMrow, float*, NN * 4);
  ALLOC(LBLm,   float*, NN * 4);
  ALLOC(LBLs,   float*, NN * 4);
  ALLOC(LSMcol, float*, LDA * 4);
  ALLOC(LBTm,   float*, LDA * 4);
  ALLOC(LBTs,   float*, LDA * 4);
  ALLOC(imgP,   float*, 272 * 4);
  ALLOC(txtP,   float*, 272 * 4);
  ALLOC(misc,   float*, 64);
  #undef ALLOC

  if (ws_size < off) {
    diag_kernel<<<1, 64, 0, stream>>>(out, -(float)(ws_size / 1000000.0),
                                      -(float)(off / 1000000.0));
    return;
  }

  float* uvec  = vecs;
  float* vvec  = vecs + 4096;
  float* utvec = vecs + 8200;
  float* vtvec = vecs + 12304;
  float* errs1 = errs;
  float* errs2 = errs + 128;
  float* rsA[2] = { rsA0, rsA1 };
  float* csA[2] = { csA0, csA1 };
  float* rsB[2] = { rsB0, rsB1 };
  float* csB[2] = { csB0, csB1 };

  detect_kernel<<<1, 64, 0, stream>>>(img, misc);
  cvt_kernel<<<2048, 256, 0, stream>>>(img, txt, Abf, Bbf, misc);
  init_kernel<<<65, 256, 0, stream>>>(ls, vecs, errs, rsA0, csA0, misc);
  gemm_mfma<<<dim3(32, 32), 256, 0, stream>>>(Abf, Bbf, S, gmin);
  colvec_kernel<<<1024, 256, 0, stream>>>(img, txt, tno, S, colvals, opP, misc);
  reduce_kernel<<<1, 256, 0, stream>>>(gmin, colvals, opP, misc);

  preds_kernel<<<1024, 256, 0, stream>>>(S, misc, preds);
  rank_kernel<<<32, 128, 0, stream>>>(preds, is_nc);

  const dim3 sg(33, 32);
  for (int k = 0; k < 100; ++k) {
    const int p = k & 1, q = (k + 1) & 1;
    const int pm = (k > 0) ? ((k - 1) & 1) : 0;
    sink_step<<<sg, 256, 0, stream>>>(S, misc, errs1, errs2,
        uvec, utvec, vvec, vtvec,
        rsB[pm], csB[pm], rsA[p], csA[p],
        csB[p], rsB[p], 4104, 4096,
        k, 0, 0, is_nc);
    sink_step<<<sg, 256, 0, stream>>>(S, misc, errs1, errs2,
        uvec, utvec, vvec, vtvec,
        rsA[p], csA[p], rsB[p], csB[p],
        rsA[q], csA[q], 4096, 4104,
        k, 1, 0, is_nc);
  }
  sink_step<<<sg, 256, 0, stream>>>(S, misc, errs1, errs2,
      uvec, utvec, vvec, vtvec,
      rsB[1], csB[1], rsA[0], csA[0],
      csB[0], rsB[0], 4104, 4096,
      100, 0, 1, is_nc);

  final_pass<<<dim3(17, 16), 256, 0, stream>>>(S, vvec, vtvec, misc, is_nc,
                                               rowLm, rowLs, rowGs, colLm, colLs, colGs);
  final_combine<<<33, 256, 0, stream>>>(rowLm, rowLs, rowGs, colLm, colLs, colGs,
                                        LSMrow, LBLm, LBLs, LSMcol, LBTm, LBTs);
  loss_pass<<<dim3(17, 16), 256, 0, stream>>>(S, vvec, vtvec, misc, is_nc,
                                              LSMrow, LBLm, LBLs, LSMcol, LBTm, LBTs, imgP, txtP);
  finish_kernel<<<1, 256, 0, stream>>>(imgP, txtP, misc, out);
}


// Round 19
// 928.029 us; speedup vs baseline: 4.5064x; 1.0963x over previous
//

#include <hip/hip_runtime.h>
#include <hip/hip_bf16.h>

// ROUND 19 (round 18: 1017.4 us, absmax 0.0; top dispatch rank_kernel 102 us
// at 0.7% occupancy):
//  - rank_kernel: one block per row (4096 blocks x 256 thr) -> ~8 us.
//  - sink_step: grid swapped to (32 row-tiles, 33 col-tiles) so linear block
//    id % 8 == rowtile % 8 -> per-XCD L2 affinity (4 row-stripes ~= 4.2 MB
//    per XCD, stable across all 201 launches).

#define NN 4096
#define LDA 4104          /* fp16 row stride for S (4097 padded to x8) */
#define DD 512
#define NCNUM 409         /* int(0.1*4096) */
#define REGc 0.03f
#define INVREG (1.0f/0.03f)
#define GAM 0.8f
#define THRESHc 1e-4f
#define LOGN 8.3177661667193433f   /* ln(4096) */
#define LOGM 8.3180102775477533f   /* ln(4097) */
#define NEGINF (-__builtin_inff())

typedef unsigned short u16;
typedef unsigned int u32;
typedef _Float16 f16;

struct alignas(16) Q  { u32 x, y, z, w; };
struct alignas(8)  Q2 { u32 x, y; };
struct alignas(16) F4 { float a, b, c, d; };
union H8 { Q q; f16 h[8]; };

typedef __attribute__((ext_vector_type(8))) short frag_ab;   /* 8 bf16 */
typedef __attribute__((ext_vector_type(4))) float frag_cd;   /* 4 f32  */

__device__ __forceinline__ float bf2f(u32 u) { return __uint_as_float(u << 16); }
__device__ __forceinline__ float bflo(u32 w) { return __uint_as_float(w << 16); }
__device__ __forceinline__ float bfhi(u32 w) { return __uint_as_float(w & 0xFFFF0000u); }
__device__ __forceinline__ u16 f2bf_rne(float f) {
  u32 b = __float_as_uint(f);
  b += 0x7FFFu + ((b >> 16) & 1u);
  return (u16)(b >> 16);
}
__device__ __forceinline__ u16 f2h_hw(float f) {
  union { f16 h; u16 u; } X; X.h = (f16)f; return X.u;
}
__device__ __forceinline__ float h2f_hw(u16 v) {
  union { u16 u; f16 h; } X; X.u = v; return (float)X.h;
}
__device__ __forceinline__ void unpack8(Q q, float* x) {
  H8 u; u.q = q;
  #pragma unroll
  for (int c = 0; c < 8; ++c) x[c] = (float)u.h[c];
}
__device__ __forceinline__ void lse_merge(float& m, float& s, float om, float os) {
  float nm = fmaxf(m, om);
  if (nm == NEGINF) return;
  float acc = 0.f;
  if (s  > 0.f) acc += s  * __expf(m  - nm);
  if (os > 0.f) acc += os * __expf(om - nm);
  m = nm; s = acc;
}
__device__ __forceinline__ float blockReduce256(float v) {
  __shared__ float sh[4];
  #pragma unroll
  for (int off = 32; off >= 1; off >>= 1) v += __shfl_xor(v, off);
  int w = threadIdx.x >> 6;
  if ((threadIdx.x & 63) == 0) sh[w] = v;
  __syncthreads();
  float r = 0.f;
  if (threadIdx.x == 0) r = sh[0] + sh[1] + sh[2] + sh[3];
  __syncthreads();
  return r;
}

__global__ void ContrastiveLoss_83391085019222_kernel(float* out) {
  if (threadIdx.x == 0) { out[0] = 0.5f; out[1] = 0.5f; }
}
__global__ void diag_kernel(float* out, float a, float b) {
  if (threadIdx.x == 0) { out[0] = a; out[1] = b; }
}

/* ---- dtype autodetect: inputs are unit-normalized rows ---- */
__global__ void detect_kernel(const u16* img, float* misc) {
  const int lane = threadIdx.x;  /* 64 */
  float nb = 0.f, nf = 0.f;
  const float* fimg = (const float*)img;
  for (int c = lane * 8; c < lane * 8 + 8; ++c) {
    float xb = bf2f((u32)img[c]);
    nb += xb * xb;
    float xf = fimg[c];
    if (fabsf(xf) < 1e10f) nf += xf * xf; else nf += 1e10f;
  }
  #pragma unroll
  for (int off = 32; off >= 1; off >>= 1) { nb += __shfl_xor(nb, off); nf += __shfl_xor(nf, off); }
  if (lane == 0) {
    float db = fabsf(nb - 1.f);
    float df = fabsf(nf - 1.f);
    if (!(db == db)) db = 1e30f;
    if (!(df == df)) df = 1e30f;
    ((int*)misc)[10] = (df < db) ? 1 : 0;   /* 1 = float32 inputs */
  }
}

/* ---- convert img/txt to bf16 planes ---- */
__global__ void cvt_kernel(const u16* img, const u16* txt,
                           u16* Abf, u16* Bbf, const float* misc) {
  const int isF = ((const int*)misc)[10];
  const int t = blockIdx.x * 256 + threadIdx.x;
  const int base = t * 4;
  if (isF) {
    const float* fi = (const float*)img;
    const float* ft = (const float*)txt;
    ushort4 oa, ob;
    oa.x = f2bf_rne(fi[base+0]); oa.y = f2bf_rne(fi[base+1]);
    oa.z = f2bf_rne(fi[base+2]); oa.w = f2bf_rne(fi[base+3]);
    ob.x = f2bf_rne(ft[base+0]); ob.y = f2bf_rne(ft[base+1]);
    ob.z = f2bf_rne(ft[base+2]); ob.w = f2bf_rne(ft[base+3]);
    *(ushort4*)(Abf + base) = oa;
    *(ushort4*)(Bbf + base) = ob;
  } else {
    *(ushort4*)(Abf + base) = *(const ushort4*)(img + base);
    *(ushort4*)(Bbf + base) = *(const ushort4*)(txt + base);
  }
}

/* init: zero vecs(16400) + errs(256) + rsA0(4096) + csA0(4104), scale */
__global__ void init_kernel(const u16* ls, float* vecs, float* errs,
                            float* rsA0, float* csA0, float* misc) {
  int t = blockIdx.x * 256 + threadIdx.x;
  if (t < 16400) vecs[t] = 0.f;
  if (t < 256)  errs[t] = 0.f;
  if (t < 4096) rsA0[t] = 0.f;
  if (t < 4104) csA0[t] = 0.f;
  if (t == 0) {
    const int isF = ((const int*)misc)[10];
    float lsv = isF ? ((const float*)ls)[0] : bf2f((u32)ls[0]);
    misc[0] = __expf(lsv);               /* scale = exp(logit_scale) */
  }
}

/* ------- MFMA GEMM: S = Abf x Bbf^T -> fp16 + per-block min ------- */
__global__ __launch_bounds__(256) void gemm_mfma(const u16* Abf, const u16* Bbf,
                                                 u16* S, float* gmin) {
  __shared__ float red[256];
  const int tid = threadIdx.x;
  const int wave = tid >> 6, lane = tid & 63;
  const int wr = wave >> 1, wc = wave & 1;
  const int rb = (int)blockIdx.y * 128 + wr * 64;
  const int cb = (int)blockIdx.x * 128 + wc * 64;
  const int l15 = lane & 15, q = lane >> 4;

  frag_cd acc[4][4];
  #pragma unroll
  for (int i = 0; i < 4; ++i)
    #pragma unroll
    for (int j = 0; j < 4; ++j) acc[i][j] = (frag_cd){0.f, 0.f, 0.f, 0.f};

  for (int kt = 0; kt < DD; kt += 32) {
    frag_ab af[4], bfr[4];
    #pragma unroll
    for (int t = 0; t < 4; ++t) {
      af[t]  = *(const frag_ab*)(Abf + (size_t)(rb + t*16 + l15) * DD + kt + q*8);
      bfr[t] = *(const frag_ab*)(Bbf + (size_t)(cb + t*16 + l15) * DD + kt + q*8);
    }
    #pragma unroll
    for (int i = 0; i < 4; ++i)
      #pragma unroll
      for (int j = 0; j < 4; ++j)
        acc[i][j] = __builtin_amdgcn_mfma_f32_16x16x32_bf16(af[i], bfr[j], acc[i][j], 0, 0, 0);
  }

  float lmin = 1e30f;
  #pragma unroll
  for (int i = 0; i < 4; ++i) {
    #pragma unroll
    for (int j = 0; j < 4; ++j) {
      #pragma unroll
      for (int r = 0; r < 4; ++r) {
        const int row = rb + i*16 + q*4 + r;
        const int col = cb + j*16 + l15;
        u16 h = f2h_hw(acc[i][j][r]);
        lmin = fminf(lmin, h2f_hw(h));
        S[(size_t)row * LDA + col] = h;
      }
    }
  }
  red[tid] = lmin;
  __syncthreads();
  for (int sN = 128; sN >= 1; sN >>= 1) {
    if (tid < sN) red[tid] = fminf(red[tid], red[tid + sN]);
    __syncthreads();
  }
  if (tid == 0) gmin[blockIdx.y * 32 + blockIdx.x] = red[0];
}

/* ------- sims_no -> S col NN + loss_op partial ------- */
__global__ void colvec_kernel(const u16* img, const u16* txt, const u16* tno,
                              u16* S, float* colvals, float* opP, const float* misc) {
  __shared__ float shOp[4];
  const int isF = ((const int*)misc)[10];
  const int wv = threadIdx.x >> 6;
  const int row = (int)(blockIdx.x << 2) + wv;
  const int lane = threadIdx.x & 63;
  const size_t base = (size_t)row * DD + lane * 8;
  float xi[8], xt[8], xn[8];
  if (isF) {
    const float* fi = (const float*)img;
    const float* ft = (const float*)txt;
    const float* fn = (const float*)tno;
    #pragma unroll
    for (int c = 0; c < 8; ++c) { xi[c] = fi[base+c]; xt[c] = ft[base+c]; xn[c] = fn[base+c]; }
  } else {
    Q qi = *(const Q*)(img + base);
    Q qt = *(const Q*)(txt + base);
    Q qn = *(const Q*)(tno + base);
    xi[0]=bflo(qi.x); xi[1]=bfhi(qi.x); xi[2]=bflo(qi.y); xi[3]=bfhi(qi.y);
    xi[4]=bflo(qi.z); xi[5]=bfhi(qi.z); xi[6]=bflo(qi.w); xi[7]=bfhi(qi.w);
    xt[0]=bflo(qt.x); xt[1]=bfhi(qt.x); xt[2]=bflo(qt.y); xt[3]=bfhi(qt.y);
    xt[4]=bflo(qt.z); xt[5]=bfhi(qt.z); xt[6]=bflo(qt.w); xt[7]=bfhi(qt.w);
    xn[0]=bflo(qn.x); xn[1]=bfhi(qn.x); xn[2]=bflo(qn.y); xn[3]=bfhi(qn.y);
    xn[4]=bflo(qn.z); xn[5]=bfhi(qn.z); xn[6]=bflo(qn.w); xn[7]=bfhi(qn.w);
  }
  float sn = 0.f, cs = 0.f;
  #pragma unroll
  for (int c = 0; c < 8; ++c) { sn += xi[c]*xn[c]; cs += xt[c]*xn[c]; }
  #pragma unroll
  for (int off = 32; off >= 1; off >>= 1) { sn += __shfl_xor(sn, off); cs += __shfl_xor(cs, off); }
  if (lane == 0) {
    colvals[row] = sn;
    S[(size_t)row * LDA + NN] = f2h_hw(sn);
    shOp[wv] = fmaxf(cs + 0.2f, 0.f) + fmaxf(-0.7f - cs, 0.f);
  }
  __syncthreads();
  if (threadIdx.x == 0) opP[blockIdx.x] = shOp[0] + shOp[1] + shOp[2] + shOp[3];
}

__global__ void reduce_kernel(const float* gmin, const float* colvals,
                              const float* opP, float* misc) {
  __shared__ float smin[256];
  __shared__ float ssum[256];
  float mn = 1e30f, sm = 0.f;
  for (int i = threadIdx.x; i < 1024; i += 256) mn = fminf(mn, gmin[i]);
  for (int i = threadIdx.x; i < 4096; i += 256) mn = fminf(mn, h2f_hw(f2h_hw(colvals[i])));
  for (int i = threadIdx.x; i < 1024; i += 256) sm += opP[i];
  smin[threadIdx.x] = mn; ssum[threadIdx.x] = sm;
  __syncthreads();
  for (int sN = 128; sN >= 1; sN >>= 1) {
    if (threadIdx.x < sN) {
      smin[threadIdx.x] = fminf(smin[threadIdx.x], smin[threadIdx.x + sN]);
      ssum[threadIdx.x] += ssum[threadIdx.x + sN];
    }
    __syncthreads();
  }
  if (threadIdx.x == 0) {
    float maxC = 1.0f - smin[0];         /* max(1-S) = 1 - min(S) */
    float a = 1.0f / (maxC * REGc);
    misc[1] = a;
    misc[4] = ssum[0];
    misc[5] = __expf(-a);                /* ea */
  }
}

__global__ void preds_kernel(const u16* S, const float* misc, float* preds) {
  const int row = (int)(blockIdx.x << 2) + (int)(threadIdx.x >> 6);
  const int lane = threadIdx.x & 63;
  const float scale = misc[0];
  const u16* Sr = S + (size_t)row * LDA;
  float m = NEGINF, s = 0.f;
  for (int it = 0; it < 8; ++it) {
    const int j0 = (it << 9) + (lane << 3);
    float x[8];
    unpack8(*(const Q*)(Sr + j0), x);
    float lm = NEGINF;
    #pragma unroll
    for (int c = 0; c < 8; ++c) { x[c] *= scale; lm = fmaxf(lm, x[c]); }
    float lsum = 0.f;
    #pragma unroll
    for (int c = 0; c < 8; ++c) lsum += __expf(x[c] - lm);
    lse_merge(m, s, lm, lsum);
  }
  #pragma unroll
  for (int off = 32; off >= 1; off >>= 1) {
    float om = __shfl_xor(m, off), os = __shfl_xor(s, off);
    lse_merge(m, s, om, os);
  }
  if (lane == 0) {
    float sii = h2f_hw(Sr[row]);
    preds[row] = __expf(scale * sii - m) / s;
  }
}

/* ------- nc rank: one block per row, 256 threads ------- */
__global__ void rank_kernel(const float* preds, int* is_nc) {
  const int i = blockIdx.x;
  const float pv = preds[i];
  float cnt = 0.f;
  for (int k2 = threadIdx.x; k2 < NN; k2 += 256) {
    float pk = preds[k2];
    cnt += (pk < pv || (pk == pv && k2 < i)) ? 1.f : 0.f;
  }
  cnt = blockReduce256(cnt);
  if (threadIdx.x == 0) is_nc[i] = (cnt < (float)NCNUM) ? 1 : 0;
}

__device__ __forceinline__ bool unmasked(int j, int r, bool ncr) {
  return (j == NN) ? ncr : !((j == r) && ncr);
}

/* ------- fused sinkhorn step (multiplicative domain) -------
   Grid (32 row-tiles, 33 col-tiles): linear block id = ct*32 + rt so
   bid%8 == rt%8 -> XCD-affine row stripes (L2 reuse across launches). */
__global__ __launch_bounds__(256) void sink_step(const u16* S, const float* misc,
                          float* errs1, float* errs2,
                          float* u, float* ut, float* vvec, float* vtvec,
                          const float* prevRow, const float* prevCol,
                          float* outRow, float* outCol,
                          float* zero1, float* zero2, int nz1, int nz2,
                          int k, int roleB, int finalOnly,
                          const int* is_nc) {
  __shared__ float shW1[128];
  __shared__ float shW2[128];
  __shared__ float shAcc[16][128];
  __shared__ int   shG[4];
  __shared__ float se[4];
  const int tid = threadIdx.x;
  const int rt = blockIdx.x, ct = blockIdx.y;
  const int cbase = ct << 7, r0 = rt << 7;
  const float a = misc[1], ea = misc[5];

  if (!finalOnly) {
    int bid = (int)blockIdx.y * 32 + (int)blockIdx.x;
    int tot = nz1 + nz2;
    for (int z = bid * 256 + tid; z < tot; z += 1056 * 256) {
      if (z < nz1) zero1[z] = 0.f; else zero2[z - nz1] = 0.f;
    }
  }
  if (tid == 0) {
    shG[0] = (k >= 1) && (errs1[k-1] < THRESHc);
    shG[1] = (k >= 1) && (errs2[k-1] < THRESHc);
    shG[2] = (k >= 2) && (errs1[k-2] < THRESHc);
    shG[3] = (k >= 2) && (errs2[k-2] < THRESHc);
  }
  __syncthreads();
  const int c1 = shG[0], c2 = shG[1], c1p = shG[2], c2p = shG[3];
  const int gRow = roleB ? c2 : c1;
  const int gCol = roleB ? c1 : c2;

  float errd = 0.f;
  if (tid < 128) {
    const int i = r0 + tid;
    float w = 0.f;
    if (!roleB) {
      if (!finalOnly && !gCol) w = (k == 0) ? ea : ea / (4096.0f * prevRow[i]);
      if (ct == 0 && k >= 1 && !c2p) vtvec[i] = REGc * (-LOGN - __logf(prevRow[i]));
    } else {
      if (!gCol) {
        w = ea / (4096.0f * prevRow[i]);
        if (ct == 0) {
          float un = REGc * (-LOGN - __logf(prevRow[i]));
          errd = fabsf(un - u[i]);
          u[i] = un;
        }
      }
    }
    shW2[tid] = w;
  } else {
    const int j = cbase + (tid - 128);
    float w = 0.f;
    if (j <= NN) {
      if (!roleB) {
        if (!finalOnly && !gRow) w = (k == 0) ? ea : ea / (4097.0f * prevCol[j]);
        if (rt == 0 && k >= 1 && !c1p) vvec[j] = REGc * (-LOGM - __logf(prevCol[j]));
      } else {
        if (!gRow) {
          w = ea / (4097.0f * prevCol[j]);
          if (rt == 0) {
            float un = REGc * (-LOGM - __logf(prevCol[j]));
            errd = fabsf(un - ut[j]);
            ut[j] = un;
          }
        }
      }
    }
    shW1[tid - 128] = w;
  }
  __syncthreads();

  if (!finalOnly && !(gRow && gCol)) {
    const int tc = tid & 15, tr = tid >> 4;
    const int j0c = tc << 3;
    const int j0 = cbase + j0c;
    const bool anyv = (j0 <= NN);
    unsigned jval = 0;
    #pragma unroll
    for (int c = 0; c < 8; ++c) if (j0 + c <= NN) jval |= 1u << c;
    float W1l[8];
    #pragma unroll
    for (int c = 0; c < 8; ++c) W1l[c] = shW1[j0c + c];
    float cs[8];
    #pragma unroll
    for (int c = 0; c < 8; ++c) cs[c] = 0.f;
    for (int st = 0; st < 8; ++st) {
      const int rr = (st << 4) + tr;
      const int r = r0 + rr;
      float E[8];
      if (anyv) {
        float xv[8];
        unpack8(*(const Q*)(S + (size_t)r * LDA + j0), xv);
        const bool ncr = (is_nc[r] != 0);
        #pragma unroll
        for (int c = 0; c < 8; ++c) {
          E[c] = __expf(xv[c] * a);
          if (!((jval >> c & 1u) && unmasked(j0 + c, r, ncr))) E[c] = 0.f;
        }
      } else {
        #pragma unroll
        for (int c = 0; c < 8; ++c) E[c] = 0.f;
      }
      if (!gCol) {
        float Wr = shW2[rr];
        #pragma unroll
        for (int c = 0; c < 8; ++c) cs[c] = fmaf(E[c], Wr, cs[c]);
      }
      if (!gRow) {
        float rs = 0.f;
        #pragma unroll
        for (int c = 0; c < 8; ++c) rs = fmaf(E[c], W1l[c], rs);
        #pragma unroll
        for (int off = 8; off >= 1; off >>= 1) rs += __shfl_xor(rs, off);
        if (tc == 0) atomicAdd(&outRow[r], rs);
      }
    }
    if (!gCol) {
      #pragma unroll
      for (int c = 0; c < 8; ++c) shAcc[tr][j0c + c] = cs[c];
      __syncthreads();
      if (tid < 128) {
        float s = 0.f;
        #pragma unroll
        for (int g = 0; g < 16; ++g) s += shAcc[g][tid];
        const int j = cbase + tid;
        if (j <= NN) atomicAdd(&outCol[j], s);
      }
    }
  }

  if (roleB) {
    #pragma unroll
    for (int off = 32; off >= 1; off >>= 1) errd += __shfl_xor(errd, off);
    if ((tid & 63) == 0) se[tid >> 6] = errd;
    __syncthreads();
    if (tid == 0) {
      if (ct == 0) atomicAdd(&errs1[k], se[0] + se[1]);
      if (rt == 0) atomicAdd(&errs2[k], se[2] + se[3]);
    }
  }
}

/* ------- final pass 1: logit sums + masked label LSEs (row & col) ------- */
__global__ void final_pass(const u16* S, const float* vvec, const float* vtvec,
                           const float* misc, const int* is_nc,
                           float* rowLm, float* rowLs, float* rowGs,
                           float* colLm, float* colLs, float* colGs) {
  const float a = misc[1], scale = misc[0];
  const int ct = blockIdx.x, rt = blockIdx.y;
  const int tid = threadIdx.x;
  const int tc = tid & 31, tr = tid >> 5;
  const int cbase = ct << 8, r0 = rt << 8;
  const int j0 = cbase + (tc << 3);
  const bool anyv = (j0 <= NN);
  float wc[8]; unsigned jval = 0;
  #pragma unroll
  for (int c = 0; c < 8; ++c) {
    int j = j0 + c;
    wc[c] = 0.f;
    if (j <= NN) { jval |= 1u << c; wc[c] = vvec[j] * INVREG; }
  }
  float cLm[8], cLs[8], cGs[8];
  #pragma unroll
  for (int c = 0; c < 8; ++c) { cLm[c] = NEGINF; cLs[c] = 0.f; cGs[c] = 0.f; }
  for (int st = 0; st < 32; ++st) {
    const int r = r0 + (st << 3) + tr;
    float xv[8], lg[8]; unsigned um = 0;
    #pragma unroll
    for (int c = 0; c < 8; ++c) { xv[c] = 0.f; lg[c] = 0.f; }
    if (anyv) {
      float raw[8];
      unpack8(*(const Q*)(S + (size_t)r * LDA + j0), raw);
      const bool ncr = (is_nc[r] != 0);
      const float vtr = vtvec[r] * INVREG;
      #pragma unroll
      for (int c = 0; c < 8; ++c) {
        if (!(jval >> c & 1u)) continue;
        xv[c] = raw[c] * a;
        lg[c] = scale * raw[c];
        cGs[c] += __expf(lg[c]);
        if (unmasked(j0 + c, r, ncr)) {
          um |= 1u << c;
          float e2 = xv[c] + vtr;
          float nm = fmaxf(cLm[c], e2);
          cLs[c] = cLs[c] * __expf(cLm[c] - nm) + __expf(e2 - nm);
          cLm[c] = nm;
        }
      }
    }
    float rsG = 0.f;
    if (anyv) {
      #pragma unroll
      for (int c = 0; c < 8; ++c) if (jval >> c & 1u) rsG += __expf(lg[c]);
    }
    #pragma unroll
    for (int off = 16; off >= 1; off >>= 1) rsG += __shfl_xor(rsG, off);
    float rmL = NEGINF;
    if (anyv) {
      #pragma unroll
      for (int c = 0; c < 8; ++c) if (um >> c & 1u) rmL = fmaxf(rmL, xv[c] + wc[c]);
    }
    #pragma unroll
    for (int off = 16; off >= 1; off >>= 1) rmL = fmaxf(rmL, __shfl_xor(rmL, off));
    float rsL = 0.f;
    if (anyv && rmL > NEGINF) {
      #pragma unroll
      for (int c = 0; c < 8; ++c) if (um >> c & 1u) rsL += __expf(xv[c] + wc[c] - rmL);
    }
    #pragma unroll
    for (int off = 16; off >= 1; off >>= 1) rsL += __shfl_xor(rsL, off);
    if (tc == 0) {
      rowGs[ct * NN + r] = rsG;
      rowLm[ct * NN + r] = rmL;
      rowLs[ct * NN + r] = rsL;
    }
  }
  __shared__ float shm[8][256];
  __shared__ float shs[8][256];
  #pragma unroll
  for (int c = 0; c < 8; ++c) { shm[tr][(tc << 3) + c] = cLm[c]; shs[tr][(tc << 3) + c] = cLs[c]; }
  __syncthreads();
  {
    float m = NEGINF, s = 0.f;
    #pragma unroll
    for (int g = 0; g < 8; ++g) lse_merge(m, s, shm[g][tid], shs[g][tid]);
    const int j = cbase + tid;
    if (j <= NN) { colLm[rt * LDA + j] = m; colLs[rt * LDA + j] = s; }
  }
  __syncthreads();
  #pragma unroll
  for (int c = 0; c < 8; ++c) shs[tr][(tc << 3) + c] = cGs[c];
  __syncthreads();
  {
    float s = 0.f;
    #pragma unroll
    for (int g = 0; g < 8; ++g) s += shs[g][tid];
    const int j = cbase + tid;
    if (j <= NN) colGs[rt * LDA + j] = s;
  }
}

__global__ void final_combine(const float* rowLm, const float* rowLs, const float* rowGs,
                              const float* colLm, const float* colLs, const float* colGs,
                              float* LSMrow, float* LBLm, float* LBLs,
                              float* LSMcol, float* LBTm, float* LBTs) {
  const int b = blockIdx.x;
  if (b < 16) {
    const int i = (b << 8) + threadIdx.x;
    float m = NEGINF, s = 0.f, sg = 0.f;
    for (int t = 0; t < 17; ++t) {
      lse_merge(m, s, rowLm[t * NN + i], rowLs[t * NN + i]);
      sg += rowGs[t * NN + i];
    }
    LBLm[i] = m; LBLs[i] = s;
    LSMrow[i] = __logf(sg);
  } else {
    const int j = ((b - 16) << 8) + threadIdx.x;
    if (j <= NN) {
      float m = NEGINF, s = 0.f, sg = 0.f;
      for (int t = 0; t < 16; ++t) {
        lse_merge(m, s, colLm[t * LDA + j], colLs[t * LDA + j]);
        sg += colGs[t * LDA + j];
      }
      LBTm[j] = m; LBTs[j] = s;
      LSMcol[j] = __logf(sg);
    }
  }
}

/* ------- final pass 2: KL sums for both orientations ------- */
__global__ void loss_pass(const u16* S, const float* vvec, const float* vtvec,
                          const float* misc, const int* is_nc,
                          const float* LSMrow, const float* LBLm, const float* LBLs,
                          const float* LSMcol, const float* LBTm, const float* LBTs,
                          float* imgP, float* txtP) {
  const float a = misc[1], scale = misc[0];
  const int ct = blockIdx.x, rt = blockIdx.y;
  const int tid = threadIdx.x;
  const int tc = tid & 31, tr = tid >> 5;
  const int cbase = ct << 8, r0 = rt << 8;
  const int j0 = cbase + (tc << 3);
  const bool anyv = (j0 <= NN);
  float vcw[8], bm[8], bsi[8], cg[8]; unsigned jval = 0;
  #pragma unroll
  for (int c = 0; c < 8; ++c) {
    int j = j0 + c;
    vcw[c] = 0.f; bm[c] = 0.f; bsi[c] = 0.f; cg[c] = 0.f;
    if (j <= NN) {
      jval |= 1u << c;
      vcw[c] = vvec[j] * INVREG; bm[c] = LBTm[j]; bsi[c] = 1.f / LBTs[j]; cg[c] = LSMcol[j];
    }
  }
  float sImg = 0.f, sTxt = 0.f;
  for (int st = 0; st < 32; ++st) {
    const int r = r0 + (st << 3) + tr;
    if (anyv) {
      float raw[8];
      unpack8(*(const Q*)(S + (size_t)r * LDA + j0), raw);
      const bool ncr = (is_nc[r] != 0);
      const float vtr = vtvec[r] * INVREG;
      const float rm = LBLm[r], rsi = 1.f / LBLs[r], rg = LSMrow[r];
      #pragma unroll
      for (int c = 0; c < 8; ++c) {
        if (!(jval >> c & 1u)) continue;
        const int j = j0 + c;
        float xv = raw[c] * a;
        float lgt = scale * raw[c];
        bool unm = unmasked(j, r, ncr);
        bool lv = (j == NN) ? ncr : ((j == r) && !ncr);
        float rr = unm ? __expf(xv + vcw[c] - rm) * rsi : 0.f;
        float t = GAM * rr + (lv ? 0.2f : 0.f);
        if (t > 0.f) sImg += t * (__logf(t) - (lgt - rg));
        float r2 = unm ? __expf(xv + vtr - bm[c]) * bsi[c] : 0.f;
        float t2 = GAM * r2 + (lv ? 0.2f : 0.f);
        if (t2 > 0.f) sTxt += t2 * (__logf(t2) - (lgt - cg[c]));
      }
    }
  }
  sImg = blockReduce256(sImg);
  sTxt = blockReduce256(sTxt);
  if (tid == 0) { imgP[rt * 17 + ct] = sImg; txtP[rt * 17 + ct] = sTxt; }
}

__global__ void finish_kernel(const float* imgP, const float* txtP,
                              const float* misc, float* out) {
  float vi = 0.f, vtx = 0.f;
  for (int idx = threadIdx.x; idx < 272; idx += 256) { vi += imgP[idx]; vtx += txtP[idx]; }
  vi = blockReduce256(vi);
  vtx = blockReduce256(vtx);
  if (threadIdx.x == 0) {
    float loss_img = vi / 4096.0f;
    float loss_txt = vtx / 4097.0f;
    float loss_ul = 0.5f * (loss_img + loss_txt);
    float loss_op = misc[4] / 4096.0f;
    if (vi == 0.f && vtx == 0.f) loss_ul = 777.0f;
    if (!(loss_ul == loss_ul))   loss_ul = 888.0f;
    out[0] = loss_ul;
    out[1] = loss_op;
  }
}

extern "C" void kernel_launch(void* const* d_in, const int* in_sizes, int n_in,
                              void* d_out, int out_size, void* d_ws, size_t ws_size,
                              hipStream_t stream) {
  (void)in_sizes; (void)n_in; (void)out_size;
  const u16* img = (const u16*)d_in[0];
  const u16* txt = (const u16*)d_in[1];
  const u16* tno = (const u16*)d_in[2];
  const u16* ls  = (const u16*)d_in[3];
  float* out = (float*)d_out;

  ContrastiveLoss_83391085019222_kernel<<<1, 64, 0, stream>>>(out);

  size_t off = 0;
  char* w = (char*)d_ws;
  u16* S; u16* Abf; u16* Bbf;
  float *rsA0, *rsA1, *csA0, *csA1, *rsB0, *rsB1, *csB0, *csB1, *errs;
  float *rowLm, *rowLs, *rowGs, *colLm, *colLs, *colGs;
  float *vecs, *preds, *colvals, *gmin, *opP;
  float *LSMrow, *LBLm, *LBLs, *LSMcol, *LBTm, *LBTs, *imgP, *txtP, *misc;
  int* is_nc;
  #define ALLOC(ptr, type, nbytes) ptr = (type)(w + off); off = (off + (size_t)(nbytes) + 255) & ~(size_t)255
  ALLOC(S,      u16*,   (size_t)NN * LDA * 2);
  ALLOC(Abf,    u16*,   (size_t)NN * DD * 2);
  ALLOC(Bbf,    u16*,   (size_t)NN * DD * 2);
  ALLOC(rsA0,   float*, 4096 * 4);
  ALLOC(rsA1,   float*, 4096 * 4);
  ALLOC(csA0,   float*, 4104 * 4);
  ALLOC(csA1,   float*, 4104 * 4);
  ALLOC(rsB0,   float*, 4096 * 4);
  ALLOC(rsB1,   float*, 4096 * 4);
  ALLOC(csB0,   float*, 4104 * 4);
  ALLOC(csB1,   float*, 4104 * 4);
  ALLOC(errs,   float*, 256 * 4);
  ALLOC(rowLm,  float*, (size_t)17 * NN * 4);
  ALLOC(rowLs,  float*, (size_t)17 * NN * 4);
  ALLOC(rowGs,  float*, (size_t)17 * NN * 4);
  ALLOC(colLm,  float*, (size_t)16 * LDA * 4);
  ALLOC(colLs,  float*, (size_t)16 * LDA * 4);
  ALLOC(colGs,  float*, (size_t)16 * LDA * 4);
  ALLOC(vecs,   float*, 16400 * 4);
  ALLOC(preds,  float*, NN * 4);
  ALLOC(is_nc,  int*,   NN * 4);
  ALLOC(colvals,float*, NN * 4);
  ALLOC(gmin,   float*, 1024 * 4);
  ALLOC(opP,    float*, 1024 * 4);
  ALLOC(LSMrow, float*, NN * 4);
  ALLOC(LBLm,   float*, NN * 4);
  ALLOC(LBLs,   float*, NN * 4);
  ALLOC(LSMcol, float*, LDA * 4);
  ALLOC(LBTm,   float*, LDA * 4);
  ALLOC(LBTs,   float*, LDA * 4);
  ALLOC(imgP,   float*, 272 * 4);
  ALLOC(txtP,   float*, 272 * 4);
  ALLOC(misc,   float*, 64);
  #undef ALLOC

  if (ws_size < off) {
    diag_kernel<<<1, 64, 0, stream>>>(out, -(float)(ws_size / 1000000.0),
                                      -(float)(off / 1000000.0));
    return;
  }

  float* uvec  = vecs;
  float* vvec  = vecs + 4096;
  float* utvec = vecs + 8200;
  float* vtvec = vecs + 12304;
  float* errs1 = errs;
  float* errs2 = errs + 128;
  float* rsA[2] = { rsA0, rsA1 };
  float* csA[2] = { csA0, csA1 };
  float* rsB[2] = { rsB0, rsB1 };
  float* csB[2] = { csB0, csB1 };

  detect_kernel<<<1, 64, 0, stream>>>(img, misc);
  cvt_kernel<<<2048, 256, 0, stream>>>(img, txt, Abf, Bbf, misc);
  init_kernel<<<65, 256, 0, stream>>>(ls, vecs, errs, rsA0, csA0, misc);
  gemm_mfma<<<dim3(32, 32), 256, 0, stream>>>(Abf, Bbf, S, gmin);
  colvec_kernel<<<1024, 256, 0, stream>>>(img, txt, tno, S, colvals, opP, misc);
  reduce_kernel<<<1, 256, 0, stream>>>(gmin, colvals, opP, misc);

  preds_kernel<<<1024, 256, 0, stream>>>(S, misc, preds);
  rank_kernel<<<4096, 256, 0, stream>>>(preds, is_nc);

  const dim3 sg(32, 33);   /* x = row tile -> bid%8 == rt%8 (XCD affinity) */
  for (int k = 0; k < 100; ++k) {
    const int p = k & 1, q = (k + 1) & 1;
    const int pm = (k > 0) ? ((k - 1) & 1) : 0;
    sink_step<<<sg, 256, 0, stream>>>(S, misc, errs1, errs2,
        uvec, utvec, vvec, vtvec,
        rsB[pm], csB[pm], rsA[p], csA[p],
        csB[p], rsB[p], 4104, 4096,
        k, 0, 0, is_nc);
    sink_step<<<sg, 256, 0, stream>>>(S, misc, errs1, errs2,
        uvec, utvec, vvec, vtvec,
        rsA[p], csA[p], rsB[p], csB[p],
        rsA[q], csA[q], 4096, 4104,
        k, 1, 0, is_nc);
  }
  sink_step<<<sg, 256, 0, stream>>>(S, misc, errs1, errs2,
      uvec, utvec, vvec, vtvec,
      rsB[1], csB[1], rsA[0], csA[0],
      csB[0], rsB[0], 4104, 4096,
      100, 0, 1, is_nc);

  final_pass<<<dim3(17, 16), 256, 0, stream>>>(S, vvec, vtvec, misc, is_nc,
                                               rowLm, rowLs, rowGs, colLm, colLs, colGs);
  final_combine<<<33, 256, 0, stream>>>(rowLm, rowLs, rowGs, colLm, colLs, colGs,
                                        LSMrow, LBLm, LBLs, LSMcol, LBTm, LBTs);
  loss_pass<<<dim3(17, 16), 256, 0, stream>>>(S, vvec, vtvec, misc, is_nc,
                                              LSMrow, LBLm, LBLs, LSMcol, LBTm, LBTs, imgP, txtP);
  finish_kernel<<<1, 256, 0, stream>>>(imgP, txtP, misc, out);
}


// Round 20
// 884.383 us; speedup vs baseline: 4.7288x; 1.0494x over previous
//

#include <hip/hip_runtime.h>
#include <hip/hip_bf16.h>

// ROUND 20 (round 19: 928.0 us, absmax 0.0; top real dispatch final_pass
// 73 us at 10% occupancy, loss_pass same structure):
//  - final_pass & loss_pass retiled 256x256 -> 128x128, grid (33,32)=1056
//    blocks (~4/CU), partial buffers resized accordingly.

#define NN 4096
#define LDA 4104          /* fp16 row stride for S (4097 padded to x8) */
#define DD 512
#define NCNUM 409         /* int(0.1*4096) */
#define REGc 0.03f
#define INVREG (1.0f/0.03f)
#define GAM 0.8f
#define THRESHc 1e-4f
#define LOGN 8.3177661667193433f   /* ln(4096) */
#define LOGM 8.3180102775477533f   /* ln(4097) */
#define NEGINF (-__builtin_inff())

typedef unsigned short u16;
typedef unsigned int u32;
typedef _Float16 f16;

struct alignas(16) Q  { u32 x, y, z, w; };
struct alignas(8)  Q2 { u32 x, y; };
struct alignas(16) F4 { float a, b, c, d; };
union H8 { Q q; f16 h[8]; };

typedef __attribute__((ext_vector_type(8))) short frag_ab;   /* 8 bf16 */
typedef __attribute__((ext_vector_type(4))) float frag_cd;   /* 4 f32  */

__device__ __forceinline__ float bf2f(u32 u) { return __uint_as_float(u << 16); }
__device__ __forceinline__ float bflo(u32 w) { return __uint_as_float(w << 16); }
__device__ __forceinline__ float bfhi(u32 w) { return __uint_as_float(w & 0xFFFF0000u); }
__device__ __forceinline__ u16 f2bf_rne(float f) {
  u32 b = __float_as_uint(f);
  b += 0x7FFFu + ((b >> 16) & 1u);
  return (u16)(b >> 16);
}
__device__ __forceinline__ u16 f2h_hw(float f) {
  union { f16 h; u16 u; } X; X.h = (f16)f; return X.u;
}
__device__ __forceinline__ float h2f_hw(u16 v) {
  union { u16 u; f16 h; } X; X.u = v; return (float)X.h;
}
__device__ __forceinline__ void unpack8(Q q, float* x) {
  H8 u; u.q = q;
  #pragma unroll
  for (int c = 0; c < 8; ++c) x[c] = (float)u.h[c];
}
__device__ __forceinline__ void lse_merge(float& m, float& s, float om, float os) {
  float nm = fmaxf(m, om);
  if (nm == NEGINF) return;
  float acc = 0.f;
  if (s  > 0.f) acc += s  * __expf(m  - nm);
  if (os > 0.f) acc += os * __expf(om - nm);
  m = nm; s = acc;
}
__device__ __forceinline__ float blockReduce256(float v) {
  __shared__ float sh[4];
  #pragma unroll
  for (int off = 32; off >= 1; off >>= 1) v += __shfl_xor(v, off);
  int w = threadIdx.x >> 6;
  if ((threadIdx.x & 63) == 0) sh[w] = v;
  __syncthreads();
  float r = 0.f;
  if (threadIdx.x == 0) r = sh[0] + sh[1] + sh[2] + sh[3];
  __syncthreads();
  return r;
}

__global__ void ContrastiveLoss_83391085019222_kernel(float* out) {
  if (threadIdx.x == 0) { out[0] = 0.5f; out[1] = 0.5f; }
}
__global__ void diag_kernel(float* out, float a, float b) {
  if (threadIdx.x == 0) { out[0] = a; out[1] = b; }
}

/* ---- dtype autodetect: inputs are unit-normalized rows ---- */
__global__ void detect_kernel(const u16* img, float* misc) {
  const int lane = threadIdx.x;  /* 64 */
  float nb = 0.f, nf = 0.f;
  const float* fimg = (const float*)img;
  for (int c = lane * 8; c < lane * 8 + 8; ++c) {
    float xb = bf2f((u32)img[c]);
    nb += xb * xb;
    float xf = fimg[c];
    if (fabsf(xf) < 1e10f) nf += xf * xf; else nf += 1e10f;
  }
  #pragma unroll
  for (int off = 32; off >= 1; off >>= 1) { nb += __shfl_xor(nb, off); nf += __shfl_xor(nf, off); }
  if (lane == 0) {
    float db = fabsf(nb - 1.f);
    float df = fabsf(nf - 1.f);
    if (!(db == db)) db = 1e30f;
    if (!(df == df)) df = 1e30f;
    ((int*)misc)[10] = (df < db) ? 1 : 0;   /* 1 = float32 inputs */
  }
}

/* ---- convert img/txt to bf16 planes ---- */
__global__ void cvt_kernel(const u16* img, const u16* txt,
                           u16* Abf, u16* Bbf, const float* misc) {
  const int isF = ((const int*)misc)[10];
  const int t = blockIdx.x * 256 + threadIdx.x;
  const int base = t * 4;
  if (isF) {
    const float* fi = (const float*)img;
    const float* ft = (const float*)txt;
    ushort4 oa, ob;
    oa.x = f2bf_rne(fi[base+0]); oa.y = f2bf_rne(fi[base+1]);
    oa.z = f2bf_rne(fi[base+2]); oa.w = f2bf_rne(fi[base+3]);
    ob.x = f2bf_rne(ft[base+0]); ob.y = f2bf_rne(ft[base+1]);
    ob.z = f2bf_rne(ft[base+2]); ob.w = f2bf_rne(ft[base+3]);
    *(ushort4*)(Abf + base) = oa;
    *(ushort4*)(Bbf + base) = ob;
  } else {
    *(ushort4*)(Abf + base) = *(const ushort4*)(img + base);
    *(ushort4*)(Bbf + base) = *(const ushort4*)(txt + base);
  }
}

/* init: zero vecs(16400) + errs(256) + rsA0(4096) + csA0(4104), scale */
__global__ void init_kernel(const u16* ls, float* vecs, float* errs,
                            float* rsA0, float* csA0, float* misc) {
  int t = blockIdx.x * 256 + threadIdx.x;
  if (t < 16400) vecs[t] = 0.f;
  if (t < 256)  errs[t] = 0.f;
  if (t < 4096) rsA0[t] = 0.f;
  if (t < 4104) csA0[t] = 0.f;
  if (t == 0) {
    const int isF = ((const int*)misc)[10];
    float lsv = isF ? ((const float*)ls)[0] : bf2f((u32)ls[0]);
    misc[0] = __expf(lsv);               /* scale = exp(logit_scale) */
  }
}

/* ------- MFMA GEMM: S = Abf x Bbf^T -> fp16 + per-block min ------- */
__global__ __launch_bounds__(256) void gemm_mfma(const u16* Abf, const u16* Bbf,
                                                 u16* S, float* gmin) {
  __shared__ float red[256];
  const int tid = threadIdx.x;
  const int wave = tid >> 6, lane = tid & 63;
  const int wr = wave >> 1, wc = wave & 1;
  const int rb = (int)blockIdx.y * 128 + wr * 64;
  const int cb = (int)blockIdx.x * 128 + wc * 64;
  const int l15 = lane & 15, q = lane >> 4;

  frag_cd acc[4][4];
  #pragma unroll
  for (int i = 0; i < 4; ++i)
    #pragma unroll
    for (int j = 0; j < 4; ++j) acc[i][j] = (frag_cd){0.f, 0.f, 0.f, 0.f};

  for (int kt = 0; kt < DD; kt += 32) {
    frag_ab af[4], bfr[4];
    #pragma unroll
    for (int t = 0; t < 4; ++t) {
      af[t]  = *(const frag_ab*)(Abf + (size_t)(rb + t*16 + l15) * DD + kt + q*8);
      bfr[t] = *(const frag_ab*)(Bbf + (size_t)(cb + t*16 + l15) * DD + kt + q*8);
    }
    #pragma unroll
    for (int i = 0; i < 4; ++i)
      #pragma unroll
      for (int j = 0; j < 4; ++j)
        acc[i][j] = __builtin_amdgcn_mfma_f32_16x16x32_bf16(af[i], bfr[j], acc[i][j], 0, 0, 0);
  }

  float lmin = 1e30f;
  #pragma unroll
  for (int i = 0; i < 4; ++i) {
    #pragma unroll
    for (int j = 0; j < 4; ++j) {
      #pragma unroll
      for (int r = 0; r < 4; ++r) {
        const int row = rb + i*16 + q*4 + r;
        const int col = cb + j*16 + l15;
        u16 h = f2h_hw(acc[i][j][r]);
        lmin = fminf(lmin, h2f_hw(h));
        S[(size_t)row * LDA + col] = h;
      }
    }
  }
  red[tid] = lmin;
  __syncthreads();
  for (int sN = 128; sN >= 1; sN >>= 1) {
    if (tid < sN) red[tid] = fminf(red[tid], red[tid + sN]);
    __syncthreads();
  }
  if (tid == 0) gmin[blockIdx.y * 32 + blockIdx.x] = red[0];
}

/* ------- sims_no -> S col NN + loss_op partial ------- */
__global__ void colvec_kernel(const u16* img, const u16* txt, const u16* tno,
                              u16* S, float* colvals, float* opP, const float* misc) {
  __shared__ float shOp[4];
  const int isF = ((const int*)misc)[10];
  const int wv = threadIdx.x >> 6;
  const int row = (int)(blockIdx.x << 2) + wv;
  const int lane = threadIdx.x & 63;
  const size_t base = (size_t)row * DD + lane * 8;
  float xi[8], xt[8], xn[8];
  if (isF) {
    const float* fi = (const float*)img;
    const float* ft = (const float*)txt;
    const float* fn = (const float*)tno;
    #pragma unroll
    for (int c = 0; c < 8; ++c) { xi[c] = fi[base+c]; xt[c] = ft[base+c]; xn[c] = fn[base+c]; }
  } else {
    Q qi = *(const Q*)(img + base);
    Q qt = *(const Q*)(txt + base);
    Q qn = *(const Q*)(tno + base);
    xi[0]=bflo(qi.x); xi[1]=bfhi(qi.x); xi[2]=bflo(qi.y); xi[3]=bfhi(qi.y);
    xi[4]=bflo(qi.z); xi[5]=bfhi(qi.z); xi[6]=bflo(qi.w); xi[7]=bfhi(qi.w);
    xt[0]=bflo(qt.x); xt[1]=bfhi(qt.x); xt[2]=bflo(qt.y); xt[3]=bfhi(qt.y);
    xt[4]=bflo(qt.z); xt[5]=bfhi(qt.z); xt[6]=bflo(qt.w); xt[7]=bfhi(qt.w);
    xn[0]=bflo(qn.x); xn[1]=bfhi(qn.x); xn[2]=bflo(qn.y); xn[3]=bfhi(qn.y);
    xn[4]=bflo(qn.z); xn[5]=bfhi(qn.z); xn[6]=bflo(qn.w); xn[7]=bfhi(qn.w);
  }
  float sn = 0.f, cs = 0.f;
  #pragma unroll
  for (int c = 0; c < 8; ++c) { sn += xi[c]*xn[c]; cs += xt[c]*xn[c]; }
  #pragma unroll
  for (int off = 32; off >= 1; off >>= 1) { sn += __shfl_xor(sn, off); cs += __shfl_xor(cs, off); }
  if (lane == 0) {
    colvals[row] = sn;
    S[(size_t)row * LDA + NN] = f2h_hw(sn);
    shOp[wv] = fmaxf(cs + 0.2f, 0.f) + fmaxf(-0.7f - cs, 0.f);
  }
  __syncthreads();
  if (threadIdx.x == 0) opP[blockIdx.x] = shOp[0] + shOp[1] + shOp[2] + shOp[3];
}

__global__ void reduce_kernel(const float* gmin, const float* colvals,
                              const float* opP, float* misc) {
  __shared__ float smin[256];
  __shared__ float ssum[256];
  float mn = 1e30f, sm = 0.f;
  for (int i = threadIdx.x; i < 1024; i += 256) mn = fminf(mn, gmin[i]);
  for (int i = threadIdx.x; i < 4096; i += 256) mn = fminf(mn, h2f_hw(f2h_hw(colvals[i])));
  for (int i = threadIdx.x; i < 1024; i += 256) sm += opP[i];
  smin[threadIdx.x] = mn; ssum[threadIdx.x] = sm;
  __syncthreads();
  for (int sN = 128; sN >= 1; sN >>= 1) {
    if (threadIdx.x < sN) {
      smin[threadIdx.x] = fminf(smin[threadIdx.x], smin[threadIdx.x + sN]);
      ssum[threadIdx.x] += ssum[threadIdx.x + sN];
    }
    __syncthreads();
  }
  if (threadIdx.x == 0) {
    float maxC = 1.0f - smin[0];         /* max(1-S) = 1 - min(S) */
    float a = 1.0f / (maxC * REGc);
    misc[1] = a;
    misc[4] = ssum[0];
    misc[5] = __expf(-a);                /* ea */
  }
}

__global__ void preds_kernel(const u16* S, const float* misc, float* preds) {
  const int row = (int)(blockIdx.x << 2) + (int)(threadIdx.x >> 6);
  const int lane = threadIdx.x & 63;
  const float scale = misc[0];
  const u16* Sr = S + (size_t)row * LDA;
  float m = NEGINF, s = 0.f;
  for (int it = 0; it < 8; ++it) {
    const int j0 = (it << 9) + (lane << 3);
    float x[8];
    unpack8(*(const Q*)(Sr + j0), x);
    float lm = NEGINF;
    #pragma unroll
    for (int c = 0; c < 8; ++c) { x[c] *= scale; lm = fmaxf(lm, x[c]); }
    float lsum = 0.f;
    #pragma unroll
    for (int c = 0; c < 8; ++c) lsum += __expf(x[c] - lm);
    lse_merge(m, s, lm, lsum);
  }
  #pragma unroll
  for (int off = 32; off >= 1; off >>= 1) {
    float om = __shfl_xor(m, off), os = __shfl_xor(s, off);
    lse_merge(m, s, om, os);
  }
  if (lane == 0) {
    float sii = h2f_hw(Sr[row]);
    preds[row] = __expf(scale * sii - m) / s;
  }
}

/* ------- nc rank: one block per row ------- */
__global__ void rank_kernel(const float* preds, int* is_nc) {
  const int i = blockIdx.x;
  const float pv = preds[i];
  float cnt = 0.f;
  for (int k2 = threadIdx.x; k2 < NN; k2 += 256) {
    float pk = preds[k2];
    cnt += (pk < pv || (pk == pv && k2 < i)) ? 1.f : 0.f;
  }
  cnt = blockReduce256(cnt);
  if (threadIdx.x == 0) is_nc[i] = (cnt < (float)NCNUM) ? 1 : 0;
}

__device__ __forceinline__ bool unmasked(int j, int r, bool ncr) {
  return (j == NN) ? ncr : !((j == r) && ncr);
}

/* ------- fused sinkhorn step (multiplicative domain) ------- */
__global__ __launch_bounds__(256) void sink_step(const u16* S, const float* misc,
                          float* errs1, float* errs2,
                          float* u, float* ut, float* vvec, float* vtvec,
                          const float* prevRow, const float* prevCol,
                          float* outRow, float* outCol,
                          float* zero1, float* zero2, int nz1, int nz2,
                          int k, int roleB, int finalOnly,
                          const int* is_nc) {
  __shared__ float shW1[128];
  __shared__ float shW2[128];
  __shared__ float shAcc[16][128];
  __shared__ int   shG[4];
  __shared__ float se[4];
  const int tid = threadIdx.x;
  const int rt = blockIdx.x, ct = blockIdx.y;
  const int cbase = ct << 7, r0 = rt << 7;
  const float a = misc[1], ea = misc[5];

  if (!finalOnly) {
    int bid = (int)blockIdx.y * 32 + (int)blockIdx.x;
    int tot = nz1 + nz2;
    for (int z = bid * 256 + tid; z < tot; z += 1056 * 256) {
      if (z < nz1) zero1[z] = 0.f; else zero2[z - nz1] = 0.f;
    }
  }
  if (tid == 0) {
    shG[0] = (k >= 1) && (errs1[k-1] < THRESHc);
    shG[1] = (k >= 1) && (errs2[k-1] < THRESHc);
    shG[2] = (k >= 2) && (errs1[k-2] < THRESHc);
    shG[3] = (k >= 2) && (errs2[k-2] < THRESHc);
  }
  __syncthreads();
  const int c1 = shG[0], c2 = shG[1], c1p = shG[2], c2p = shG[3];
  const int gRow = roleB ? c2 : c1;
  const int gCol = roleB ? c1 : c2;

  float errd = 0.f;
  if (tid < 128) {
    const int i = r0 + tid;
    float w = 0.f;
    if (!roleB) {
      if (!finalOnly && !gCol) w = (k == 0) ? ea : ea / (4096.0f * prevRow[i]);
      if (ct == 0 && k >= 1 && !c2p) vtvec[i] = REGc * (-LOGN - __logf(prevRow[i]));
    } else {
      if (!gCol) {
        w = ea / (4096.0f * prevRow[i]);
        if (ct == 0) {
          float un = REGc * (-LOGN - __logf(prevRow[i]));
          errd = fabsf(un - u[i]);
          u[i] = un;
        }
      }
    }
    shW2[tid] = w;
  } else {
    const int j = cbase + (tid - 128);
    float w = 0.f;
    if (j <= NN) {
      if (!roleB) {
        if (!finalOnly && !gRow) w = (k == 0) ? ea : ea / (4097.0f * prevCol[j]);
        if (rt == 0 && k >= 1 && !c1p) vvec[j] = REGc * (-LOGM - __logf(prevCol[j]));
      } else {
        if (!gRow) {
          w = ea / (4097.0f * prevCol[j]);
          if (rt == 0) {
            float un = REGc * (-LOGM - __logf(prevCol[j]));
            errd = fabsf(un - ut[j]);
            ut[j] = un;
          }
        }
      }
    }
    shW1[tid - 128] = w;
  }
  __syncthreads();

  if (!finalOnly && !(gRow && gCol)) {
    const int tc = tid & 15, tr = tid >> 4;
    const int j0c = tc << 3;
    const int j0 = cbase + j0c;
    const bool anyv = (j0 <= NN);
    unsigned jval = 0;
    #pragma unroll
    for (int c = 0; c < 8; ++c) if (j0 + c <= NN) jval |= 1u << c;
    float W1l[8];
    #pragma unroll
    for (int c = 0; c < 8; ++c) W1l[c] = shW1[j0c + c];
    float cs[8];
    #pragma unroll
    for (int c = 0; c < 8; ++c) cs[c] = 0.f;
    for (int st = 0; st < 8; ++st) {
      const int rr = (st << 4) + tr;
      const int r = r0 + rr;
      float E[8];
      if (anyv) {
        float xv[8];
        unpack8(*(const Q*)(S + (size_t)r * LDA + j0), xv);
        const bool ncr = (is_nc[r] != 0);
        #pragma unroll
        for (int c = 0; c < 8; ++c) {
          E[c] = __expf(xv[c] * a);
          if (!((jval >> c & 1u) && unmasked(j0 + c, r, ncr))) E[c] = 0.f;
        }
      } else {
        #pragma unroll
        for (int c = 0; c < 8; ++c) E[c] = 0.f;
      }
      if (!gCol) {
        float Wr = shW2[rr];
        #pragma unroll
        for (int c = 0; c < 8; ++c) cs[c] = fmaf(E[c], Wr, cs[c]);
      }
      if (!gRow) {
        float rs = 0.f;
        #pragma unroll
        for (int c = 0; c < 8; ++c) rs = fmaf(E[c], W1l[c], rs);
        #pragma unroll
        for (int off = 8; off >= 1; off >>= 1) rs += __shfl_xor(rs, off);
        if (tc == 0) atomicAdd(&outRow[r], rs);
      }
    }
    if (!gCol) {
      #pragma unroll
      for (int c = 0; c < 8; ++c) shAcc[tr][j0c + c] = cs[c];
      __syncthreads();
      if (tid < 128) {
        float s = 0.f;
        #pragma unroll
        for (int g = 0; g < 16; ++g) s += shAcc[g][tid];
        const int j = cbase + tid;
        if (j <= NN) atomicAdd(&outCol[j], s);
      }
    }
  }

  if (roleB) {
    #pragma unroll
    for (int off = 32; off >= 1; off >>= 1) errd += __shfl_xor(errd, off);
    if ((tid & 63) == 0) se[tid >> 6] = errd;
    __syncthreads();
    if (tid == 0) {
      if (ct == 0) atomicAdd(&errs1[k], se[0] + se[1]);
      if (rt == 0) atomicAdd(&errs2[k], se[2] + se[3]);
    }
  }
}

/* ------- final pass 1 (128x128 tiles, grid (33,32)) ------- */
__global__ __launch_bounds__(256) void final_pass(const u16* S, const float* vvec,
                           const float* vtvec, const float* misc, const int* is_nc,
                           float* rowLm, float* rowLs, float* rowGs,
                           float* colLm, float* colLs, float* colGs) {
  const float a = misc[1], scale = misc[0];
  const int ct = blockIdx.x, rt = blockIdx.y;
  const int tid = threadIdx.x;
  const int tc = tid & 15, tr = tid >> 4;
  const int cbase = ct << 7, r0 = rt << 7;
  const int j0 = cbase + (tc << 3);
  const bool anyv = (j0 <= NN);
  float wc[8]; unsigned jval = 0;
  #pragma unroll
  for (int c = 0; c < 8; ++c) {
    int j = j0 + c;
    wc[c] = 0.f;
    if (j <= NN) { jval |= 1u << c; wc[c] = vvec[j] * INVREG; }
  }
  float cLm[8], cLs[8], cGs[8];
  #pragma unroll
  for (int c = 0; c < 8; ++c) { cLm[c] = NEGINF; cLs[c] = 0.f; cGs[c] = 0.f; }
  for (int st = 0; st < 8; ++st) {
    const int r = r0 + (st << 4) + tr;
    float xv[8], lg[8]; unsigned um = 0;
    #pragma unroll
    for (int c = 0; c < 8; ++c) { xv[c] = 0.f; lg[c] = 0.f; }
    if (anyv) {
      float raw[8];
      unpack8(*(const Q*)(S + (size_t)r * LDA + j0), raw);
      const bool ncr = (is_nc[r] != 0);
      const float vtr = vtvec[r] * INVREG;
      #pragma unroll
      for (int c = 0; c < 8; ++c) {
        if (!(jval >> c & 1u)) continue;
        xv[c] = raw[c] * a;
        lg[c] = scale * raw[c];
        cGs[c] += __expf(lg[c]);
        if (unmasked(j0 + c, r, ncr)) {
          um |= 1u << c;
          float e2 = xv[c] + vtr;
          float nm = fmaxf(cLm[c], e2);
          cLs[c] = cLs[c] * __expf(cLm[c] - nm) + __expf(e2 - nm);
          cLm[c] = nm;
        }
      }
    }
    float rsG = 0.f;
    if (anyv) {
      #pragma unroll
      for (int c = 0; c < 8; ++c) if (jval >> c & 1u) rsG += __expf(lg[c]);
    }
    #pragma unroll
    for (int off = 8; off >= 1; off >>= 1) rsG += __shfl_xor(rsG, off);
    float rmL = NEGINF;
    if (anyv) {
      #pragma unroll
      for (int c = 0; c < 8; ++c) if (um >> c & 1u) rmL = fmaxf(rmL, xv[c] + wc[c]);
    }
    #pragma unroll
    for (int off = 8; off >= 1; off >>= 1) rmL = fmaxf(rmL, __shfl_xor(rmL, off));
    float rsL = 0.f;
    if (anyv && rmL > NEGINF) {
      #pragma unroll
      for (int c = 0; c < 8; ++c) if (um >> c & 1u) rsL += __expf(xv[c] + wc[c] - rmL);
    }
    #pragma unroll
    for (int off = 8; off >= 1; off >>= 1) rsL += __shfl_xor(rsL, off);
    if (tc == 0) {
      rowGs[ct * NN + r] = rsG;
      rowLm[ct * NN + r] = rmL;
      rowLs[ct * NN + r] = rsL;
    }
  }
  __shared__ float shm[16][128];
  __shared__ float shs[16][128];
  #pragma unroll
  for (int c = 0; c < 8; ++c) { shm[tr][(tc << 3) + c] = cLm[c]; shs[tr][(tc << 3) + c] = cLs[c]; }
  __syncthreads();
  if (tid < 128) {
    float m = NEGINF, s = 0.f;
    #pragma unroll
    for (int g = 0; g < 16; ++g) lse_merge(m, s, shm[g][tid], shs[g][tid]);
    const int j = cbase + tid;
    if (j <= NN) { colLm[rt * LDA + j] = m; colLs[rt * LDA + j] = s; }
  }
  __syncthreads();
  #pragma unroll
  for (int c = 0; c < 8; ++c) shs[tr][(tc << 3) + c] = cGs[c];
  __syncthreads();
  if (tid < 128) {
    float s = 0.f;
    #pragma unroll
    for (int g = 0; g < 16; ++g) s += shs[g][tid];
    const int j = cbase + tid;
    if (j <= NN) colGs[rt * LDA + j] = s;
  }
}

__global__ void final_combine(const float* rowLm, const float* rowLs, const float* rowGs,
                              const float* colLm, const float* colLs, const float* colGs,
                              float* LSMrow, float* LBLm, float* LBLs,
                              float* LSMcol, float* LBTm, float* LBTs) {
  const int b = blockIdx.x;
  if (b < 16) {
    const int i = (b << 8) + threadIdx.x;
    float m = NEGINF, s = 0.f, sg = 0.f;
    for (int t = 0; t < 33; ++t) {
      lse_merge(m, s, rowLm[t * NN + i], rowLs[t * NN + i]);
      sg += rowGs[t * NN + i];
    }
    LBLm[i] = m; LBLs[i] = s;
    LSMrow[i] = __logf(sg);
  } else {
    const int j = ((b - 16) << 8) + threadIdx.x;
    if (j <= NN) {
      float m = NEGINF, s = 0.f, sg = 0.f;
      for (int t = 0; t < 32; ++t) {
        lse_merge(m, s, colLm[t * LDA + j], colLs[t * LDA + j]);
        sg += colGs[t * LDA + j];
      }
      LBTm[j] = m; LBTs[j] = s;
      LSMcol[j] = __logf(sg);
    }
  }
}

/* ------- final pass 2: KL sums (128x128 tiles, grid (33,32)) ------- */
__global__ __launch_bounds__(256) void loss_pass(const u16* S, const float* vvec,
                          const float* vtvec, const float* misc, const int* is_nc,
                          const float* LSMrow, const float* LBLm, const float* LBLs,
                          const float* LSMcol, const float* LBTm, const float* LBTs,
                          float* imgP, float* txtP) {
  const float a = misc[1], scale = misc[0];
  const int ct = blockIdx.x, rt = blockIdx.y;
  const int tid = threadIdx.x;
  const int tc = tid & 15, tr = tid >> 4;
  const int cbase = ct << 7, r0 = rt << 7;
  const int j0 = cbase + (tc << 3);
  const bool anyv = (j0 <= NN);
  float vcw[8], bm[8], bsi[8], cg[8]; unsigned jval = 0;
  #pragma unroll
  for (int c = 0; c < 8; ++c) {
    int j = j0 + c;
    vcw[c] = 0.f; bm[c] = 0.f; bsi[c] = 0.f; cg[c] = 0.f;
    if (j <= NN) {
      jval |= 1u << c;
      vcw[c] = vvec[j] * INVREG; bm[c] = LBTm[j]; bsi[c] = 1.f / LBTs[j]; cg[c] = LSMcol[j];
    }
  }
  float sImg = 0.f, sTxt = 0.f;
  for (int st = 0; st < 8; ++st) {
    const int r = r0 + (st << 4) + tr;
    if (anyv) {
      float raw[8];
      unpack8(*(const Q*)(S + (size_t)r * LDA + j0), raw);
      const bool ncr = (is_nc[r] != 0);
      const float vtr = vtvec[r] * INVREG;
      const float rm = LBLm[r], rsi = 1.f / LBLs[r], rg = LSMrow[r];
      #pragma unroll
      for (int c = 0; c < 8; ++c) {
        if (!(jval >> c & 1u)) continue;
        const int j = j0 + c;
        float xv = raw[c] * a;
        float lgt = scale * raw[c];
        bool unm = unmasked(j, r, ncr);
        bool lv = (j == NN) ? ncr : ((j == r) && !ncr);
        float rr = unm ? __expf(xv + vcw[c] - rm) * rsi : 0.f;
        float t = GAM * rr + (lv ? 0.2f : 0.f);
        if (t > 0.f) sImg += t * (__logf(t) - (lgt - rg));
        float r2 = unm ? __expf(xv + vtr - bm[c]) * bsi[c] : 0.f;
        float t2 = GAM * r2 + (lv ? 0.2f : 0.f);
        if (t2 > 0.f) sTxt += t2 * (__logf(t2) - (lgt - cg[c]));
      }
    }
  }
  sImg = blockReduce256(sImg);
  sTxt = blockReduce256(sTxt);
  if (tid == 0) { imgP[rt * 33 + ct] = sImg; txtP[rt * 33 + ct] = sTxt; }
}

__global__ void finish_kernel(const float* imgP, const float* txtP,
                              const float* misc, float* out) {
  float vi = 0.f, vtx = 0.f;
  for (int idx = threadIdx.x; idx < 1056; idx += 256) { vi += imgP[idx]; vtx += txtP[idx]; }
  vi = blockReduce256(vi);
  vtx = blockReduce256(vtx);
  if (threadIdx.x == 0) {
    float loss_img = vi / 4096.0f;
    float loss_txt = vtx / 4097.0f;
    float loss_ul = 0.5f * (loss_img + loss_txt);
    float loss_op = misc[4] / 4096.0f;
    if (vi == 0.f && vtx == 0.f) loss_ul = 777.0f;
    if (!(loss_ul == loss_ul))   loss_ul = 888.0f;
    out[0] = loss_ul;
    out[1] = loss_op;
  }
}

extern "C" void kernel_launch(void* const* d_in, const int* in_sizes, int n_in,
                              void* d_out, int out_size, void* d_ws, size_t ws_size,
                              hipStream_t stream) {
  (void)in_sizes; (void)n_in; (void)out_size;
  const u16* img = (const u16*)d_in[0];
  const u16* txt = (const u16*)d_in[1];
  const u16* tno = (const u16*)d_in[2];
  const u16* ls  = (const u16*)d_in[3];
  float* out = (float*)d_out;

  ContrastiveLoss_83391085019222_kernel<<<1, 64, 0, stream>>>(out);

  size_t off = 0;
  char* w = (char*)d_ws;
  u16* S; u16* Abf; u16* Bbf;
  float *rsA0, *rsA1, *csA0, *csA1, *rsB0, *rsB1, *csB0, *csB1, *errs;
  float *rowLm, *rowLs, *rowGs, *colLm, *colLs, *colGs;
  float *vecs, *preds, *colvals, *gmin, *opP;
  float *LSMrow, *LBLm, *LBLs, *LSMcol, *LBTm, *LBTs, *imgP, *txtP, *misc;
  int* is_nc;
  #define ALLOC(ptr, type, nbytes) ptr = (type)(w + off); off = (off + (size_t)(nbytes) + 255) & ~(size_t)255
  ALLOC(S,      u16*,   (size_t)NN * LDA * 2);
  ALLOC(Abf,    u16*,   (size_t)NN * DD * 2);
  ALLOC(Bbf,    u16*,   (size_t)NN * DD * 2);
  ALLOC(rsA0,   float*, 4096 * 4);
  ALLOC(rsA1,   float*, 4096 * 4);
  ALLOC(csA0,   float*, 4104 * 4);
  ALLOC(csA1,   float*, 4104 * 4);
  ALLOC(rsB0,   float*, 4096 * 4);
  ALLOC(rsB1,   float*, 4096 * 4);
  ALLOC(csB0,   float*, 4104 * 4);
  ALLOC(csB1,   float*, 4104 * 4);
  ALLOC(errs,   float*, 256 * 4);
  ALLOC(rowLm,  float*, (size_t)33 * NN * 4);
  ALLOC(rowLs,  float*, (size_t)33 * NN * 4);
  ALLOC(rowGs,  float*, (size_t)33 * NN * 4);
  ALLOC(colLm,  float*, (size_t)32 * LDA * 4);
  ALLOC(colLs,  float*, (size_t)32 * LDA * 4);
  ALLOC(colGs,  float*, (size_t)32 * LDA * 4);
  ALLOC(vecs,   float*, 16400 * 4);
  ALLOC(preds,  float*, NN * 4);
  ALLOC(is_nc,  int*,   NN * 4);
  ALLOC(colvals,float*, NN * 4);
  ALLOC(gmin,   float*, 1024 * 4);
  ALLOC(opP,    float*, 1024 * 4);
  ALLOC(LSMrow, float*, NN * 4);
  ALLOC(LBLm,   float*, NN * 4);
  ALLOC(LBLs,   float*, NN * 4);
  ALLOC(LSMcol, float*, LDA * 4);
  ALLOC(LBTm,   float*, LDA * 4);
  ALLOC(LBTs,   float*, LDA * 4);
  ALLOC(imgP,   float*, 1056 * 4);
  ALLOC(txtP,   float*, 1056 * 4);
  ALLOC(misc,   float*, 64);
  #undef ALLOC

  if (ws_size < off) {
    diag_kernel<<<1, 64, 0, stream>>>(out, -(float)(ws_size / 1000000.0),
                                      -(float)(off / 1000000.0));
    return;
  }

  float* uvec  = vecs;
  float* vvec  = vecs + 4096;
  float* utvec = vecs + 8200;
  float* vtvec = vecs + 12304;
  float* errs1 = errs;
  float* errs2 = errs + 128;
  float* rsA[2] = { rsA0, rsA1 };
  float* csA[2] = { csA0, csA1 };
  float* rsB[2] = { rsB0, rsB1 };
  float* csB[2] = { csB0, csB1 };

  detect_kernel<<<1, 64, 0, stream>>>(img, misc);
  cvt_kernel<<<2048, 256, 0, stream>>>(img, txt, Abf, Bbf, misc);
  init_kernel<<<65, 256, 0, stream>>>(ls, vecs, errs, rsA0, csA0, misc);
  gemm_mfma<<<dim3(32, 32), 256, 0, stream>>>(Abf, Bbf, S, gmin);
  colvec_kernel<<<1024, 256, 0, stream>>>(img, txt, tno, S, colvals, opP, misc);
  reduce_kernel<<<1, 256, 0, stream>>>(gmin, colvals, opP, misc);

  preds_kernel<<<1024, 256, 0, stream>>>(S, misc, preds);
  rank_kernel<<<4096, 256, 0, stream>>>(preds, is_nc);

  const dim3 sg(32, 33);   /* x = row tile -> bid%8 == rt%8 (XCD affinity) */
  for (int k = 0; k < 100; ++k) {
    const int p = k & 1, q = (k + 1) & 1;
    const int pm = (k > 0) ? ((k - 1) & 1) : 0;
    sink_step<<<sg, 256, 0, stream>>>(S, misc, errs1, errs2,
        uvec, utvec, vvec, vtvec,
        rsB[pm], csB[pm], rsA[p], csA[p],
        csB[p], rsB[p], 4104, 4096,
        k, 0, 0, is_nc);
    sink_step<<<sg, 256, 0, stream>>>(S, misc, errs1, errs2,
        uvec, utvec, vvec, vtvec,
        rsA[p], csA[p], rsB[p], csB[p],
        rsA[q], csA[q], 4096, 4104,
        k, 1, 0, is_nc);
  }
  sink_step<<<sg, 256, 0, stream>>>(S, misc, errs1, errs2,
      uvec, utvec, vvec, vtvec,
      rsB[1], csB[1], rsA[0], csA[0],
      csB[0], rsB[0], 4104, 4096,
      100, 0, 1, is_nc);

  final_pass<<<dim3(33, 32), 256, 0, stream>>>(S, vvec, vtvec, misc, is_nc,
                                               rowLm, rowLs, rowGs, colLm, colLs, colGs);
  final_combine<<<33, 256, 0, stream>>>(rowLm, rowLs, rowGs, colLm, colLs, colGs,
                                        LSMrow, LBLm, LBLs, LSMcol, LBTm, LBTs);
  loss_pass<<<dim3(33, 32), 256, 0, stream>>>(S, vvec, vtvec, misc, is_nc,
                                              LSMrow, LBLm, LBLs, LSMcol, LBTm, LBTs, imgP, txtP);
  finish_kernel<<<1, 256, 0, stream>>>(imgP, txtP, misc, out);
}
